// Round 5
// baseline (497.820 us; speedup 1.0000x reference)
//
#include <hip/hip_runtime.h>
#include <hip/hip_bf16.h>
#include <math.h>

// ---------------- problem constants ----------------
#define NB   256
#define NT   288
#define NOBS 256
#define NTP  32

// output offsets (floats)
#define O_ST_OBS   0
#define O_ST_PRED  131072
#define O_ZM_OBS   147456
#define O_ZS_OBS   1196032
#define O_ZM_PRED  2244608
#define O_ZS_PRED  2375680
#define O_XREC     2506752
#define O_NLL      4079616

// workspace offsets (floats)
#define W_U    0          // [288][256][2]
#define W_H2N  147456     // [32][4][256][32] normalized h2 by quadrant
#define W_P3   1196032    // [32][4][16][2]  convT1 per-(tp,g) partial sums (s,ss)
// total ws usage: 1200128 floats = 4.80 MB

__device__ __forceinline__ float wred(float v) {
    v += __shfl_down(v, 32); v += __shfl_down(v, 16); v += __shfl_down(v, 8);
    v += __shfl_down(v, 4);  v += __shfl_down(v, 2);  v += __shfl_down(v, 1);
    return v;
}
__device__ __forceinline__ float sigm(float x) { return 1.0f / (1.0f + __expf(-x)); }
__device__ __forceinline__ float tanh_f(float x) {
    x = fminf(fmaxf(x, -15.0f), 15.0f);
    float e = __expf(2.0f * x);
    return (e - 1.0f) / (e + 1.0f);
}
// NOTE: no macro parameter may be named x/y/z/w (member-access collision!)
#define FMA4(ax,ay,az,aw,wv,acc) fmaf((ax),(wv).x,fmaf((ay),(wv).y,fmaf((az),(wv).z,fmaf((aw),(wv).w,(acc)))))

// ==================== Kernel 0: U[t][b][2] = act^T . Wa ====================
extern "C" __global__ void __launch_bounds__(288)
k_pre(const float* __restrict__ act, const float* __restrict__ Wa, float* __restrict__ ws)
{
    const int b = blockIdx.x;     // 0..255
    const int t = threadIdx.x;    // 0..287
    float u0 = 0.f, u1 = 0.f;
#pragma unroll
    for (int a = 0; a < 5; a++) {
        const float av = act[(b * 5 + a) * 288 + t];
        u0 = fmaf(av, Wa[a], u0);
        u1 = fmaf(av, Wa[5 + a], u1);
    }
    ws[W_U + (t * 256 + b) * 2 + 0] = u0;
    ws[W_U + (t * 256 + b) * 2 + 1] = u1;
}

// ==================== Kernel 1: recurrence (block 0) + encoder (blocks 1..288) ====================
extern "C" __global__ void __launch_bounds__(256, 3)
k_enc_rec(const float* __restrict__ x,
          const int*   __restrict__ pos,  const float* __restrict__ s0,
          const float* __restrict__ nobs, const float* __restrict__ npred,
          const float* __restrict__ Ws1,  const float* __restrict__ bs1,
          const float* __restrict__ Ws2,  const float* __restrict__ bs2,
          const float* __restrict__ Wc1,  const float* __restrict__ bc1,
          const float* __restrict__ g1,   const float* __restrict__ be1,
          const float* __restrict__ Wc2,  const float* __restrict__ bc2,
          const float* __restrict__ g2,   const float* __restrict__ be2,
          const float* __restrict__ Wzm,  const float* __restrict__ bzm,
          const float* __restrict__ Wzs,  const float* __restrict__ bzs,
          const float* __restrict__ ws,
          float* __restrict__ out)
{
    const int tid = threadIdx.x;

    if (blockIdx.x == 0) {
        // ---------------- state recurrence: thread = batch element ----------------
        const int b = tid;
        float w1[10], w2[10], c1[5], c2_0, c2_1;
#pragma unroll
        for (int i = 0; i < 10; i++) { w1[i] = Ws1[i]; w2[i] = Ws2[i]; }
#pragma unroll
        for (int i = 0; i < 5; i++) c1[i] = bs1[i];
        c2_0 = bs2[0]; c2_1 = bs2[1];

        float sv0 = s0[b * 2 + 0], sv1 = s0[b * 2 + 1];
        ((float2*)(out + O_ST_OBS))[b] = make_float2(sv0, sv1);
        if (b == 0) out[O_NLL] = 0.0f;   // re-zeroed every call, stream-ordered before k_dec2

        const float2* Up   = (const float2*)(ws + W_U);
        const float2* Nobs = (const float2*)nobs;
        const float2* Nprd = (const float2*)npred;

        float2 u  = Up[256 + b];
        float2 nz = Nobs[b];

        for (int t = 1; t < 288; t++) {
            float2 u_n = make_float2(0.f, 0.f), nz_n = make_float2(0.f, 0.f);
            if (t < 287) {
                u_n = Up[(t + 1) * 256 + b];
                const float2* np = (t + 1 < 256) ? (Nobs + t * 256 + b)
                                                 : (Nprd + (t - 255) * 256 + b);
                nz_n = *np;
            }
            const float v0 = sv0 + u.x, v1 = sv1 + u.y;
            float h[5];
#pragma unroll
            for (int j = 0; j < 5; j++)
                h[j] = tanh_f(fmaf(v1, w1[j * 2 + 1], fmaf(v0, w1[j * 2 + 0], c1[j])));
            float a0 = fmaf(h[0], w2[0], fmaf(h[1], w2[1], c2_0));
            float a0b = fmaf(h[2], w2[2], h[3] * w2[3]);
            a0 = fmaf(h[4], w2[4], a0 + a0b);
            float a1 = fmaf(h[0], w2[5], fmaf(h[1], w2[6], c2_1));
            float a1b = fmaf(h[2], w2[7], h[3] * w2[8]);
            a1 = fmaf(h[4], w2[9], a1 + a1b);

            sv0 = fmaf(u.x, sigm(a0), sv0) + nz.x;
            sv1 = fmaf(u.y, sigm(a1), sv1) + nz.y;

            if (t < 256) ((float2*)(out + O_ST_OBS))[t * 256 + b] = make_float2(sv0, sv1);
            else         ((float2*)(out + O_ST_PRED))[(t - 256) * 256 + b] = make_float2(sv0, sv1);

            u = u_n; nz = nz_n;
        }
        return;
    }

    // ---------------- glimpse encoder, t = blockIdx.x - 1, thread = batch ----------------
    const int t = blockIdx.x - 1;
    __shared__ __align__(16) float sWc1[192];
    __shared__ __align__(16) float sWc2[2048];    // natural [oc][ic][q]
    __shared__ __align__(16) float sWzm[512];
    __shared__ __align__(16) float sWzs[512];
    __shared__ __align__(16) float sM1[16], sS1[16], sE1[16];
    __shared__ float sB1[16], sB2[32], sE2[32], sBzm[16], sBzs[16];
    __shared__ float sM2[32], sS2[32];
    __shared__ float sRed[4][64];

    for (int i = tid; i < 192; i += 256) sWc1[i] = Wc1[i];
    for (int i = tid; i < 2048; i += 256) sWc2[i] = Wc2[i];
    for (int i = tid; i < 512; i += 256) { sWzm[i] = Wzm[i]; sWzs[i] = Wzs[i]; }
    if (tid < 16) { sB1[tid] = bc1[tid]; sE1[tid] = be1[tid]; sBzm[tid] = bzm[tid]; sBzs[tid] = bzs[tid]; }
    if (tid < 32) { sB2[tid] = bc2[tid]; sE2[tid] = be2[tid]; }
    __syncthreads();

    const int b = tid;
    const int wid = tid >> 6, lane = tid & 63;
    const float* xb = x + b * 3072;
    const int pr = 3 * pos[(b * 2 + 0) * 288 + t];
    const int pc = 3 * pos[(b * 2 + 1) * 288 + t];

    // ---- conv1 (3->16, 2x2, s2) + relu + maxpool -> pooled[oc*4 + pos] (registers) ----
    float pooled[64];
#pragma unroll
    for (int i = 0; i < 64; i++) pooled[i] = 0.f;   // relu >= 0, so 0-init == true max

#pragma unroll
    for (int py = 0; py < 2; py++)
#pragma unroll
    for (int px = 0; px < 2; px++) {
#pragma unroll 2
        for (int d = 0; d < 4; d++) {
            const int rbase = pr + 4 * py + 2 * (d >> 1);
            const int cbase = pc + 4 * px + 2 * (d & 1);
            float in[12];
#pragma unroll
            for (int ic = 0; ic < 3; ic++)
#pragma unroll
            for (int ky = 0; ky < 2; ky++)
#pragma unroll
            for (int kx = 0; kx < 2; kx++)
                in[ic * 4 + ky * 2 + kx] = xb[ic * 1024 + (rbase + ky) * 32 + (cbase + kx)];
#pragma unroll
            for (int oc = 0; oc < 16; oc++) {
                const float4 wq0 = *(const float4*)&sWc1[oc * 12 + 0];
                const float4 wq1 = *(const float4*)&sWc1[oc * 12 + 4];
                const float4 wq2 = *(const float4*)&sWc1[oc * 12 + 8];
                float v = sB1[oc];
                v = FMA4(in[0], in[1], in[2], in[3], wq0, v);
                v = FMA4(in[4], in[5], in[6], in[7], wq1, v);
                v = FMA4(in[8], in[9], in[10], in[11], wq2, v);
                pooled[oc * 4 + py * 2 + px] = fmaxf(pooled[oc * 4 + py * 2 + px], fmaxf(v, 0.f));
            }
        }
    }

    // ---- BN1 stats: per channel over (b, 4 pos) = 1024 ----
#pragma unroll
    for (int oc = 0; oc < 16; oc++) {
        float s = 0.f, ss = 0.f;
#pragma unroll
        for (int q = 0; q < 4; q++) { const float v = pooled[oc * 4 + q]; s += v; ss = fmaf(v, v, ss); }
        s = wred(s); ss = wred(ss);
        if (lane == 0) { sRed[wid][2 * oc] = s; sRed[wid][2 * oc + 1] = ss; }
    }
    __syncthreads();
    if (tid < 16) {
        const float s  = sRed[0][2 * tid] + sRed[1][2 * tid] + sRed[2][2 * tid] + sRed[3][2 * tid];
        const float ss = sRed[0][2 * tid + 1] + sRed[1][2 * tid + 1] + sRed[2][2 * tid + 1] + sRed[3][2 * tid + 1];
        const float m = s * (1.f / 1024.f);
        const float var = fmaf(-m, m, ss * (1.f / 1024.f));
        sM1[tid] = m; sS1[tid] = g1[tid] * rsqrtf(var + 1e-5f);
    }
    __syncthreads();
#pragma unroll
    for (int oc = 0; oc < 16; oc++) {
        const float m = sM1[oc], sc = sS1[oc], e = sE1[oc];
#pragma unroll
        for (int q = 0; q < 4; q++) pooled[oc * 4 + q] = fmaf(pooled[oc * 4 + q] - m, sc, e);
    }

    // ---- conv2 (16ch x 4pos -> 32) + relu, register-blocked JB=8 ----
    float h2v[32];
#pragma unroll
    for (int og = 0; og < 4; og++) {
        float acc[8];
#pragma unroll
        for (int jj = 0; jj < 8; jj++) acc[jj] = sB2[og * 8 + jj];
#pragma unroll 2
        for (int ic = 0; ic < 16; ic++) {
#pragma unroll
            for (int jj = 0; jj < 8; jj++) {
                const float4 wv = *(const float4*)&sWc2[(og * 8 + jj) * 64 + ic * 4];
                acc[jj] = FMA4(pooled[ic*4+0], pooled[ic*4+1], pooled[ic*4+2], pooled[ic*4+3], wv, acc[jj]);
            }
        }
#pragma unroll
        for (int jj = 0; jj < 8; jj++) h2v[og * 8 + jj] = fmaxf(acc[jj], 0.f);
    }

    // ---- BN2: per-channel over b ----
#pragma unroll
    for (int oc = 0; oc < 32; oc++) {
        float s = wred(h2v[oc]), ss = wred(h2v[oc] * h2v[oc]);
        if (lane == 0) { sRed[wid][2 * (oc & 15) + 32 * (oc >> 4)] = s; }
        // need both s and ss: pack per-16 to stay in 64 slots; simpler: two rounds below
        if (lane == 0) { /* placeholder */ }
        // NOTE: handled via second buffer pass below
        (void)ss;
    }
    // simpler correct path: redo with explicit two-pass staging
    __syncthreads();
#pragma unroll
    for (int half = 0; half < 2; half++) {
#pragma unroll
        for (int oc16 = 0; oc16 < 16; oc16++) {
            const int oc = half * 16 + oc16;
            float s = wred(h2v[oc]), ss = wred(h2v[oc] * h2v[oc]);
            if (lane == 0) { sRed[wid][2 * oc16] = s; sRed[wid][2 * oc16 + 1] = ss; }
        }
        __syncthreads();
        if (tid < 16) {
            const int oc = half * 16 + tid;
            const float s  = sRed[0][2 * tid] + sRed[1][2 * tid] + sRed[2][2 * tid] + sRed[3][2 * tid];
            const float ss = sRed[0][2 * tid + 1] + sRed[1][2 * tid + 1] + sRed[2][2 * tid + 1] + sRed[3][2 * tid + 1];
            const float m = s * (1.f / 256.f);
            const float var = fmaf(-m, m, ss * (1.f / 256.f));
            sM2[oc] = m; sS2[oc] = g2[oc] * rsqrtf(var + 1e-5f);
        }
        __syncthreads();
    }
#pragma unroll
    for (int oc = 0; oc < 32; oc++) h2v[oc] = fmaf(h2v[oc] - sM2[oc], sS2[oc], sE2[oc]);

    // ---- zm / zs heads (32 -> 16 each) ----
    const int obase_m = (t < 256) ? (O_ZM_OBS + (t * 256 + b) * 16) : (O_ZM_PRED + ((t - 256) * 256 + b) * 16);
    const int obase_s = (t < 256) ? (O_ZS_OBS + (t * 256 + b) * 16) : (O_ZS_PRED + ((t - 256) * 256 + b) * 16);
#pragma unroll 2
    for (int k = 0; k < 16; k++) {
        float vm = sBzm[k], vs = sBzs[k];
#pragma unroll
        for (int c = 0; c < 32; c += 4) {
            const float4 wm = *(const float4*)&sWzm[k * 32 + c];
            const float4 wsq = *(const float4*)&sWzs[k * 32 + c];
            vm = FMA4(h2v[c], h2v[c + 1], h2v[c + 2], h2v[c + 3], wm, vm);
            vs = FMA4(h2v[c], h2v[c + 1], h2v[c + 2], h2v[c + 3], wsq, vs);
        }
        out[obase_m + k] = vm;
        out[obase_s + k] = __expf(vs);
    }
}

// ==================== Kernel 2: z + fc1 + BN1 + fc2(g) + BN2 + convT1(g) stats ====================
// grid = 128: tp = bid>>2, quadrant g = bid&3
extern "C" __global__ void __launch_bounds__(256)
k_dec1(const float* __restrict__ eps,
       const float* __restrict__ Wd1,  const float* __restrict__ bd1,
       const float* __restrict__ gd1,  const float* __restrict__ bed1,
       const float* __restrict__ Wd2,  const float* __restrict__ bd2,
       const float* __restrict__ gd2,  const float* __restrict__ bed2,
       const float* __restrict__ Wt1,  const float* __restrict__ bt1,
       const float* __restrict__ out,  float* __restrict__ ws)
{
    const int tp = blockIdx.x >> 2, g = blockIdx.x & 3;
    const int tid = threadIdx.x, b = tid;
    const int wid = tid >> 6, lane = tid & 63;

    __shared__ __align__(16) float sWd1[1024];
    __shared__ __align__(16) float sWd2g[2048];   // rows j=4*ic+g, [ic][64]
    __shared__ __align__(16) float sWt1g[2048];   // [dp][oc][ic] for this g
    __shared__ __align__(16) float sM1[64], sS1[64], sE1[64];
    __shared__ float sBd1[64], sBd2g[32], sBt1[16];
    __shared__ float sRed[4][128];
    __shared__ float sM2[32], sS2[32], sE2[32];

    for (int i = tid; i < 1024; i += 256) sWd1[i] = Wd1[i];
    for (int i = tid; i < 2048; i += 256) {
        const int ic = i >> 6, k = i & 63;
        sWd2g[i] = Wd2[(4 * ic + g) * 64 + k];
    }
    for (int i = tid; i < 2048; i += 256) {
        const int dp = i >> 9, rem = i & 511, oc = rem >> 5, ic = i & 31;
        const int py = (g >> 1) * 2 + (dp >> 1), px = (g & 1) * 2 + (dp & 1);
        const int k9 = ((py + 1) % 3) * 3 + ((px + 1) % 3);
        sWt1g[(dp * 16 + oc) * 32 + ic] = Wt1[ic * 144 + oc * 9 + k9];
    }
    if (tid < 64) sBd1[tid] = bd1[tid];
    if (tid < 32) sBd2g[tid] = bd2[4 * tid + g];
    if (tid < 16) sBt1[tid] = bt1[tid];
    __syncthreads();

    // ---- z sample (4 named quads) ----
    float4 zA, zB, zC, zD;
    {
        const int base = (tp * 256 + b) * 16;
        const float4 e0 = *(const float4*)&eps[base + 0],  e1 = *(const float4*)&eps[base + 4];
        const float4 e2 = *(const float4*)&eps[base + 8],  e3 = *(const float4*)&eps[base + 12];
        const float4 s0v = *(const float4*)&out[O_ZS_PRED + base + 0],  s1v = *(const float4*)&out[O_ZS_PRED + base + 4];
        const float4 s2v = *(const float4*)&out[O_ZS_PRED + base + 8],  s3v = *(const float4*)&out[O_ZS_PRED + base + 12];
        const float4 m0 = *(const float4*)&out[O_ZM_PRED + base + 0],  m1 = *(const float4*)&out[O_ZM_PRED + base + 4];
        const float4 m2 = *(const float4*)&out[O_ZM_PRED + base + 8],  m3 = *(const float4*)&out[O_ZM_PRED + base + 12];
        zA = make_float4(fmaf(e0.x,s0v.x,m0.x), fmaf(e0.y,s0v.y,m0.y), fmaf(e0.z,s0v.z,m0.z), fmaf(e0.w,s0v.w,m0.w));
        zB = make_float4(fmaf(e1.x,s1v.x,m1.x), fmaf(e1.y,s1v.y,m1.y), fmaf(e1.z,s1v.z,m1.z), fmaf(e1.w,s1v.w,m1.w));
        zC = make_float4(fmaf(e2.x,s2v.x,m2.x), fmaf(e2.y,s2v.y,m2.y), fmaf(e2.z,s2v.z,m2.z), fmaf(e2.w,s2v.w,m2.w));
        zD = make_float4(fmaf(e3.x,s3v.x,m3.x), fmaf(e3.y,s3v.y,m3.y), fmaf(e3.z,s3v.z,m3.z), fmaf(e3.w,s3v.w,m3.w));
    }

    // ---- fc1 (16->64) + relu, h1 in registers ----
    float h1[64];
#pragma unroll 2
    for (int jg = 0; jg < 8; jg++) {
        const int j0 = jg * 8;
#pragma unroll
        for (int jj = 0; jj < 8; jj++) {
            const float4 wq0 = *(const float4*)&sWd1[(j0 + jj) * 16 + 0];
            const float4 wq1 = *(const float4*)&sWd1[(j0 + jj) * 16 + 4];
            const float4 wq2 = *(const float4*)&sWd1[(j0 + jj) * 16 + 8];
            const float4 wq3 = *(const float4*)&sWd1[(j0 + jj) * 16 + 12];
            float v = sBd1[j0 + jj];
            v = FMA4(zA.x, zA.y, zA.z, zA.w, wq0, v);
            v = FMA4(zB.x, zB.y, zB.z, zB.w, wq1, v);
            v = FMA4(zC.x, zC.y, zC.z, zC.w, wq2, v);
            v = FMA4(zD.x, zD.y, zD.z, zD.w, wq3, v);
            h1[j0 + jj] = fmaxf(v, 0.f);
        }
    }

    // ---- BN1: per channel over b (64 ch, wred in two 32-ch passes using sRed[4][128]) ----
#pragma unroll
    for (int j = 0; j < 64; j++) {
        float s = wred(h1[j]), ss = wred(h1[j] * h1[j]);
        if (lane == 0) { sRed[wid][2 * j] = s; sRed[wid][2 * j + 1] = ss; }
    }
    __syncthreads();
    if (tid < 64) {
        const float s  = sRed[0][2 * tid] + sRed[1][2 * tid] + sRed[2][2 * tid] + sRed[3][2 * tid];
        const float ss = sRed[0][2 * tid + 1] + sRed[1][2 * tid + 1] + sRed[2][2 * tid + 1] + sRed[3][2 * tid + 1];
        const float m = s * (1.f / 256.f);
        const float var = fmaf(-m, m, ss * (1.f / 256.f));
        sM1[tid] = m; sS1[tid] = gd1[tid] * rsqrtf(var + 1e-5f); sE1[tid] = bed1[tid];
    }
    __syncthreads();
#pragma unroll
    for (int j = 0; j < 64; j++) h1[j] = fmaf(h1[j] - sM1[j], sS1[j], sE1[j]);

    // ---- fc2 for this g only (32 channels: j = 4*ic+g) + relu ----
    float h2g[32];
#pragma unroll 1
    for (int icg = 0; icg < 4; icg++) {
        const int ic0 = icg * 8;
        float acc[8];
#pragma unroll
        for (int jj = 0; jj < 8; jj++) acc[jj] = sBd2g[ic0 + jj];
#pragma unroll 2
        for (int k4 = 0; k4 < 16; k4++) {
#pragma unroll
            for (int jj = 0; jj < 8; jj++) {
                const float4 wv = *(const float4*)&sWd2g[(ic0 + jj) * 64 + 4 * k4];
                acc[jj] = FMA4(h1[4*k4], h1[4*k4+1], h1[4*k4+2], h1[4*k4+3], wv, acc[jj]);
            }
        }
#pragma unroll
        for (int jj = 0; jj < 8; jj++) h2g[ic0 + jj] = fmaxf(acc[jj], 0.f);
    }

    // ---- BN2 for this g's 32 channels ----
#pragma unroll
    for (int ic = 0; ic < 32; ic++) {
        float s = wred(h2g[ic]), ss = wred(h2g[ic] * h2g[ic]);
        if (lane == 0) { sRed[wid][2 * ic] = s; sRed[wid][2 * ic + 1] = ss; }
    }
    __syncthreads();
    if (tid < 32) {
        const float s  = sRed[0][2 * tid] + sRed[1][2 * tid] + sRed[2][2 * tid] + sRed[3][2 * tid];
        const float ss = sRed[0][2 * tid + 1] + sRed[1][2 * tid + 1] + sRed[2][2 * tid + 1] + sRed[3][2 * tid + 1];
        const float m = s * (1.f / 256.f);
        const float var = fmaf(-m, m, ss * (1.f / 256.f));
        sM2[tid] = m;
        sS2[tid] = gd2[4 * tid + g] * rsqrtf(var + 1e-5f);
        sE2[tid] = bed2[4 * tid + g];
    }
    __syncthreads();
#pragma unroll
    for (int ic = 0; ic < 32; ic++) h2g[ic] = fmaf(h2g[ic] - sM2[ic], sS2[ic], sE2[ic]);

    // write normalized h2 for k_dec2's recompute
    {
        float* dst = ws + W_H2N + (((tp * 4 + g) * 256 + b) * 32);
#pragma unroll
        for (int ic = 0; ic < 32; ic += 4)
            *(float4*)&dst[ic] = make_float4(h2g[ic], h2g[ic + 1], h2g[ic + 2], h2g[ic + 3]);
    }

    // ---- convT1 for this g's 4 positions: BN3 partial stats only ----
    float ls[16], lss[16];
#pragma unroll
    for (int i = 0; i < 16; i++) { ls[i] = 0.f; lss[i] = 0.f; }
#pragma unroll 1
    for (int dp = 0; dp < 4; dp++) {
#pragma unroll
        for (int og = 0; og < 4; og++) {
            float acc[4];
#pragma unroll
            for (int jj = 0; jj < 4; jj++) acc[jj] = sBt1[og * 4 + jj];
#pragma unroll
            for (int i4 = 0; i4 < 8; i4++) {
#pragma unroll
                for (int jj = 0; jj < 4; jj++) {
                    const float4 wv = *(const float4*)&sWt1g[(dp * 16 + og * 4 + jj) * 32 + 4 * i4];
                    acc[jj] = FMA4(h2g[4*i4], h2g[4*i4+1], h2g[4*i4+2], h2g[4*i4+3], wv, acc[jj]);
                }
            }
#pragma unroll
            for (int jj = 0; jj < 4; jj++) {
                const float v = fmaxf(acc[jj], 0.f);
                ls[og * 4 + jj] += v; lss[og * 4 + jj] = fmaf(v, v, lss[og * 4 + jj]);
            }
        }
    }
#pragma unroll
    for (int oc = 0; oc < 16; oc++) {
        float s = wred(ls[oc]), ss = wred(lss[oc]);
        if (lane == 0) { sRed[wid][2 * oc] = s; sRed[wid][2 * oc + 1] = ss; }
    }
    __syncthreads();
    if (tid < 16) {
        const float s  = sRed[0][2 * tid] + sRed[1][2 * tid] + sRed[2][2 * tid] + sRed[3][2 * tid];
        const float ss = sRed[0][2 * tid + 1] + sRed[1][2 * tid + 1] + sRed[2][2 * tid + 1] + sRed[3][2 * tid + 1];
        ws[W_P3 + (tp * 4 + g) * 32 + 2 * tid + 0] = s;
        ws[W_P3 + (tp * 4 + g) * 32 + 2 * tid + 1] = ss;
    }
}

// ==================== Kernel 3: BN3 finalize + convT1 recompute + convT2 + nll ====================
// grid = 128: tp = bid>>2, quadrant g = bid&3
extern "C" __global__ void __launch_bounds__(256)
k_dec2(const float* __restrict__ x,    const int* __restrict__ pos,
       const float* __restrict__ Wt1,  const float* __restrict__ bt1,
       const float* __restrict__ gt1,  const float* __restrict__ bet1,
       const float* __restrict__ Wt2,  const float* __restrict__ bt2,
       float* __restrict__ out, const float* __restrict__ ws)
{
    const int tp = blockIdx.x >> 2, g = blockIdx.x & 3;
    const int tid = threadIdx.x, b = tid;
    const int wid = tid >> 6, lane = tid & 63;

    __shared__ __align__(16) float sWt1g[2048];   // [dp][oc][ic]
    __shared__ __align__(16) float sWt2[192];     // [(c*4+dy*2+dx)*16+ic]
    __shared__ float sBt1[16], sBt2[3];
    __shared__ float sRed[4][64];
    __shared__ float sM3[16], sS3[16], sE3[16];

    for (int i = tid; i < 2048; i += 256) {
        const int dp = i >> 9, rem = i & 511, oc = rem >> 5, ic = i & 31;
        const int py = (g >> 1) * 2 + (dp >> 1), px = (g & 1) * 2 + (dp & 1);
        const int k9 = ((py + 1) % 3) * 3 + ((px + 1) % 3);
        sWt1g[(dp * 16 + oc) * 32 + ic] = Wt1[ic * 144 + oc * 9 + k9];
    }
    if (tid < 192) { const int ic = tid / 12, r = tid % 12; sWt2[r * 16 + ic] = Wt2[tid]; }
    if (tid < 16) sBt1[tid] = bt1[tid];
    if (tid < 3) sBt2[tid] = bt2[tid];
    if (tid < 16) {
        float s = 0.f, ss = 0.f;
#pragma unroll
        for (int gg = 0; gg < 4; gg++) {
            s  += ws[W_P3 + (tp * 4 + gg) * 32 + 2 * tid + 0];
            ss += ws[W_P3 + (tp * 4 + gg) * 32 + 2 * tid + 1];
        }
        const float m = s * (1.f / 4096.f);
        const float var = fmaf(-m, m, ss * (1.f / 4096.f));
        sM3[tid] = m; sS3[tid] = gt1[tid] * rsqrtf(var + 1e-5f); sE3[tid] = bet1[tid];
    }
    __syncthreads();

    // load normalized h2 for (tp,g,b)
    float h2g[32];
    {
        const float* src = ws + W_H2N + (((tp * 4 + g) * 256 + b) * 32);
#pragma unroll
        for (int i4 = 0; i4 < 8; i4++) {
            const float4 v4 = *(const float4*)&src[4 * i4];
            h2g[4 * i4] = v4.x; h2g[4 * i4 + 1] = v4.y; h2g[4 * i4 + 2] = v4.z; h2g[4 * i4 + 3] = v4.w;
        }
    }

    const int t = 256 + tp;
    const int pr = 3 * pos[(b * 2 + 0) * 288 + t];
    const int pc = 3 * pos[(b * 2 + 1) * 288 + t];
    const float* xb = x + b * 3072;
    const int rbase = O_XREC + (tp * 256 + b) * 192;
    const int py0 = (g >> 1) * 2, px0 = (g & 1) * 2;
    float err = 0.f;

#pragma unroll 1
    for (int dp = 0; dp < 4; dp++) {
        const int py = py0 + (dp >> 1), px = px0 + (dp & 1);
        float hn[16];
#pragma unroll
        for (int og = 0; og < 4; og++) {
            float acc[4];
#pragma unroll
            for (int jj = 0; jj < 4; jj++) acc[jj] = sBt1[og * 4 + jj];
#pragma unroll
            for (int i4 = 0; i4 < 8; i4++) {
#pragma unroll
                for (int jj = 0; jj < 4; jj++) {
                    const float4 wv = *(const float4*)&sWt1g[(dp * 16 + og * 4 + jj) * 32 + 4 * i4];
                    acc[jj] = FMA4(h2g[4*i4], h2g[4*i4+1], h2g[4*i4+2], h2g[4*i4+3], wv, acc[jj]);
                }
            }
#pragma unroll
            for (int jj = 0; jj < 4; jj++) {
                const int oc = og * 4 + jj;
                hn[oc] = fmaf(fmaxf(acc[jj], 0.f) - sM3[oc], sS3[oc], sE3[oc]);
            }
        }
#pragma unroll
        for (int c = 0; c < 3; c++)
#pragma unroll
        for (int dy = 0; dy < 2; dy++)
#pragma unroll
        for (int dx = 0; dx < 2; dx++) {
            const float* wp = &sWt2[(c * 4 + dy * 2 + dx) * 16];
            float v = sBt2[c];
#pragma unroll
            for (int ic = 0; ic < 16; ic += 4) {
                const float4 wq = *(const float4*)&wp[ic];
                v = FMA4(hn[ic], hn[ic + 1], hn[ic + 2], hn[ic + 3], wq, v);
            }
            v = sigm(v);
            const int oy = 2 * py + dy, ox = 2 * px + dx;
            out[rbase + c * 64 + oy * 8 + ox] = v;
            const float d = v - xb[c * 1024 + (pr + oy) * 32 + (pc + ox)];
            err = fmaf(d, d, err);
        }
    }

    const float es = wred(err);
    if (lane == 0) sRed[wid][0] = es;
    __syncthreads();
    if (tid == 0)
        atomicAdd(&out[O_NLL], sRed[0][0] + sRed[1][0] + sRed[2][0] + sRed[3][0]);
}

// ==================== host ====================
extern "C" void kernel_launch(void* const* d_in, const int* in_sizes, int n_in,
                              void* d_out, int out_size, void* d_ws, size_t ws_size,
                              hipStream_t stream)
{
    const float* x    = (const float*)d_in[0];
    const float* act  = (const float*)d_in[1];
    const int*   pos  = (const int*)d_in[2];
    const float* s0   = (const float*)d_in[3];
    const float* nobs = (const float*)d_in[4];
    const float* nprd = (const float*)d_in[5];
    const float* eps  = (const float*)d_in[6];
    const float* Wa   = (const float*)d_in[7];
    const float* Ws1  = (const float*)d_in[8];
    const float* bs1  = (const float*)d_in[9];
    const float* Ws2  = (const float*)d_in[10];
    const float* bs2  = (const float*)d_in[11];
    const float* Wc1  = (const float*)d_in[12];
    const float* bc1  = (const float*)d_in[13];
    const float* g1   = (const float*)d_in[14];
    const float* be1  = (const float*)d_in[15];
    const float* Wc2  = (const float*)d_in[16];
    const float* bc2  = (const float*)d_in[17];
    const float* g2   = (const float*)d_in[18];
    const float* be2  = (const float*)d_in[19];
    const float* Wzm  = (const float*)d_in[20];
    const float* bzm  = (const float*)d_in[21];
    const float* Wzs  = (const float*)d_in[22];
    const float* bzs  = (const float*)d_in[23];
    const float* Wd1  = (const float*)d_in[24];
    const float* bd1  = (const float*)d_in[25];
    const float* gd1  = (const float*)d_in[26];
    const float* bed1 = (const float*)d_in[27];
    const float* Wd2  = (const float*)d_in[28];
    const float* bd2  = (const float*)d_in[29];
    const float* gd2  = (const float*)d_in[30];
    const float* bed2 = (const float*)d_in[31];
    const float* Wt1  = (const float*)d_in[32];
    const float* bt1  = (const float*)d_in[33];
    const float* gt1  = (const float*)d_in[34];
    const float* bet1 = (const float*)d_in[35];
    const float* Wt2  = (const float*)d_in[36];
    const float* bt2  = (const float*)d_in[37];
    float* out = (float*)d_out;
    float* ws  = (float*)d_ws;

    k_pre<<<dim3(256), dim3(288), 0, stream>>>(act, Wa, ws);

    k_enc_rec<<<dim3(289), dim3(256), 0, stream>>>(
        x, pos, s0, nobs, nprd, Ws1, bs1, Ws2, bs2,
        Wc1, bc1, g1, be1, Wc2, bc2, g2, be2, Wzm, bzm, Wzs, bzs, ws, out);

    k_dec1<<<dim3(128), dim3(256), 0, stream>>>(
        eps, Wd1, bd1, gd1, bed1, Wd2, bd2, gd2, bed2, Wt1, bt1, out, ws);

    k_dec2<<<dim3(128), dim3(256), 0, stream>>>(
        x, pos, Wt1, bt1, gt1, bet1, Wt2, bt2, out, ws);
}

// Round 6
// 405.193 us; speedup vs baseline: 1.2286x; 1.2286x over previous
//
#include <hip/hip_runtime.h>
#include <hip/hip_bf16.h>
#include <math.h>

// ---------------- problem constants ----------------
#define NB   256
#define NT   288
#define NOBS 256
#define NTP  32

// output offsets (floats)
#define O_ST_OBS   0
#define O_ST_PRED  131072
#define O_ZM_OBS   147456
#define O_ZS_OBS   1196032
#define O_ZM_PRED  2244608
#define O_ZS_PRED  2375680
#define O_XREC     2506752
#define O_NLL      4079616

#define POOL_FLOATS ((size_t)288 * 256 * 64)   // 4,718,592 floats = 18.9 MB

__device__ __forceinline__ float wred(float v) {
    v += __shfl_down(v, 32); v += __shfl_down(v, 16); v += __shfl_down(v, 8);
    v += __shfl_down(v, 4);  v += __shfl_down(v, 2);  v += __shfl_down(v, 1);
    return v;
}
__device__ __forceinline__ float sigm(float x) { return 1.0f / (1.0f + __expf(-x)); }
__device__ __forceinline__ float tanh_f(float x) {
    x = fminf(fmaxf(x, -15.0f), 15.0f);
    float e = __expf(2.0f * x);
    return (e - 1.0f) / (e + 1.0f);
}
// NOTE: no macro parameter may be named x/y/z/w (member-access collision!)
#define FMA4(ax,ay,az,aw,wv,acc) fmaf((ax),(wv).x,fmaf((ay),(wv).y,fmaf((az),(wv).z,fmaf((aw),(wv).w,(acc)))))

// ==================== recurrence (device fn; one 256-thread block, thread = b) ====================
__device__ __forceinline__ void run_recurrence(
    int b, const float* __restrict__ s0,
    const float* __restrict__ nobs, const float* __restrict__ npred,
    const float* __restrict__ Ws1, const float* __restrict__ bs1,
    const float* __restrict__ Ws2, const float* __restrict__ bs2,
    const float* __restrict__ ws_u, float* __restrict__ out)
{
    float w1[10], w2[10], c1[5], c2_0, c2_1;
#pragma unroll
    for (int i = 0; i < 10; i++) { w1[i] = Ws1[i]; w2[i] = Ws2[i]; }
#pragma unroll
    for (int i = 0; i < 5; i++) c1[i] = bs1[i];
    c2_0 = bs2[0]; c2_1 = bs2[1];

    float sv0 = s0[b * 2 + 0], sv1 = s0[b * 2 + 1];
    ((float2*)(out + O_ST_OBS))[b] = make_float2(sv0, sv1);
    if (b == 0) out[O_NLL] = 0.0f;   // re-zeroed every call; stream-ordered before k_dec2

    const float2* Up   = (const float2*)ws_u;
    const float2* Nobs = (const float2*)nobs;
    const float2* Nprd = (const float2*)npred;

    float2 u  = Up[256 + b];
    float2 nz = Nobs[b];

    for (int t = 1; t < 288; t++) {
        float2 u_n = make_float2(0.f, 0.f), nz_n = make_float2(0.f, 0.f);
        if (t < 287) {
            u_n = Up[(t + 1) * 256 + b];
            const float2* np = (t + 1 < 256) ? (Nobs + t * 256 + b)
                                             : (Nprd + (t - 255) * 256 + b);
            nz_n = *np;
        }
        const float v0 = sv0 + u.x, v1 = sv1 + u.y;
        float h[5];
#pragma unroll
        for (int j = 0; j < 5; j++)
            h[j] = tanh_f(fmaf(v1, w1[j * 2 + 1], fmaf(v0, w1[j * 2 + 0], c1[j])));
        float a0 = fmaf(h[0], w2[0], fmaf(h[1], w2[1], c2_0));
        float a0b = fmaf(h[2], w2[2], h[3] * w2[3]);
        a0 = fmaf(h[4], w2[4], a0 + a0b);
        float a1 = fmaf(h[0], w2[5], fmaf(h[1], w2[6], c2_1));
        float a1b = fmaf(h[2], w2[7], h[3] * w2[8]);
        a1 = fmaf(h[4], w2[9], a1 + a1b);

        sv0 = fmaf(u.x, sigm(a0), sv0) + nz.x;
        sv1 = fmaf(u.y, sigm(a1), sv1) + nz.y;

        if (t < 256) ((float2*)(out + O_ST_OBS))[t * 256 + b] = make_float2(sv0, sv1);
        else         ((float2*)(out + O_ST_PRED))[(t - 256) * 256 + b] = make_float2(sv0, sv1);

        u = u_n; nz = nz_n;
    }
}

// ==================== Kernel 0: U[t][b][2] = act^T . Wa ====================
extern "C" __global__ void __launch_bounds__(288)
k_pre(const float* __restrict__ act, const float* __restrict__ Wa, float* __restrict__ ws_u)
{
    const int b = blockIdx.x;     // 0..255
    const int t = threadIdx.x;    // 0..287
    float u0 = 0.f, u1 = 0.f;
#pragma unroll
    for (int a = 0; a < 5; a++) {
        const float av = act[(b * 5 + a) * 288 + t];
        u0 = fmaf(av, Wa[a], u0);
        u1 = fmaf(av, Wa[5 + a], u1);
    }
    ws_u[(t * 256 + b) * 2 + 0] = u0;
    ws_u[(t * 256 + b) * 2 + 1] = u1;
}

// ==================== Kernel 1a (fast path): per-batch patch conv1+maxpool ====================
// grid 257: blocks 0..255 = batch b (image in LDS), block 256 = recurrence
extern "C" __global__ void __launch_bounds__(256)
k_patch(const float* __restrict__ x, const int* __restrict__ pos,
        const float* __restrict__ s0, const float* __restrict__ nobs,
        const float* __restrict__ npred,
        const float* __restrict__ Ws1, const float* __restrict__ bs1,
        const float* __restrict__ Ws2, const float* __restrict__ bs2,
        const float* __restrict__ Wc1, const float* __restrict__ bc1,
        const float* __restrict__ ws_u, float* __restrict__ ws_pool,
        float* __restrict__ out)
{
    const int tid = threadIdx.x;
    if (blockIdx.x == 256) {
        run_recurrence(tid, s0, nobs, npred, Ws1, bs1, Ws2, bs2, ws_u, out);
        return;
    }
    const int b = blockIdx.x;
    __shared__ __align__(16) float sImg[3072];
    __shared__ __align__(16) float sWc1[192];
    __shared__ float sB1[16];

    {
        const float4* x4 = (const float4*)(x + b * 3072);
        float4* s4 = (float4*)sImg;
        for (int i = tid; i < 768; i += 256) s4[i] = x4[i];
        if (tid < 192) sWc1[tid] = Wc1[tid];
        if (tid < 16) sB1[tid] = bc1[tid];
    }
    __syncthreads();

#pragma unroll 1
    for (int t = tid; t < 288; t += 256) {
        const int pr = 3 * pos[(b * 2 + 0) * 288 + t];
        const int pc = 3 * pos[(b * 2 + 1) * 288 + t];
        float4* dst = (float4*)(ws_pool + ((size_t)t * 256 + b) * 64);
#pragma unroll
        for (int py = 0; py < 2; py++)
#pragma unroll
        for (int px = 0; px < 2; px++) {
            float p16[16];
#pragma unroll
            for (int i = 0; i < 16; i++) p16[i] = 0.f;   // relu >= 0 => 0-init == true max
#pragma unroll 2
            for (int d = 0; d < 4; d++) {
                const int rbase = pr + 4 * py + 2 * (d >> 1);
                const int cbase = pc + 4 * px + 2 * (d & 1);
                float in[12];
#pragma unroll
                for (int ic = 0; ic < 3; ic++)
#pragma unroll
                for (int ky = 0; ky < 2; ky++)
#pragma unroll
                for (int kx = 0; kx < 2; kx++)
                    in[ic * 4 + ky * 2 + kx] = sImg[ic * 1024 + (rbase + ky) * 32 + (cbase + kx)];
#pragma unroll
                for (int oc = 0; oc < 16; oc++) {
                    const float4 wq0 = *(const float4*)&sWc1[oc * 12 + 0];
                    const float4 wq1 = *(const float4*)&sWc1[oc * 12 + 4];
                    const float4 wq2 = *(const float4*)&sWc1[oc * 12 + 8];
                    float v = sB1[oc];
                    v = FMA4(in[0], in[1], in[2], in[3], wq0, v);
                    v = FMA4(in[4], in[5], in[6], in[7], wq1, v);
                    v = FMA4(in[8], in[9], in[10], in[11], wq2, v);
                    p16[oc] = fmaxf(p16[oc], fmaxf(v, 0.f));
                }
            }
            const int q0 = (py * 2 + px) * 4;   // float4 index base: pos*16 floats
            dst[q0 + 0] = make_float4(p16[0], p16[1], p16[2], p16[3]);
            dst[q0 + 1] = make_float4(p16[4], p16[5], p16[6], p16[7]);
            dst[q0 + 2] = make_float4(p16[8], p16[9], p16[10], p16[11]);
            dst[q0 + 3] = make_float4(p16[12], p16[13], p16[14], p16[15]);
        }
    }
}

// ==================== Kernel 1b (fast path): BN1 + conv2 + BN2 + heads ====================
// grid 288: block = timestep t; thread = batch b. pooled row layout: [pos(4)][ch(16)]
extern "C" __global__ void __launch_bounds__(256)
k_enc(const float* __restrict__ g1,   const float* __restrict__ be1,
      const float* __restrict__ Wc2,  const float* __restrict__ bc2,
      const float* __restrict__ g2,   const float* __restrict__ be2,
      const float* __restrict__ Wzm,  const float* __restrict__ bzm,
      const float* __restrict__ Wzs,  const float* __restrict__ bzs,
      const float* __restrict__ ws_pool, float* __restrict__ out)
{
    const int t = blockIdx.x, tid = threadIdx.x, b = tid;
    const int wid = tid >> 6, lane = tid & 63;

    __shared__ __align__(16) float pooledL[256 * 68];   // [b][pos*16+ch], stride 68
    __shared__ __align__(16) float sWc2r[2048];          // remapped [oc][q][ic]
    __shared__ __align__(16) float sWzm[512];
    __shared__ __align__(16) float sWzs[512];
    __shared__ __align__(16) float sM1[16], sS1[16], sE1[16];
    __shared__ float sB2[32], sE2[32], sBzm[16], sBzs[16];
    __shared__ float sM2[32], sS2[32];
    __shared__ float sRed[4][64];

    for (int i = tid; i < 2048; i += 256) {
        const int oc = i >> 6, rem = i & 63, ic = rem >> 2, q = rem & 3;
        sWc2r[oc * 64 + q * 16 + ic] = Wc2[i];
    }
    for (int i = tid; i < 512; i += 256) { sWzm[i] = Wzm[i]; sWzs[i] = Wzs[i]; }
    if (tid < 16) { sE1[tid] = be1[tid]; sBzm[tid] = bzm[tid]; sBzs[tid] = bzs[tid]; }
    if (tid < 32) { sB2[tid] = bc2[tid]; sE2[tid] = be2[tid]; }

    // load my pooled row (64 floats, [pos][ch]) from ws
    float* myrow = &pooledL[b * 68];
    {
        const float4* src = (const float4*)(ws_pool + ((size_t)t * 256 + b) * 64);
#pragma unroll
        for (int q = 0; q < 16; q++) *(float4*)&myrow[4 * q] = src[q];
    }
    __syncthreads();

    // ---- BN1 stats: per channel over (b, 4 pos) = 1024; column partial sums ----
    {
        const int col = tid & 63, q = tid >> 6;
        float s = 0.f, ss = 0.f;
        const float* cp = &pooledL[(q * 64) * 68 + col];
#pragma unroll 4
        for (int i = 0; i < 64; i++) { const float v = cp[i * 68]; s += v; ss = fmaf(v, v, ss); }
        sRed[q][2 * (col & 31)] = 0.f;  // no-op placeholder avoided; direct write below
        // store into per-quarter slots: col indexes 0..63 -> use two banks of sRed rows
    }
    __syncthreads();
    // redo staging cleanly: column partials stored in pooledL's tail is messy; use direct approach:
    {
        const int col = tid & 63, q = tid >> 6;
        float s = 0.f, ss = 0.f;
        const float* cp = &pooledL[(q * 64) * 68 + col];
#pragma unroll 4
        for (int i = 0; i < 64; i++) { const float v = cp[i * 68]; s += v; ss = fmaf(v, v, ss); }
        // reduce the 4 pos-columns of each channel via LDS: sRed[q][...] holds (s,ss) for col
        // pack: channel = col & 15, pos = col >> 4
        // first accumulate (s,ss) for this col into sRed[q]
        sRed[q][col] = s;
        __syncthreads();
        float ssum = 0.f;
        if (tid < 16) {
#pragma unroll
            for (int p = 0; p < 4; p++)
#pragma unroll
            for (int qq = 0; qq < 4; qq++) ssum += sRed[qq][p * 16 + tid];
        }
        __syncthreads();
        sRed[q][col] = ss;
        __syncthreads();
        if (tid < 16) {
            float sssum = 0.f;
#pragma unroll
            for (int p = 0; p < 4; p++)
#pragma unroll
            for (int qq = 0; qq < 4; qq++) sssum += sRed[qq][p * 16 + tid];
            const float m = ssum * (1.f / 1024.f);
            const float var = fmaf(-m, m, sssum * (1.f / 1024.f));
            sM1[tid] = m; sS1[tid] = g1[tid] * rsqrtf(var + 1e-5f);
        }
    }
    __syncthreads();

    // ---- normalize own row (quad tq: ch-quad = tq&3) ----
#pragma unroll 4
    for (int tq = 0; tq < 16; tq++) {
        const int ic0 = (tq & 3) * 4;
        float4 v = *(float4*)&myrow[4 * tq];
        const float4 mq = *(const float4*)&sM1[ic0];
        const float4 sq = *(const float4*)&sS1[ic0];
        const float4 eq = *(const float4*)&sE1[ic0];
        v.x = fmaf(v.x - mq.x, sq.x, eq.x);
        v.y = fmaf(v.y - mq.y, sq.y, eq.y);
        v.z = fmaf(v.z - mq.z, sq.z, eq.z);
        v.w = fmaf(v.w - mq.w, sq.w, eq.w);
        *(float4*)&myrow[4 * tq] = v;
    }

    // ---- conv2 (16ch x 4pos -> 32) + relu, register-blocked JB=8 ----
    float h2v[32];
#pragma unroll
    for (int og = 0; og < 4; og++) {
        float acc[8];
#pragma unroll
        for (int jj = 0; jj < 8; jj++) acc[jj] = sB2[og * 8 + jj];
#pragma unroll 2
        for (int tq = 0; tq < 16; tq++) {
            const float4 hq = *(const float4*)&myrow[4 * tq];
#pragma unroll
            for (int jj = 0; jj < 8; jj++) {
                const float4 wv = *(const float4*)&sWc2r[(og * 8 + jj) * 64 + 4 * tq];
                acc[jj] = FMA4(hq.x, hq.y, hq.z, hq.w, wv, acc[jj]);
            }
        }
#pragma unroll
        for (int jj = 0; jj < 8; jj++) h2v[og * 8 + jj] = fmaxf(acc[jj], 0.f);
    }

    // ---- BN2: per-channel over b (single-pass wred; 32ch -> 64 slots) ----
#pragma unroll
    for (int oc = 0; oc < 32; oc++) {
        float s = wred(h2v[oc]), ss = wred(h2v[oc] * h2v[oc]);
        if (lane == 0) { sRed[wid][2 * oc] = s; sRed[wid][2 * oc + 1] = ss; }
    }
    __syncthreads();
    if (tid < 32) {
        const float s  = sRed[0][2 * tid] + sRed[1][2 * tid] + sRed[2][2 * tid] + sRed[3][2 * tid];
        const float ss = sRed[0][2 * tid + 1] + sRed[1][2 * tid + 1] + sRed[2][2 * tid + 1] + sRed[3][2 * tid + 1];
        const float m = s * (1.f / 256.f);
        const float var = fmaf(-m, m, ss * (1.f / 256.f));
        sM2[tid] = m; sS2[tid] = g2[tid] * rsqrtf(var + 1e-5f);
    }
    __syncthreads();
#pragma unroll
    for (int oc = 0; oc < 32; oc++) h2v[oc] = fmaf(h2v[oc] - sM2[oc], sS2[oc], sE2[oc]);

    // ---- zm / zs heads (32 -> 16 each) ----
    const int obase_m = (t < 256) ? (O_ZM_OBS + (t * 256 + b) * 16) : (O_ZM_PRED + ((t - 256) * 256 + b) * 16);
    const int obase_s = (t < 256) ? (O_ZS_OBS + (t * 256 + b) * 16) : (O_ZS_PRED + ((t - 256) * 256 + b) * 16);
#pragma unroll 2
    for (int k = 0; k < 16; k++) {
        float vm = sBzm[k], vs = sBzs[k];
#pragma unroll
        for (int c = 0; c < 32; c += 4) {
            const float4 wm = *(const float4*)&sWzm[k * 32 + c];
            const float4 wsq = *(const float4*)&sWzs[k * 32 + c];
            vm = FMA4(h2v[c], h2v[c + 1], h2v[c + 2], h2v[c + 3], wm, vm);
            vs = FMA4(h2v[c], h2v[c + 1], h2v[c + 2], h2v[c + 3], wsq, vs);
        }
        out[obase_m + k] = vm;
        out[obase_s + k] = __expf(vs);
    }
}

// ==================== Kernel 1 (fallback): fused encoder with global gathers (R4-proven) ====================
extern "C" __global__ void __launch_bounds__(256)
k_enc_full(const float* __restrict__ x,
           const int*   __restrict__ pos,  const float* __restrict__ s0,
           const float* __restrict__ nobs, const float* __restrict__ npred,
           const float* __restrict__ Ws1,  const float* __restrict__ bs1,
           const float* __restrict__ Ws2,  const float* __restrict__ bs2,
           const float* __restrict__ Wc1,  const float* __restrict__ bc1,
           const float* __restrict__ g1,   const float* __restrict__ be1,
           const float* __restrict__ Wc2,  const float* __restrict__ bc2,
           const float* __restrict__ g2,   const float* __restrict__ be2,
           const float* __restrict__ Wzm,  const float* __restrict__ bzm,
           const float* __restrict__ Wzs,  const float* __restrict__ bzs,
           const float* __restrict__ ws_u, float* __restrict__ out)
{
    const int tid = threadIdx.x;
    if (blockIdx.x == 0) {
        run_recurrence(tid, s0, nobs, npred, Ws1, bs1, Ws2, bs2, ws_u, out);
        return;
    }
    const int t = blockIdx.x - 1;
    __shared__ __align__(16) float sWc1[192];
    __shared__ __align__(16) float sWc2r[2048];
    __shared__ __align__(16) float sWzm[512];
    __shared__ __align__(16) float sWzs[512];
    __shared__ __align__(16) float sM1[16], sS1[16], sE1[16];
    __shared__ float sB1[16], sB2[32], sE2[32], sBzm[16], sBzs[16];
    __shared__ float sM2[32], sS2[32];
    __shared__ float sRed[4][64];
    __shared__ __align__(16) float pooledL[256 * 68];

    for (int i = tid; i < 192; i += 256) sWc1[i] = Wc1[i];
    for (int i = tid; i < 2048; i += 256) {
        const int oc = i >> 6, rem = i & 63, ic = rem >> 2, q = rem & 3;
        sWc2r[oc * 64 + q * 16 + ic] = Wc2[i];
    }
    for (int i = tid; i < 512; i += 256) { sWzm[i] = Wzm[i]; sWzs[i] = Wzs[i]; }
    if (tid < 16) { sB1[tid] = bc1[tid]; sE1[tid] = be1[tid]; sBzm[tid] = bzm[tid]; sBzs[tid] = bzs[tid]; }
    if (tid < 32) { sB2[tid] = bc2[tid]; sE2[tid] = be2[tid]; }
    __syncthreads();

    const int b = tid;
    const int wid = tid >> 6, lane = tid & 63;
    const float* xb = x + b * 3072;
    const int pr = 3 * pos[(b * 2 + 0) * 288 + t];
    const int pc = 3 * pos[(b * 2 + 1) * 288 + t];
    float* myrow = &pooledL[b * 68];

#pragma unroll
    for (int py = 0; py < 2; py++)
#pragma unroll
    for (int px = 0; px < 2; px++) {
        float p16[16];
#pragma unroll
        for (int i = 0; i < 16; i++) p16[i] = 0.f;
#pragma unroll 2
        for (int d = 0; d < 4; d++) {
            const int rbase = pr + 4 * py + 2 * (d >> 1);
            const int cbase = pc + 4 * px + 2 * (d & 1);
            float in[12];
#pragma unroll
            for (int ic = 0; ic < 3; ic++)
#pragma unroll
            for (int ky = 0; ky < 2; ky++)
#pragma unroll
            for (int kx = 0; kx < 2; kx++)
                in[ic * 4 + ky * 2 + kx] = xb[ic * 1024 + (rbase + ky) * 32 + (cbase + kx)];
#pragma unroll
            for (int oc = 0; oc < 16; oc++) {
                const float4 wq0 = *(const float4*)&sWc1[oc * 12 + 0];
                const float4 wq1 = *(const float4*)&sWc1[oc * 12 + 4];
                const float4 wq2 = *(const float4*)&sWc1[oc * 12 + 8];
                float v = sB1[oc];
                v = FMA4(in[0], in[1], in[2], in[3], wq0, v);
                v = FMA4(in[4], in[5], in[6], in[7], wq1, v);
                v = FMA4(in[8], in[9], in[10], in[11], wq2, v);
                p16[oc] = fmaxf(p16[oc], fmaxf(v, 0.f));
            }
        }
        const int pbase = (py * 2 + px) * 16;
        *(float4*)&myrow[pbase + 0]  = make_float4(p16[0], p16[1], p16[2], p16[3]);
        *(float4*)&myrow[pbase + 4]  = make_float4(p16[4], p16[5], p16[6], p16[7]);
        *(float4*)&myrow[pbase + 8]  = make_float4(p16[8], p16[9], p16[10], p16[11]);
        *(float4*)&myrow[pbase + 12] = make_float4(p16[12], p16[13], p16[14], p16[15]);
    }
    __syncthreads();

    // BN1 column partials (two LDS rounds via sRed[4][64])
    {
        const int col = tid & 63, q = tid >> 6;
        float s = 0.f, ss = 0.f;
        const float* cp = &pooledL[(q * 64) * 68 + col];
#pragma unroll 4
        for (int i = 0; i < 64; i++) { const float v = cp[i * 68]; s += v; ss = fmaf(v, v, ss); }
        sRed[q][col] = s;
        __syncthreads();
        float ssum = 0.f;
        if (tid < 16) {
#pragma unroll
            for (int p = 0; p < 4; p++)
#pragma unroll
            for (int qq = 0; qq < 4; qq++) ssum += sRed[qq][p * 16 + tid];
        }
        __syncthreads();
        sRed[q][col] = ss;
        __syncthreads();
        if (tid < 16) {
            float sssum = 0.f;
#pragma unroll
            for (int p = 0; p < 4; p++)
#pragma unroll
            for (int qq = 0; qq < 4; qq++) sssum += sRed[qq][p * 16 + tid];
            const float m = ssum * (1.f / 1024.f);
            const float var = fmaf(-m, m, sssum * (1.f / 1024.f));
            sM1[tid] = m; sS1[tid] = g1[tid] * rsqrtf(var + 1e-5f);
        }
    }
    __syncthreads();

#pragma unroll 4
    for (int tq = 0; tq < 16; tq++) {
        const int ic0 = (tq & 3) * 4;
        float4 v = *(float4*)&myrow[4 * tq];
        const float4 mq = *(const float4*)&sM1[ic0];
        const float4 sq = *(const float4*)&sS1[ic0];
        const float4 eq = *(const float4*)&sE1[ic0];
        v.x = fmaf(v.x - mq.x, sq.x, eq.x);
        v.y = fmaf(v.y - mq.y, sq.y, eq.y);
        v.z = fmaf(v.z - mq.z, sq.z, eq.z);
        v.w = fmaf(v.w - mq.w, sq.w, eq.w);
        *(float4*)&myrow[4 * tq] = v;
    }

    float h2v[32];
#pragma unroll
    for (int og = 0; og < 4; og++) {
        float acc[8];
#pragma unroll
        for (int jj = 0; jj < 8; jj++) acc[jj] = sB2[og * 8 + jj];
#pragma unroll 2
        for (int tq = 0; tq < 16; tq++) {
            const float4 hq = *(const float4*)&myrow[4 * tq];
#pragma unroll
            for (int jj = 0; jj < 8; jj++) {
                const float4 wv = *(const float4*)&sWc2r[(og * 8 + jj) * 64 + 4 * tq];
                acc[jj] = FMA4(hq.x, hq.y, hq.z, hq.w, wv, acc[jj]);
            }
        }
#pragma unroll
        for (int jj = 0; jj < 8; jj++) h2v[og * 8 + jj] = fmaxf(acc[jj], 0.f);
    }

#pragma unroll
    for (int oc = 0; oc < 32; oc++) {
        float s = wred(h2v[oc]), ss = wred(h2v[oc] * h2v[oc]);
        if (lane == 0) { sRed[wid][2 * oc] = s; sRed[wid][2 * oc + 1] = ss; }
    }
    __syncthreads();
    if (tid < 32) {
        const float s  = sRed[0][2 * tid] + sRed[1][2 * tid] + sRed[2][2 * tid] + sRed[3][2 * tid];
        const float ss = sRed[0][2 * tid + 1] + sRed[1][2 * tid + 1] + sRed[2][2 * tid + 1] + sRed[3][2 * tid + 1];
        const float m = s * (1.f / 256.f);
        const float var = fmaf(-m, m, ss * (1.f / 256.f));
        sM2[tid] = m; sS2[tid] = g2[tid] * rsqrtf(var + 1e-5f);
    }
    __syncthreads();
#pragma unroll
    for (int oc = 0; oc < 32; oc++) h2v[oc] = fmaf(h2v[oc] - sM2[oc], sS2[oc], sE2[oc]);

    const int obase_m = (t < 256) ? (O_ZM_OBS + (t * 256 + b) * 16) : (O_ZM_PRED + ((t - 256) * 256 + b) * 16);
    const int obase_s = (t < 256) ? (O_ZS_OBS + (t * 256 + b) * 16) : (O_ZS_PRED + ((t - 256) * 256 + b) * 16);
#pragma unroll 2
    for (int k = 0; k < 16; k++) {
        float vm = sBzm[k], vs = sBzs[k];
#pragma unroll
        for (int c = 0; c < 32; c += 4) {
            const float4 wm = *(const float4*)&sWzm[k * 32 + c];
            const float4 wsq = *(const float4*)&sWzs[k * 32 + c];
            vm = FMA4(h2v[c], h2v[c + 1], h2v[c + 2], h2v[c + 3], wm, vm);
            vs = FMA4(h2v[c], h2v[c + 1], h2v[c + 2], h2v[c + 3], wsq, vs);
        }
        out[obase_m + k] = vm;
        out[obase_s + k] = __expf(vs);
    }
}

// ==================== Kernel 2: z + fc1 + BN1 + fc2(g) + BN2 + convT1(g) stats ====================
// grid = 128: tp = bid>>2, quadrant g = bid&3
extern "C" __global__ void __launch_bounds__(256)
k_dec1(const float* __restrict__ eps,
       const float* __restrict__ Wd1,  const float* __restrict__ bd1,
       const float* __restrict__ gd1,  const float* __restrict__ bed1,
       const float* __restrict__ Wd2,  const float* __restrict__ bd2,
       const float* __restrict__ gd2,  const float* __restrict__ bed2,
       const float* __restrict__ Wt1,  const float* __restrict__ bt1,
       const float* __restrict__ out,
       float* __restrict__ ws_h2n, float* __restrict__ ws_p3)
{
    const int tp = blockIdx.x >> 2, g = blockIdx.x & 3;
    const int tid = threadIdx.x, b = tid;
    const int wid = tid >> 6, lane = tid & 63;

    __shared__ __align__(16) float sWd1[1024];
    __shared__ __align__(16) float sWd2g[2048];
    __shared__ __align__(16) float sWt1g[2048];
    __shared__ __align__(16) float sM1[64], sS1[64], sE1[64];
    __shared__ float sBd1[64], sBd2g[32], sBt1[16];
    __shared__ float sRed[4][128];
    __shared__ float sM2[32], sS2[32], sE2[32];

    for (int i = tid; i < 1024; i += 256) sWd1[i] = Wd1[i];
    for (int i = tid; i < 2048; i += 256) {
        const int ic = i >> 6, k = i & 63;
        sWd2g[i] = Wd2[(4 * ic + g) * 64 + k];
    }
    for (int i = tid; i < 2048; i += 256) {
        const int dp = i >> 9, rem = i & 511, oc = rem >> 5, ic = i & 31;
        const int py = (g >> 1) * 2 + (dp >> 1), px = (g & 1) * 2 + (dp & 1);
        const int k9 = ((py + 1) % 3) * 3 + ((px + 1) % 3);
        sWt1g[(dp * 16 + oc) * 32 + ic] = Wt1[ic * 144 + oc * 9 + k9];
    }
    if (tid < 64) sBd1[tid] = bd1[tid];
    if (tid < 32) sBd2g[tid] = bd2[4 * tid + g];
    if (tid < 16) sBt1[tid] = bt1[tid];
    __syncthreads();

    float4 zA, zB, zC, zD;
    {
        const int base = (tp * 256 + b) * 16;
        const float4 e0 = *(const float4*)&eps[base + 0],  e1 = *(const float4*)&eps[base + 4];
        const float4 e2 = *(const float4*)&eps[base + 8],  e3 = *(const float4*)&eps[base + 12];
        const float4 s0v = *(const float4*)&out[O_ZS_PRED + base + 0],  s1v = *(const float4*)&out[O_ZS_PRED + base + 4];
        const float4 s2v = *(const float4*)&out[O_ZS_PRED + base + 8],  s3v = *(const float4*)&out[O_ZS_PRED + base + 12];
        const float4 m0 = *(const float4*)&out[O_ZM_PRED + base + 0],  m1 = *(const float4*)&out[O_ZM_PRED + base + 4];
        const float4 m2 = *(const float4*)&out[O_ZM_PRED + base + 8],  m3 = *(const float4*)&out[O_ZM_PRED + base + 12];
        zA = make_float4(fmaf(e0.x,s0v.x,m0.x), fmaf(e0.y,s0v.y,m0.y), fmaf(e0.z,s0v.z,m0.z), fmaf(e0.w,s0v.w,m0.w));
        zB = make_float4(fmaf(e1.x,s1v.x,m1.x), fmaf(e1.y,s1v.y,m1.y), fmaf(e1.z,s1v.z,m1.z), fmaf(e1.w,s1v.w,m1.w));
        zC = make_float4(fmaf(e2.x,s2v.x,m2.x), fmaf(e2.y,s2v.y,m2.y), fmaf(e2.z,s2v.z,m2.z), fmaf(e2.w,s2v.w,m2.w));
        zD = make_float4(fmaf(e3.x,s3v.x,m3.x), fmaf(e3.y,s3v.y,m3.y), fmaf(e3.z,s3v.z,m3.z), fmaf(e3.w,s3v.w,m3.w));
    }

    float h1[64];
#pragma unroll 2
    for (int jg = 0; jg < 8; jg++) {
        const int j0 = jg * 8;
#pragma unroll
        for (int jj = 0; jj < 8; jj++) {
            const float4 wq0 = *(const float4*)&sWd1[(j0 + jj) * 16 + 0];
            const float4 wq1 = *(const float4*)&sWd1[(j0 + jj) * 16 + 4];
            const float4 wq2 = *(const float4*)&sWd1[(j0 + jj) * 16 + 8];
            const float4 wq3 = *(const float4*)&sWd1[(j0 + jj) * 16 + 12];
            float v = sBd1[j0 + jj];
            v = FMA4(zA.x, zA.y, zA.z, zA.w, wq0, v);
            v = FMA4(zB.x, zB.y, zB.z, zB.w, wq1, v);
            v = FMA4(zC.x, zC.y, zC.z, zC.w, wq2, v);
            v = FMA4(zD.x, zD.y, zD.z, zD.w, wq3, v);
            h1[j0 + jj] = fmaxf(v, 0.f);
        }
    }

#pragma unroll
    for (int j = 0; j < 64; j++) {
        float s = wred(h1[j]), ss = wred(h1[j] * h1[j]);
        if (lane == 0) { sRed[wid][2 * j] = s; sRed[wid][2 * j + 1] = ss; }
    }
    __syncthreads();
    if (tid < 64) {
        const float s  = sRed[0][2 * tid] + sRed[1][2 * tid] + sRed[2][2 * tid] + sRed[3][2 * tid];
        const float ss = sRed[0][2 * tid + 1] + sRed[1][2 * tid + 1] + sRed[2][2 * tid + 1] + sRed[3][2 * tid + 1];
        const float m = s * (1.f / 256.f);
        const float var = fmaf(-m, m, ss * (1.f / 256.f));
        sM1[tid] = m; sS1[tid] = gd1[tid] * rsqrtf(var + 1e-5f); sE1[tid] = bed1[tid];
    }
    __syncthreads();
#pragma unroll
    for (int j = 0; j < 64; j++) h1[j] = fmaf(h1[j] - sM1[j], sS1[j], sE1[j]);

    float h2g[32];
#pragma unroll 1
    for (int icg = 0; icg < 4; icg++) {
        const int ic0 = icg * 8;
        float acc[8];
#pragma unroll
        for (int jj = 0; jj < 8; jj++) acc[jj] = sBd2g[ic0 + jj];
#pragma unroll 2
        for (int k4 = 0; k4 < 16; k4++) {
#pragma unroll
            for (int jj = 0; jj < 8; jj++) {
                const float4 wv = *(const float4*)&sWd2g[(ic0 + jj) * 64 + 4 * k4];
                acc[jj] = FMA4(h1[4*k4], h1[4*k4+1], h1[4*k4+2], h1[4*k4+3], wv, acc[jj]);
            }
        }
#pragma unroll
        for (int jj = 0; jj < 8; jj++) h2g[ic0 + jj] = fmaxf(acc[jj], 0.f);
    }

#pragma unroll
    for (int ic = 0; ic < 32; ic++) {
        float s = wred(h2g[ic]), ss = wred(h2g[ic] * h2g[ic]);
        if (lane == 0) { sRed[wid][2 * ic] = s; sRed[wid][2 * ic + 1] = ss; }
    }
    __syncthreads();
    if (tid < 32) {
        const float s  = sRed[0][2 * tid] + sRed[1][2 * tid] + sRed[2][2 * tid] + sRed[3][2 * tid];
        const float ss = sRed[0][2 * tid + 1] + sRed[1][2 * tid + 1] + sRed[2][2 * tid + 1] + sRed[3][2 * tid + 1];
        const float m = s * (1.f / 256.f);
        const float var = fmaf(-m, m, ss * (1.f / 256.f));
        sM2[tid] = m;
        sS2[tid] = gd2[4 * tid + g] * rsqrtf(var + 1e-5f);
        sE2[tid] = bed2[4 * tid + g];
    }
    __syncthreads();
#pragma unroll
    for (int ic = 0; ic < 32; ic++) h2g[ic] = fmaf(h2g[ic] - sM2[ic], sS2[ic], sE2[ic]);

    {
        float* dst = ws_h2n + (((size_t)(tp * 4 + g) * 256 + b) * 32);
#pragma unroll
        for (int ic = 0; ic < 32; ic += 4)
            *(float4*)&dst[ic] = make_float4(h2g[ic], h2g[ic + 1], h2g[ic + 2], h2g[ic + 3]);
    }

    float ls[16], lss[16];
#pragma unroll
    for (int i = 0; i < 16; i++) { ls[i] = 0.f; lss[i] = 0.f; }
#pragma unroll 1
    for (int dp = 0; dp < 4; dp++) {
#pragma unroll
        for (int og = 0; og < 4; og++) {
            float acc[4];
#pragma unroll
            for (int jj = 0; jj < 4; jj++) acc[jj] = sBt1[og * 4 + jj];
#pragma unroll
            for (int i4 = 0; i4 < 8; i4++) {
#pragma unroll
                for (int jj = 0; jj < 4; jj++) {
                    const float4 wv = *(const float4*)&sWt1g[(dp * 16 + og * 4 + jj) * 32 + 4 * i4];
                    acc[jj] = FMA4(h2g[4*i4], h2g[4*i4+1], h2g[4*i4+2], h2g[4*i4+3], wv, acc[jj]);
                }
            }
#pragma unroll
            for (int jj = 0; jj < 4; jj++) {
                const float v = fmaxf(acc[jj], 0.f);
                ls[og * 4 + jj] += v; lss[og * 4 + jj] = fmaf(v, v, lss[og * 4 + jj]);
            }
        }
    }
#pragma unroll
    for (int oc = 0; oc < 16; oc++) {
        float s = wred(ls[oc]), ss = wred(lss[oc]);
        if (lane == 0) { sRed[wid][2 * oc] = s; sRed[wid][2 * oc + 1] = ss; }
    }
    __syncthreads();
    if (tid < 16) {
        const float s  = sRed[0][2 * tid] + sRed[1][2 * tid] + sRed[2][2 * tid] + sRed[3][2 * tid];
        const float ss = sRed[0][2 * tid + 1] + sRed[1][2 * tid + 1] + sRed[2][2 * tid + 1] + sRed[3][2 * tid + 1];
        ws_p3[(tp * 4 + g) * 32 + 2 * tid + 0] = s;
        ws_p3[(tp * 4 + g) * 32 + 2 * tid + 1] = ss;
    }
}

// ==================== Kernel 3: BN3 finalize + convT1 recompute + convT2 + nll ====================
extern "C" __global__ void __launch_bounds__(256)
k_dec2(const float* __restrict__ x,    const int* __restrict__ pos,
       const float* __restrict__ Wt1,  const float* __restrict__ bt1,
       const float* __restrict__ gt1,  const float* __restrict__ bet1,
       const float* __restrict__ Wt2,  const float* __restrict__ bt2,
       float* __restrict__ out,
       const float* __restrict__ ws_h2n, const float* __restrict__ ws_p3)
{
    const int tp = blockIdx.x >> 2, g = blockIdx.x & 3;
    const int tid = threadIdx.x, b = tid;
    const int wid = tid >> 6, lane = tid & 63;

    __shared__ __align__(16) float sWt1g[2048];
    __shared__ __align__(16) float sWt2[192];
    __shared__ float sBt1[16], sBt2[3];
    __shared__ float sRed[4][64];
    __shared__ float sM3[16], sS3[16], sE3[16];

    for (int i = tid; i < 2048; i += 256) {
        const int dp = i >> 9, rem = i & 511, oc = rem >> 5, ic = i & 31;
        const int py = (g >> 1) * 2 + (dp >> 1), px = (g & 1) * 2 + (dp & 1);
        const int k9 = ((py + 1) % 3) * 3 + ((px + 1) % 3);
        sWt1g[(dp * 16 + oc) * 32 + ic] = Wt1[ic * 144 + oc * 9 + k9];
    }
    if (tid < 192) { const int ic = tid / 12, r = tid % 12; sWt2[r * 16 + ic] = Wt2[tid]; }
    if (tid < 16) sBt1[tid] = bt1[tid];
    if (tid < 3) sBt2[tid] = bt2[tid];
    if (tid < 16) {
        float s = 0.f, ss = 0.f;
#pragma unroll
        for (int gg = 0; gg < 4; gg++) {
            s  += ws_p3[(tp * 4 + gg) * 32 + 2 * tid + 0];
            ss += ws_p3[(tp * 4 + gg) * 32 + 2 * tid + 1];
        }
        const float m = s * (1.f / 4096.f);
        const float var = fmaf(-m, m, ss * (1.f / 4096.f));
        sM3[tid] = m; sS3[tid] = gt1[tid] * rsqrtf(var + 1e-5f); sE3[tid] = bet1[tid];
    }
    __syncthreads();

    float h2g[32];
    {
        const float* src = ws_h2n + (((size_t)(tp * 4 + g) * 256 + b) * 32);
#pragma unroll
        for (int i4 = 0; i4 < 8; i4++) {
            const float4 v4 = *(const float4*)&src[4 * i4];
            h2g[4 * i4] = v4.x; h2g[4 * i4 + 1] = v4.y; h2g[4 * i4 + 2] = v4.z; h2g[4 * i4 + 3] = v4.w;
        }
    }

    const int t = 256 + tp;
    const int pr = 3 * pos[(b * 2 + 0) * 288 + t];
    const int pc = 3 * pos[(b * 2 + 1) * 288 + t];
    const float* xb = x + b * 3072;
    const int rbase = O_XREC + (tp * 256 + b) * 192;
    const int py0 = (g >> 1) * 2, px0 = (g & 1) * 2;
    float err = 0.f;

#pragma unroll 1
    for (int dp = 0; dp < 4; dp++) {
        const int py = py0 + (dp >> 1), px = px0 + (dp & 1);
        float hn[16];
#pragma unroll
        for (int og = 0; og < 4; og++) {
            float acc[4];
#pragma unroll
            for (int jj = 0; jj < 4; jj++) acc[jj] = sBt1[og * 4 + jj];
#pragma unroll
            for (int i4 = 0; i4 < 8; i4++) {
#pragma unroll
                for (int jj = 0; jj < 4; jj++) {
                    const float4 wv = *(const float4*)&sWt1g[(dp * 16 + og * 4 + jj) * 32 + 4 * i4];
                    acc[jj] = FMA4(h2g[4*i4], h2g[4*i4+1], h2g[4*i4+2], h2g[4*i4+3], wv, acc[jj]);
                }
            }
#pragma unroll
            for (int jj = 0; jj < 4; jj++) {
                const int oc = og * 4 + jj;
                hn[oc] = fmaf(fmaxf(acc[jj], 0.f) - sM3[oc], sS3[oc], sE3[oc]);
            }
        }
#pragma unroll
        for (int c = 0; c < 3; c++)
#pragma unroll
        for (int dy = 0; dy < 2; dy++)
#pragma unroll
        for (int dx = 0; dx < 2; dx++) {
            const float* wp = &sWt2[(c * 4 + dy * 2 + dx) * 16];
            float v = sBt2[c];
#pragma unroll
            for (int ic = 0; ic < 16; ic += 4) {
                const float4 wq = *(const float4*)&wp[ic];
                v = FMA4(hn[ic], hn[ic + 1], hn[ic + 2], hn[ic + 3], wq, v);
            }
            v = sigm(v);
            const int oy = 2 * py + dy, ox = 2 * px + dx;
            out[rbase + c * 64 + oy * 8 + ox] = v;
            const float d = v - xb[c * 1024 + (pr + oy) * 32 + (pc + ox)];
            err = fmaf(d, d, err);
        }
    }

    const float es = wred(err);
    if (lane == 0) sRed[wid][0] = es;
    __syncthreads();
    if (tid == 0)
        atomicAdd(&out[O_NLL], sRed[0][0] + sRed[1][0] + sRed[2][0] + sRed[3][0]);
}

// ==================== host ====================
extern "C" void kernel_launch(void* const* d_in, const int* in_sizes, int n_in,
                              void* d_out, int out_size, void* d_ws, size_t ws_size,
                              hipStream_t stream)
{
    const float* x    = (const float*)d_in[0];
    const float* act  = (const float*)d_in[1];
    const int*   pos  = (const int*)d_in[2];
    const float* s0   = (const float*)d_in[3];
    const float* nobs = (const float*)d_in[4];
    const float* nprd = (const float*)d_in[5];
    const float* eps  = (const float*)d_in[6];
    const float* Wa   = (const float*)d_in[7];
    const float* Ws1  = (const float*)d_in[8];
    const float* bs1  = (const float*)d_in[9];
    const float* Ws2  = (const float*)d_in[10];
    const float* bs2  = (const float*)d_in[11];
    const float* Wc1  = (const float*)d_in[12];
    const float* bc1  = (const float*)d_in[13];
    const float* g1   = (const float*)d_in[14];
    const float* be1  = (const float*)d_in[15];
    const float* Wc2  = (const float*)d_in[16];
    const float* bc2  = (const float*)d_in[17];
    const float* g2   = (const float*)d_in[18];
    const float* be2  = (const float*)d_in[19];
    const float* Wzm  = (const float*)d_in[20];
    const float* bzm  = (const float*)d_in[21];
    const float* Wzs  = (const float*)d_in[22];
    const float* bzs  = (const float*)d_in[23];
    const float* Wd1  = (const float*)d_in[24];
    const float* bd1  = (const float*)d_in[25];
    const float* gd1  = (const float*)d_in[26];
    const float* bed1 = (const float*)d_in[27];
    const float* Wd2  = (const float*)d_in[28];
    const float* bd2  = (const float*)d_in[29];
    const float* gd2  = (const float*)d_in[30];
    const float* bed2 = (const float*)d_in[31];
    const float* Wt1  = (const float*)d_in[32];
    const float* bt1  = (const float*)d_in[33];
    const float* gt1  = (const float*)d_in[34];
    const float* bet1 = (const float*)d_in[35];
    const float* Wt2  = (const float*)d_in[36];
    const float* bt2  = (const float*)d_in[37];
    float* out = (float*)d_out;
    float* ws  = (float*)d_ws;

    const size_t need_fast = (POOL_FLOATS + 147456) * sizeof(float);  // 19.46 MB

    if (ws_size >= need_fast) {
        // fast path: pool staged in ws; U beyond pool; H2N/P3 reuse pool region after k_enc
        float* ws_pool = ws;
        float* ws_u    = ws + POOL_FLOATS;
        float* ws_h2n  = ws;                 // written by k_dec1 (after k_enc consumed pool)
        float* ws_p3   = ws + 1048576;

        k_pre<<<dim3(256), dim3(288), 0, stream>>>(act, Wa, ws_u);
        k_patch<<<dim3(257), dim3(256), 0, stream>>>(
            x, pos, s0, nobs, nprd, Ws1, bs1, Ws2, bs2, Wc1, bc1, ws_u, ws_pool, out);
        k_enc<<<dim3(288), dim3(256), 0, stream>>>(
            g1, be1, Wc2, bc2, g2, be2, Wzm, bzm, Wzs, bzs, ws_pool, out);
        k_dec1<<<dim3(128), dim3(256), 0, stream>>>(
            eps, Wd1, bd1, gd1, bed1, Wd2, bd2, gd2, bed2, Wt1, bt1, out, ws_h2n, ws_p3);
        k_dec2<<<dim3(128), dim3(256), 0, stream>>>(
            x, pos, Wt1, bt1, gt1, bet1, Wt2, bt2, out, ws_h2n, ws_p3);
    } else {
        // fallback: 4.8 MB layout (validated in rounds 2-5)
        float* ws_u   = ws;
        float* ws_h2n = ws + 147456;
        float* ws_p3  = ws + 1196032;

        k_pre<<<dim3(256), dim3(288), 0, stream>>>(act, Wa, ws_u);
        k_enc_full<<<dim3(289), dim3(256), 0, stream>>>(
            x, pos, s0, nobs, nprd, Ws1, bs1, Ws2, bs2,
            Wc1, bc1, g1, be1, Wc2, bc2, g2, be2, Wzm, bzm, Wzs, bzs, ws_u, out);
        k_dec1<<<dim3(128), dim3(256), 0, stream>>>(
            eps, Wd1, bd1, gd1, bed1, Wd2, bd2, gd2, bed2, Wt1, bt1, out, ws_h2n, ws_p3);
        k_dec2<<<dim3(128), dim3(256), 0, stream>>>(
            x, pos, Wt1, bt1, gt1, bet1, Wt2, bt2, out, ws_h2n, ws_p3);
    }
}

// Round 7
// 335.863 us; speedup vs baseline: 1.4822x; 1.2064x over previous
//
#include <hip/hip_runtime.h>
#include <hip/hip_bf16.h>
#include <math.h>

// ---------------- problem constants ----------------
#define NB   256
#define NT   288
#define NOBS 256
#define NTP  32

// output offsets (floats)
#define O_ST_OBS   0
#define O_ST_PRED  131072
#define O_ZM_OBS   147456
#define O_ZS_OBS   1196032
#define O_ZM_PRED  2244608
#define O_ZS_PRED  2375680
#define O_XREC     2506752
#define O_NLL      4079616

#define POOL_FLOATS ((size_t)288 * 256 * 64)   // 4,718,592 floats = 18.9 MB

__device__ __forceinline__ float wred(float v) {
    v += __shfl_down(v, 32); v += __shfl_down(v, 16); v += __shfl_down(v, 8);
    v += __shfl_down(v, 4);  v += __shfl_down(v, 2);  v += __shfl_down(v, 1);
    return v;
}
__device__ __forceinline__ float sigm(float x) { return 1.0f / (1.0f + __expf(-x)); }
__device__ __forceinline__ float tanh_f(float x) {
    x = fminf(fmaxf(x, -15.0f), 15.0f);
    float e = __expf(2.0f * x);
    return (e - 1.0f) / (e + 1.0f);
}
// NOTE: no macro parameter may be named x/y/z/w (member-access collision!)
#define FMA4(ax,ay,az,aw,wv,acc) fmaf((ax),(wv).x,fmaf((ay),(wv).y,fmaf((az),(wv).z,fmaf((aw),(wv).w,(acc)))))

// ==================== recurrence (device fn; one 256-thread block, thread = b) ====================
__device__ __forceinline__ void run_recurrence(
    int b, const float* __restrict__ s0,
    const float* __restrict__ nobs, const float* __restrict__ npred,
    const float* __restrict__ Ws1, const float* __restrict__ bs1,
    const float* __restrict__ Ws2, const float* __restrict__ bs2,
    const float* __restrict__ ws_u, float* __restrict__ out)
{
    float w1[10], w2[10], c1[5], c2_0, c2_1;
#pragma unroll
    for (int i = 0; i < 10; i++) { w1[i] = Ws1[i]; w2[i] = Ws2[i]; }
#pragma unroll
    for (int i = 0; i < 5; i++) c1[i] = bs1[i];
    c2_0 = bs2[0]; c2_1 = bs2[1];

    float sv0 = s0[b * 2 + 0], sv1 = s0[b * 2 + 1];
    ((float2*)(out + O_ST_OBS))[b] = make_float2(sv0, sv1);
    if (b == 0) out[O_NLL] = 0.0f;   // re-zeroed every call; stream-ordered before k_dec2

    const float2* Up   = (const float2*)ws_u;
    const float2* Nobs = (const float2*)nobs;
    const float2* Nprd = (const float2*)npred;

    float2 u  = Up[256 + b];
    float2 nz = Nobs[b];

    for (int t = 1; t < 288; t++) {
        float2 u_n = make_float2(0.f, 0.f), nz_n = make_float2(0.f, 0.f);
        if (t < 287) {
            u_n = Up[(t + 1) * 256 + b];
            const float2* np = (t + 1 < 256) ? (Nobs + t * 256 + b)
                                             : (Nprd + (t - 255) * 256 + b);
            nz_n = *np;
        }
        const float v0 = sv0 + u.x, v1 = sv1 + u.y;
        float h[5];
#pragma unroll
        for (int j = 0; j < 5; j++)
            h[j] = tanh_f(fmaf(v1, w1[j * 2 + 1], fmaf(v0, w1[j * 2 + 0], c1[j])));
        float a0 = fmaf(h[0], w2[0], fmaf(h[1], w2[1], c2_0));
        float a0b = fmaf(h[2], w2[2], h[3] * w2[3]);
        a0 = fmaf(h[4], w2[4], a0 + a0b);
        float a1 = fmaf(h[0], w2[5], fmaf(h[1], w2[6], c2_1));
        float a1b = fmaf(h[2], w2[7], h[3] * w2[8]);
        a1 = fmaf(h[4], w2[9], a1 + a1b);

        sv0 = fmaf(u.x, sigm(a0), sv0) + nz.x;
        sv1 = fmaf(u.y, sigm(a1), sv1) + nz.y;

        if (t < 256) ((float2*)(out + O_ST_OBS))[t * 256 + b] = make_float2(sv0, sv1);
        else         ((float2*)(out + O_ST_PRED))[(t - 256) * 256 + b] = make_float2(sv0, sv1);

        u = u_n; nz = nz_n;
    }
}

// ==================== Kernel 0: U[t][b][2] = act^T . Wa ====================
extern "C" __global__ void __launch_bounds__(288)
k_pre(const float* __restrict__ act, const float* __restrict__ Wa, float* __restrict__ ws_u)
{
    const int b = blockIdx.x;     // 0..255
    const int t = threadIdx.x;    // 0..287
    float u0 = 0.f, u1 = 0.f;
#pragma unroll
    for (int a = 0; a < 5; a++) {
        const float av = act[(b * 5 + a) * 288 + t];
        u0 = fmaf(av, Wa[a], u0);
        u1 = fmaf(av, Wa[5 + a], u1);
    }
    ws_u[(t * 256 + b) * 2 + 0] = u0;
    ws_u[(t * 256 + b) * 2 + 1] = u1;
}

// ==================== Kernel 1a (fast path): conv1+maxpool, work = (b, t, posq) ====================
// grid 1 + 256*5: block 0 = recurrence; else b = (bid-1)/5, t-chunk c = (bid-1)%5
// thread: t_local = tid>>2 (0..63), posq = tid&3. pool layout: [b][t][posq][16]
extern "C" __global__ void __launch_bounds__(256)
k_patch(const float* __restrict__ x, const int* __restrict__ pos,
        const float* __restrict__ s0, const float* __restrict__ nobs,
        const float* __restrict__ npred,
        const float* __restrict__ Ws1, const float* __restrict__ bs1,
        const float* __restrict__ Ws2, const float* __restrict__ bs2,
        const float* __restrict__ Wc1, const float* __restrict__ bc1,
        const float* __restrict__ ws_u, float* __restrict__ ws_pool,
        float* __restrict__ out)
{
    const int tid = threadIdx.x;
    if (blockIdx.x == 0) {
        run_recurrence(tid, s0, nobs, npred, Ws1, bs1, Ws2, bs2, ws_u, out);
        return;
    }
    const int bid = blockIdx.x - 1;
    const int b = bid / 5, c = bid % 5;

    __shared__ __align__(16) float sImg[3 * 1056];   // rows padded to stride 33
    __shared__ float sWc1[192];
    __shared__ float sB1[16];

    for (int i = tid; i < 3072; i += 256) {
        const int ic = i >> 10, r = (i >> 5) & 31, cc = i & 31;
        sImg[ic * 1056 + r * 33 + cc] = x[b * 3072 + i];
    }
    if (tid < 192) sWc1[tid] = Wc1[tid];
    if (tid < 16) sB1[tid] = bc1[tid];
    __syncthreads();

    const int t = c * 64 + (tid >> 2);
    if (t >= 288) return;                 // c==4 chunk has 32 t's
    const int posq = tid & 3;
    const int py = posq >> 1, px = posq & 1;

    const int pr = 3 * pos[(b * 2 + 0) * 288 + t];
    const int pc = 3 * pos[(b * 2 + 1) * 288 + t];

    float p16[16];
#pragma unroll
    for (int i = 0; i < 16; i++) p16[i] = 0.f;       // relu >= 0 => 0-init == true max

#pragma unroll 2
    for (int d = 0; d < 4; d++) {
        const int rbase = pr + 4 * py + 2 * (d >> 1);
        const int cbase = pc + 4 * px + 2 * (d & 1);
        float in[12];
#pragma unroll
        for (int ic = 0; ic < 3; ic++)
#pragma unroll
        for (int ky = 0; ky < 2; ky++)
#pragma unroll
        for (int kx = 0; kx < 2; kx++)
            in[ic * 4 + ky * 2 + kx] = sImg[ic * 1056 + (rbase + ky) * 33 + (cbase + kx)];
#pragma unroll
        for (int oc = 0; oc < 16; oc++) {
            const float4 wq0 = *(const float4*)&sWc1[oc * 12 + 0];
            const float4 wq1 = *(const float4*)&sWc1[oc * 12 + 4];
            const float4 wq2 = *(const float4*)&sWc1[oc * 12 + 8];
            float v = sB1[oc];
            v = FMA4(in[0], in[1], in[2], in[3], wq0, v);
            v = FMA4(in[4], in[5], in[6], in[7], wq1, v);
            v = FMA4(in[8], in[9], in[10], in[11], wq2, v);
            p16[oc] = fmaxf(p16[oc], fmaxf(v, 0.f));
        }
    }

    float4* dst = (float4*)(ws_pool + (((size_t)b * 288 + t) * 4 + posq) * 16);
    dst[0] = make_float4(p16[0], p16[1], p16[2], p16[3]);
    dst[1] = make_float4(p16[4], p16[5], p16[6], p16[7]);
    dst[2] = make_float4(p16[8], p16[9], p16[10], p16[11]);
    dst[3] = make_float4(p16[12], p16[13], p16[14], p16[15]);
}

// ==================== Kernel 1b (fast path): BN1 + conv2 + BN2 + heads ====================
// grid 288: block = timestep t; thread = batch b. pooled row layout: [pos(4)][ch(16)]
extern "C" __global__ void __launch_bounds__(256)
k_enc(const float* __restrict__ g1,   const float* __restrict__ be1,
      const float* __restrict__ Wc2,  const float* __restrict__ bc2,
      const float* __restrict__ g2,   const float* __restrict__ be2,
      const float* __restrict__ Wzm,  const float* __restrict__ bzm,
      const float* __restrict__ Wzs,  const float* __restrict__ bzs,
      const float* __restrict__ ws_pool, float* __restrict__ out)
{
    const int t = blockIdx.x, tid = threadIdx.x, b = tid;
    const int wid = tid >> 6, lane = tid & 63;

    __shared__ __align__(16) float pooledL[256 * 68];   // [b][pos*16+ch], stride 68
    __shared__ __align__(16) float sWc2r[2048];          // remapped [oc][q][ic]
    __shared__ __align__(16) float sWzm[512];
    __shared__ __align__(16) float sWzs[512];
    __shared__ __align__(16) float sM1[16], sS1[16], sE1[16];
    __shared__ float sB2[32], sE2[32], sBzm[16], sBzs[16];
    __shared__ float sM2[32], sS2[32];
    __shared__ float sRed[4][64];

    for (int i = tid; i < 2048; i += 256) {
        const int oc = i >> 6, rem = i & 63, ic = rem >> 2, q = rem & 3;
        sWc2r[oc * 64 + q * 16 + ic] = Wc2[i];
    }
    for (int i = tid; i < 512; i += 256) { sWzm[i] = Wzm[i]; sWzs[i] = Wzs[i]; }
    if (tid < 16) { sE1[tid] = be1[tid]; sBzm[tid] = bzm[tid]; sBzs[tid] = bzs[tid]; }
    if (tid < 32) { sB2[tid] = bc2[tid]; sE2[tid] = be2[tid]; }

    // load my pooled row (64 floats, [pos][ch]) from ws ([b][t] layout)
    float* myrow = &pooledL[b * 68];
    {
        const float4* src = (const float4*)(ws_pool + ((size_t)b * 288 + t) * 64);
#pragma unroll
        for (int q = 0; q < 16; q++) *(float4*)&myrow[4 * q] = src[q];
    }
    __syncthreads();

    // ---- BN1 stats: per channel over (b, 4 pos) = 1024; column partial sums ----
    {
        const int col = tid & 63, q = tid >> 6;
        float s = 0.f, ss = 0.f;
        const float* cp = &pooledL[(q * 64) * 68 + col];
#pragma unroll 4
        for (int i = 0; i < 64; i++) { const float v = cp[i * 68]; s += v; ss = fmaf(v, v, ss); }
        sRed[q][col] = s;
        __syncthreads();
        float ssum = 0.f;
        if (tid < 16) {
#pragma unroll
            for (int p = 0; p < 4; p++)
#pragma unroll
            for (int qq = 0; qq < 4; qq++) ssum += sRed[qq][p * 16 + tid];
        }
        __syncthreads();
        sRed[q][col] = ss;
        __syncthreads();
        if (tid < 16) {
            float sssum = 0.f;
#pragma unroll
            for (int p = 0; p < 4; p++)
#pragma unroll
            for (int qq = 0; qq < 4; qq++) sssum += sRed[qq][p * 16 + tid];
            const float m = ssum * (1.f / 1024.f);
            const float var = fmaf(-m, m, sssum * (1.f / 1024.f));
            sM1[tid] = m; sS1[tid] = g1[tid] * rsqrtf(var + 1e-5f);
        }
    }
    __syncthreads();

    // ---- normalize own row (quad tq: ch-quad = tq&3) ----
#pragma unroll 4
    for (int tq = 0; tq < 16; tq++) {
        const int ic0 = (tq & 3) * 4;
        float4 v = *(float4*)&myrow[4 * tq];
        const float4 mq = *(const float4*)&sM1[ic0];
        const float4 sq = *(const float4*)&sS1[ic0];
        const float4 eq = *(const float4*)&sE1[ic0];
        v.x = fmaf(v.x - mq.x, sq.x, eq.x);
        v.y = fmaf(v.y - mq.y, sq.y, eq.y);
        v.z = fmaf(v.z - mq.z, sq.z, eq.z);
        v.w = fmaf(v.w - mq.w, sq.w, eq.w);
        *(float4*)&myrow[4 * tq] = v;
    }

    // ---- conv2 (16ch x 4pos -> 32) + relu, register-blocked JB=8 ----
    float h2v[32];
#pragma unroll
    for (int og = 0; og < 4; og++) {
        float acc[8];
#pragma unroll
        for (int jj = 0; jj < 8; jj++) acc[jj] = sB2[og * 8 + jj];
#pragma unroll 2
        for (int tq = 0; tq < 16; tq++) {
            const float4 hq = *(const float4*)&myrow[4 * tq];
#pragma unroll
            for (int jj = 0; jj < 8; jj++) {
                const float4 wv = *(const float4*)&sWc2r[(og * 8 + jj) * 64 + 4 * tq];
                acc[jj] = FMA4(hq.x, hq.y, hq.z, hq.w, wv, acc[jj]);
            }
        }
#pragma unroll
        for (int jj = 0; jj < 8; jj++) h2v[og * 8 + jj] = fmaxf(acc[jj], 0.f);
    }

    // ---- BN2: per-channel over b (single-pass wred; 32ch -> 64 slots) ----
#pragma unroll
    for (int oc = 0; oc < 32; oc++) {
        float s = wred(h2v[oc]), ss = wred(h2v[oc] * h2v[oc]);
        if (lane == 0) { sRed[wid][2 * oc] = s; sRed[wid][2 * oc + 1] = ss; }
    }
    __syncthreads();
    if (tid < 32) {
        const float s  = sRed[0][2 * tid] + sRed[1][2 * tid] + sRed[2][2 * tid] + sRed[3][2 * tid];
        const float ss = sRed[0][2 * tid + 1] + sRed[1][2 * tid + 1] + sRed[2][2 * tid + 1] + sRed[3][2 * tid + 1];
        const float m = s * (1.f / 256.f);
        const float var = fmaf(-m, m, ss * (1.f / 256.f));
        sM2[tid] = m; sS2[tid] = g2[tid] * rsqrtf(var + 1e-5f);
    }
    __syncthreads();
#pragma unroll
    for (int oc = 0; oc < 32; oc++) h2v[oc] = fmaf(h2v[oc] - sM2[oc], sS2[oc], sE2[oc]);

    // ---- zm / zs heads (32 -> 16 each) ----
    const int obase_m = (t < 256) ? (O_ZM_OBS + (t * 256 + b) * 16) : (O_ZM_PRED + ((t - 256) * 256 + b) * 16);
    const int obase_s = (t < 256) ? (O_ZS_OBS + (t * 256 + b) * 16) : (O_ZS_PRED + ((t - 256) * 256 + b) * 16);
#pragma unroll 2
    for (int k = 0; k < 16; k++) {
        float vm = sBzm[k], vs = sBzs[k];
#pragma unroll
        for (int c = 0; c < 32; c += 4) {
            const float4 wm = *(const float4*)&sWzm[k * 32 + c];
            const float4 wsq = *(const float4*)&sWzs[k * 32 + c];
            vm = FMA4(h2v[c], h2v[c + 1], h2v[c + 2], h2v[c + 3], wm, vm);
            vs = FMA4(h2v[c], h2v[c + 1], h2v[c + 2], h2v[c + 3], wsq, vs);
        }
        out[obase_m + k] = vm;
        out[obase_s + k] = __expf(vs);
    }
}

// ==================== Kernel 1 (fallback): fused encoder with global gathers (R4-proven) ====================
extern "C" __global__ void __launch_bounds__(256)
k_enc_full(const float* __restrict__ x,
           const int*   __restrict__ pos,  const float* __restrict__ s0,
           const float* __restrict__ nobs, const float* __restrict__ npred,
           const float* __restrict__ Ws1,  const float* __restrict__ bs1,
           const float* __restrict__ Ws2,  const float* __restrict__ bs2,
           const float* __restrict__ Wc1,  const float* __restrict__ bc1,
           const float* __restrict__ g1,   const float* __restrict__ be1,
           const float* __restrict__ Wc2,  const float* __restrict__ bc2,
           const float* __restrict__ g2,   const float* __restrict__ be2,
           const float* __restrict__ Wzm,  const float* __restrict__ bzm,
           const float* __restrict__ Wzs,  const float* __restrict__ bzs,
           const float* __restrict__ ws_u, float* __restrict__ out)
{
    const int tid = threadIdx.x;
    if (blockIdx.x == 0) {
        run_recurrence(tid, s0, nobs, npred, Ws1, bs1, Ws2, bs2, ws_u, out);
        return;
    }
    const int t = blockIdx.x - 1;
    __shared__ __align__(16) float sWc1[192];
    __shared__ __align__(16) float sWc2r[2048];
    __shared__ __align__(16) float sWzm[512];
    __shared__ __align__(16) float sWzs[512];
    __shared__ __align__(16) float sM1[16], sS1[16], sE1[16];
    __shared__ float sB1[16], sB2[32], sE2[32], sBzm[16], sBzs[16];
    __shared__ float sM2[32], sS2[32];
    __shared__ float sRed[4][64];
    __shared__ __align__(16) float pooledL[256 * 68];

    for (int i = tid; i < 192; i += 256) sWc1[i] = Wc1[i];
    for (int i = tid; i < 2048; i += 256) {
        const int oc = i >> 6, rem = i & 63, ic = rem >> 2, q = rem & 3;
        sWc2r[oc * 64 + q * 16 + ic] = Wc2[i];
    }
    for (int i = tid; i < 512; i += 256) { sWzm[i] = Wzm[i]; sWzs[i] = Wzs[i]; }
    if (tid < 16) { sB1[tid] = bc1[tid]; sE1[tid] = be1[tid]; sBzm[tid] = bzm[tid]; sBzs[tid] = bzs[tid]; }
    if (tid < 32) { sB2[tid] = bc2[tid]; sE2[tid] = be2[tid]; }
    __syncthreads();

    const int b = tid;
    const int wid = tid >> 6, lane = tid & 63;
    const float* xb = x + b * 3072;
    const int pr = 3 * pos[(b * 2 + 0) * 288 + t];
    const int pc = 3 * pos[(b * 2 + 1) * 288 + t];
    float* myrow = &pooledL[b * 68];

#pragma unroll
    for (int py = 0; py < 2; py++)
#pragma unroll
    for (int px = 0; px < 2; px++) {
        float p16[16];
#pragma unroll
        for (int i = 0; i < 16; i++) p16[i] = 0.f;
#pragma unroll 2
        for (int d = 0; d < 4; d++) {
            const int rbase = pr + 4 * py + 2 * (d >> 1);
            const int cbase = pc + 4 * px + 2 * (d & 1);
            float in[12];
#pragma unroll
            for (int ic = 0; ic < 3; ic++)
#pragma unroll
            for (int ky = 0; ky < 2; ky++)
#pragma unroll
            for (int kx = 0; kx < 2; kx++)
                in[ic * 4 + ky * 2 + kx] = xb[ic * 1024 + (rbase + ky) * 32 + (cbase + kx)];
#pragma unroll
            for (int oc = 0; oc < 16; oc++) {
                const float4 wq0 = *(const float4*)&sWc1[oc * 12 + 0];
                const float4 wq1 = *(const float4*)&sWc1[oc * 12 + 4];
                const float4 wq2 = *(const float4*)&sWc1[oc * 12 + 8];
                float v = sB1[oc];
                v = FMA4(in[0], in[1], in[2], in[3], wq0, v);
                v = FMA4(in[4], in[5], in[6], in[7], wq1, v);
                v = FMA4(in[8], in[9], in[10], in[11], wq2, v);
                p16[oc] = fmaxf(p16[oc], fmaxf(v, 0.f));
            }
        }
        const int pbase = (py * 2 + px) * 16;
        *(float4*)&myrow[pbase + 0]  = make_float4(p16[0], p16[1], p16[2], p16[3]);
        *(float4*)&myrow[pbase + 4]  = make_float4(p16[4], p16[5], p16[6], p16[7]);
        *(float4*)&myrow[pbase + 8]  = make_float4(p16[8], p16[9], p16[10], p16[11]);
        *(float4*)&myrow[pbase + 12] = make_float4(p16[12], p16[13], p16[14], p16[15]);
    }
    __syncthreads();

    // BN1 column partials (two LDS rounds via sRed[4][64])
    {
        const int col = tid & 63, q = tid >> 6;
        float s = 0.f, ss = 0.f;
        const float* cp = &pooledL[(q * 64) * 68 + col];
#pragma unroll 4
        for (int i = 0; i < 64; i++) { const float v = cp[i * 68]; s += v; ss = fmaf(v, v, ss); }
        sRed[q][col] = s;
        __syncthreads();
        float ssum = 0.f;
        if (tid < 16) {
#pragma unroll
            for (int p = 0; p < 4; p++)
#pragma unroll
            for (int qq = 0; qq < 4; qq++) ssum += sRed[qq][p * 16 + tid];
        }
        __syncthreads();
        sRed[q][col] = ss;
        __syncthreads();
        if (tid < 16) {
            float sssum = 0.f;
#pragma unroll
            for (int p = 0; p < 4; p++)
#pragma unroll
            for (int qq = 0; qq < 4; qq++) sssum += sRed[qq][p * 16 + tid];
            const float m = ssum * (1.f / 1024.f);
            const float var = fmaf(-m, m, sssum * (1.f / 1024.f));
            sM1[tid] = m; sS1[tid] = g1[tid] * rsqrtf(var + 1e-5f);
        }
    }
    __syncthreads();

#pragma unroll 4
    for (int tq = 0; tq < 16; tq++) {
        const int ic0 = (tq & 3) * 4;
        float4 v = *(float4*)&myrow[4 * tq];
        const float4 mq = *(const float4*)&sM1[ic0];
        const float4 sq = *(const float4*)&sS1[ic0];
        const float4 eq = *(const float4*)&sE1[ic0];
        v.x = fmaf(v.x - mq.x, sq.x, eq.x);
        v.y = fmaf(v.y - mq.y, sq.y, eq.y);
        v.z = fmaf(v.z - mq.z, sq.z, eq.z);
        v.w = fmaf(v.w - mq.w, sq.w, eq.w);
        *(float4*)&myrow[4 * tq] = v;
    }

    float h2v[32];
#pragma unroll
    for (int og = 0; og < 4; og++) {
        float acc[8];
#pragma unroll
        for (int jj = 0; jj < 8; jj++) acc[jj] = sB2[og * 8 + jj];
#pragma unroll 2
        for (int tq = 0; tq < 16; tq++) {
            const float4 hq = *(const float4*)&myrow[4 * tq];
#pragma unroll
            for (int jj = 0; jj < 8; jj++) {
                const float4 wv = *(const float4*)&sWc2r[(og * 8 + jj) * 64 + 4 * tq];
                acc[jj] = FMA4(hq.x, hq.y, hq.z, hq.w, wv, acc[jj]);
            }
        }
#pragma unroll
        for (int jj = 0; jj < 8; jj++) h2v[og * 8 + jj] = fmaxf(acc[jj], 0.f);
    }

#pragma unroll
    for (int oc = 0; oc < 32; oc++) {
        float s = wred(h2v[oc]), ss = wred(h2v[oc] * h2v[oc]);
        if (lane == 0) { sRed[wid][2 * oc] = s; sRed[wid][2 * oc + 1] = ss; }
    }
    __syncthreads();
    if (tid < 32) {
        const float s  = sRed[0][2 * tid] + sRed[1][2 * tid] + sRed[2][2 * tid] + sRed[3][2 * tid];
        const float ss = sRed[0][2 * tid + 1] + sRed[1][2 * tid + 1] + sRed[2][2 * tid + 1] + sRed[3][2 * tid + 1];
        const float m = s * (1.f / 256.f);
        const float var = fmaf(-m, m, ss * (1.f / 256.f));
        sM2[tid] = m; sS2[tid] = g2[tid] * rsqrtf(var + 1e-5f);
    }
    __syncthreads();
#pragma unroll
    for (int oc = 0; oc < 32; oc++) h2v[oc] = fmaf(h2v[oc] - sM2[oc], sS2[oc], sE2[oc]);

    const int obase_m = (t < 256) ? (O_ZM_OBS + (t * 256 + b) * 16) : (O_ZM_PRED + ((t - 256) * 256 + b) * 16);
    const int obase_s = (t < 256) ? (O_ZS_OBS + (t * 256 + b) * 16) : (O_ZS_PRED + ((t - 256) * 256 + b) * 16);
#pragma unroll 2
    for (int k = 0; k < 16; k++) {
        float vm = sBzm[k], vs = sBzs[k];
#pragma unroll
        for (int c = 0; c < 32; c += 4) {
            const float4 wm = *(const float4*)&sWzm[k * 32 + c];
            const float4 wsq = *(const float4*)&sWzs[k * 32 + c];
            vm = FMA4(h2v[c], h2v[c + 1], h2v[c + 2], h2v[c + 3], wm, vm);
            vs = FMA4(h2v[c], h2v[c + 1], h2v[c + 2], h2v[c + 3], wsq, vs);
        }
        out[obase_m + k] = vm;
        out[obase_s + k] = __expf(vs);
    }
}

// ==================== Kernel 2: z + fc1 + BN1 + fc2(g) + BN2 + convT1(g) stats ====================
// grid = 128: tp = bid>>2, quadrant g = bid&3
extern "C" __global__ void __launch_bounds__(256)
k_dec1(const float* __restrict__ eps,
       const float* __restrict__ Wd1,  const float* __restrict__ bd1,
       const float* __restrict__ gd1,  const float* __restrict__ bed1,
       const float* __restrict__ Wd2,  const float* __restrict__ bd2,
       const float* __restrict__ gd2,  const float* __restrict__ bed2,
       const float* __restrict__ Wt1,  const float* __restrict__ bt1,
       const float* __restrict__ out,
       float* __restrict__ ws_h2n, float* __restrict__ ws_p3)
{
    const int tp = blockIdx.x >> 2, g = blockIdx.x & 3;
    const int tid = threadIdx.x, b = tid;
    const int wid = tid >> 6, lane = tid & 63;

    __shared__ __align__(16) float sWd1[1024];
    __shared__ __align__(16) float sWd2g[2048];
    __shared__ __align__(16) float sWt1g[2048];
    __shared__ __align__(16) float sM1[64], sS1[64], sE1[64];
    __shared__ float sBd1[64], sBd2g[32], sBt1[16];
    __shared__ float sRed[4][128];
    __shared__ float sM2[32], sS2[32], sE2[32];

    for (int i = tid; i < 1024; i += 256) sWd1[i] = Wd1[i];
    for (int i = tid; i < 2048; i += 256) {
        const int ic = i >> 6, k = i & 63;
        sWd2g[i] = Wd2[(4 * ic + g) * 64 + k];
    }
    for (int i = tid; i < 2048; i += 256) {
        const int dp = i >> 9, rem = i & 511, oc = rem >> 5, ic = i & 31;
        const int py = (g >> 1) * 2 + (dp >> 1), px = (g & 1) * 2 + (dp & 1);
        const int k9 = ((py + 1) % 3) * 3 + ((px + 1) % 3);
        sWt1g[(dp * 16 + oc) * 32 + ic] = Wt1[ic * 144 + oc * 9 + k9];
    }
    if (tid < 64) sBd1[tid] = bd1[tid];
    if (tid < 32) sBd2g[tid] = bd2[4 * tid + g];
    if (tid < 16) sBt1[tid] = bt1[tid];
    __syncthreads();

    float4 zA, zB, zC, zD;
    {
        const int base = (tp * 256 + b) * 16;
        const float4 e0 = *(const float4*)&eps[base + 0],  e1 = *(const float4*)&eps[base + 4];
        const float4 e2 = *(const float4*)&eps[base + 8],  e3 = *(const float4*)&eps[base + 12];
        const float4 s0v = *(const float4*)&out[O_ZS_PRED + base + 0],  s1v = *(const float4*)&out[O_ZS_PRED + base + 4];
        const float4 s2v = *(const float4*)&out[O_ZS_PRED + base + 8],  s3v = *(const float4*)&out[O_ZS_PRED + base + 12];
        const float4 m0 = *(const float4*)&out[O_ZM_PRED + base + 0],  m1 = *(const float4*)&out[O_ZM_PRED + base + 4];
        const float4 m2 = *(const float4*)&out[O_ZM_PRED + base + 8],  m3 = *(const float4*)&out[O_ZM_PRED + base + 12];
        zA = make_float4(fmaf(e0.x,s0v.x,m0.x), fmaf(e0.y,s0v.y,m0.y), fmaf(e0.z,s0v.z,m0.z), fmaf(e0.w,s0v.w,m0.w));
        zB = make_float4(fmaf(e1.x,s1v.x,m1.x), fmaf(e1.y,s1v.y,m1.y), fmaf(e1.z,s1v.z,m1.z), fmaf(e1.w,s1v.w,m1.w));
        zC = make_float4(fmaf(e2.x,s2v.x,m2.x), fmaf(e2.y,s2v.y,m2.y), fmaf(e2.z,s2v.z,m2.z), fmaf(e2.w,s2v.w,m2.w));
        zD = make_float4(fmaf(e3.x,s3v.x,m3.x), fmaf(e3.y,s3v.y,m3.y), fmaf(e3.z,s3v.z,m3.z), fmaf(e3.w,s3v.w,m3.w));
    }

    float h1[64];
#pragma unroll 2
    for (int jg = 0; jg < 8; jg++) {
        const int j0 = jg * 8;
#pragma unroll
        for (int jj = 0; jj < 8; jj++) {
            const float4 wq0 = *(const float4*)&sWd1[(j0 + jj) * 16 + 0];
            const float4 wq1 = *(const float4*)&sWd1[(j0 + jj) * 16 + 4];
            const float4 wq2 = *(const float4*)&sWd1[(j0 + jj) * 16 + 8];
            const float4 wq3 = *(const float4*)&sWd1[(j0 + jj) * 16 + 12];
            float v = sBd1[j0 + jj];
            v = FMA4(zA.x, zA.y, zA.z, zA.w, wq0, v);
            v = FMA4(zB.x, zB.y, zB.z, zB.w, wq1, v);
            v = FMA4(zC.x, zC.y, zC.z, zC.w, wq2, v);
            v = FMA4(zD.x, zD.y, zD.z, zD.w, wq3, v);
            h1[j0 + jj] = fmaxf(v, 0.f);
        }
    }

#pragma unroll
    for (int j = 0; j < 64; j++) {
        float s = wred(h1[j]), ss = wred(h1[j] * h1[j]);
        if (lane == 0) { sRed[wid][2 * j] = s; sRed[wid][2 * j + 1] = ss; }
    }
    __syncthreads();
    if (tid < 64) {
        const float s  = sRed[0][2 * tid] + sRed[1][2 * tid] + sRed[2][2 * tid] + sRed[3][2 * tid];
        const float ss = sRed[0][2 * tid + 1] + sRed[1][2 * tid + 1] + sRed[2][2 * tid + 1] + sRed[3][2 * tid + 1];
        const float m = s * (1.f / 256.f);
        const float var = fmaf(-m, m, ss * (1.f / 256.f));
        sM1[tid] = m; sS1[tid] = gd1[tid] * rsqrtf(var + 1e-5f); sE1[tid] = bed1[tid];
    }
    __syncthreads();
#pragma unroll
    for (int j = 0; j < 64; j++) h1[j] = fmaf(h1[j] - sM1[j], sS1[j], sE1[j]);

    float h2g[32];
#pragma unroll 1
    for (int icg = 0; icg < 4; icg++) {
        const int ic0 = icg * 8;
        float acc[8];
#pragma unroll
        for (int jj = 0; jj < 8; jj++) acc[jj] = sBd2g[ic0 + jj];
#pragma unroll 2
        for (int k4 = 0; k4 < 16; k4++) {
#pragma unroll
            for (int jj = 0; jj < 8; jj++) {
                const float4 wv = *(const float4*)&sWd2g[(ic0 + jj) * 64 + 4 * k4];
                acc[jj] = FMA4(h1[4*k4], h1[4*k4+1], h1[4*k4+2], h1[4*k4+3], wv, acc[jj]);
            }
        }
#pragma unroll
        for (int jj = 0; jj < 8; jj++) h2g[ic0 + jj] = fmaxf(acc[jj], 0.f);
    }

#pragma unroll
    for (int ic = 0; ic < 32; ic++) {
        float s = wred(h2g[ic]), ss = wred(h2g[ic] * h2g[ic]);
        if (lane == 0) { sRed[wid][2 * ic] = s; sRed[wid][2 * ic + 1] = ss; }
    }
    __syncthreads();
    if (tid < 32) {
        const float s  = sRed[0][2 * tid] + sRed[1][2 * tid] + sRed[2][2 * tid] + sRed[3][2 * tid];
        const float ss = sRed[0][2 * tid + 1] + sRed[1][2 * tid + 1] + sRed[2][2 * tid + 1] + sRed[3][2 * tid + 1];
        const float m = s * (1.f / 256.f);
        const float var = fmaf(-m, m, ss * (1.f / 256.f));
        sM2[tid] = m;
        sS2[tid] = gd2[4 * tid + g] * rsqrtf(var + 1e-5f);
        sE2[tid] = bed2[4 * tid + g];
    }
    __syncthreads();
#pragma unroll
    for (int ic = 0; ic < 32; ic++) h2g[ic] = fmaf(h2g[ic] - sM2[ic], sS2[ic], sE2[ic]);

    {
        float* dst = ws_h2n + (((size_t)(tp * 4 + g) * 256 + b) * 32);
#pragma unroll
        for (int ic = 0; ic < 32; ic += 4)
            *(float4*)&dst[ic] = make_float4(h2g[ic], h2g[ic + 1], h2g[ic + 2], h2g[ic + 3]);
    }

    float ls[16], lss[16];
#pragma unroll
    for (int i = 0; i < 16; i++) { ls[i] = 0.f; lss[i] = 0.f; }
#pragma unroll 1
    for (int dp = 0; dp < 4; dp++) {
#pragma unroll
        for (int og = 0; og < 4; og++) {
            float acc[4];
#pragma unroll
            for (int jj = 0; jj < 4; jj++) acc[jj] = sBt1[og * 4 + jj];
#pragma unroll
            for (int i4 = 0; i4 < 8; i4++) {
#pragma unroll
                for (int jj = 0; jj < 4; jj++) {
                    const float4 wv = *(const float4*)&sWt1g[(dp * 16 + og * 4 + jj) * 32 + 4 * i4];
                    acc[jj] = FMA4(h2g[4*i4], h2g[4*i4+1], h2g[4*i4+2], h2g[4*i4+3], wv, acc[jj]);
                }
            }
#pragma unroll
            for (int jj = 0; jj < 4; jj++) {
                const float v = fmaxf(acc[jj], 0.f);
                ls[og * 4 + jj] += v; lss[og * 4 + jj] = fmaf(v, v, lss[og * 4 + jj]);
            }
        }
    }
#pragma unroll
    for (int oc = 0; oc < 16; oc++) {
        float s = wred(ls[oc]), ss = wred(lss[oc]);
        if (lane == 0) { sRed[wid][2 * oc] = s; sRed[wid][2 * oc + 1] = ss; }
    }
    __syncthreads();
    if (tid < 16) {
        const float s  = sRed[0][2 * tid] + sRed[1][2 * tid] + sRed[2][2 * tid] + sRed[3][2 * tid];
        const float ss = sRed[0][2 * tid + 1] + sRed[1][2 * tid + 1] + sRed[2][2 * tid + 1] + sRed[3][2 * tid + 1];
        ws_p3[(tp * 4 + g) * 32 + 2 * tid + 0] = s;
        ws_p3[(tp * 4 + g) * 32 + 2 * tid + 1] = ss;
    }
}

// ==================== Kernel 3: BN3 finalize + convT1 recompute + convT2 + nll ====================
extern "C" __global__ void __launch_bounds__(256)
k_dec2(const float* __restrict__ x,    const int* __restrict__ pos,
       const float* __restrict__ Wt1,  const float* __restrict__ bt1,
       const float* __restrict__ gt1,  const float* __restrict__ bet1,
       const float* __restrict__ Wt2,  const float* __restrict__ bt2,
       float* __restrict__ out,
       const float* __restrict__ ws_h2n, const float* __restrict__ ws_p3)
{
    const int tp = blockIdx.x >> 2, g = blockIdx.x & 3;
    const int tid = threadIdx.x, b = tid;
    const int wid = tid >> 6, lane = tid & 63;

    __shared__ __align__(16) float sWt1g[2048];
    __shared__ __align__(16) float sWt2[192];
    __shared__ float sBt1[16], sBt2[3];
    __shared__ float sRed[4][64];
    __shared__ float sM3[16], sS3[16], sE3[16];

    for (int i = tid; i < 2048; i += 256) {
        const int dp = i >> 9, rem = i & 511, oc = rem >> 5, ic = i & 31;
        const int py = (g >> 1) * 2 + (dp >> 1), px = (g & 1) * 2 + (dp & 1);
        const int k9 = ((py + 1) % 3) * 3 + ((px + 1) % 3);
        sWt1g[(dp * 16 + oc) * 32 + ic] = Wt1[ic * 144 + oc * 9 + k9];
    }
    if (tid < 192) { const int ic = tid / 12, r = tid % 12; sWt2[r * 16 + ic] = Wt2[tid]; }
    if (tid < 16) sBt1[tid] = bt1[tid];
    if (tid < 3) sBt2[tid] = bt2[tid];
    if (tid < 16) {
        float s = 0.f, ss = 0.f;
#pragma unroll
        for (int gg = 0; gg < 4; gg++) {
            s  += ws_p3[(tp * 4 + gg) * 32 + 2 * tid + 0];
            ss += ws_p3[(tp * 4 + gg) * 32 + 2 * tid + 1];
        }
        const float m = s * (1.f / 4096.f);
        const float var = fmaf(-m, m, ss * (1.f / 4096.f));
        sM3[tid] = m; sS3[tid] = gt1[tid] * rsqrtf(var + 1e-5f); sE3[tid] = bet1[tid];
    }
    __syncthreads();

    float h2g[32];
    {
        const float* src = ws_h2n + (((size_t)(tp * 4 + g) * 256 + b) * 32);
#pragma unroll
        for (int i4 = 0; i4 < 8; i4++) {
            const float4 v4 = *(const float4*)&src[4 * i4];
            h2g[4 * i4] = v4.x; h2g[4 * i4 + 1] = v4.y; h2g[4 * i4 + 2] = v4.z; h2g[4 * i4 + 3] = v4.w;
        }
    }

    const int t = 256 + tp;
    const int pr = 3 * pos[(b * 2 + 0) * 288 + t];
    const int pc = 3 * pos[(b * 2 + 1) * 288 + t];
    const float* xb = x + b * 3072;
    const int rbase = O_XREC + (tp * 256 + b) * 192;
    const int py0 = (g >> 1) * 2, px0 = (g & 1) * 2;
    float err = 0.f;

#pragma unroll 1
    for (int dp = 0; dp < 4; dp++) {
        const int py = py0 + (dp >> 1), px = px0 + (dp & 1);
        float hn[16];
#pragma unroll
        for (int og = 0; og < 4; og++) {
            float acc[4];
#pragma unroll
            for (int jj = 0; jj < 4; jj++) acc[jj] = sBt1[og * 4 + jj];
#pragma unroll
            for (int i4 = 0; i4 < 8; i4++) {
#pragma unroll
                for (int jj = 0; jj < 4; jj++) {
                    const float4 wv = *(const float4*)&sWt1g[(dp * 16 + og * 4 + jj) * 32 + 4 * i4];
                    acc[jj] = FMA4(h2g[4*i4], h2g[4*i4+1], h2g[4*i4+2], h2g[4*i4+3], wv, acc[jj]);
                }
            }
#pragma unroll
            for (int jj = 0; jj < 4; jj++) {
                const int oc = og * 4 + jj;
                hn[oc] = fmaf(fmaxf(acc[jj], 0.f) - sM3[oc], sS3[oc], sE3[oc]);
            }
        }
#pragma unroll
        for (int c = 0; c < 3; c++)
#pragma unroll
        for (int dy = 0; dy < 2; dy++)
#pragma unroll
        for (int dx = 0; dx < 2; dx++) {
            const float* wp = &sWt2[(c * 4 + dy * 2 + dx) * 16];
            float v = sBt2[c];
#pragma unroll
            for (int ic = 0; ic < 16; ic += 4) {
                const float4 wq = *(const float4*)&wp[ic];
                v = FMA4(hn[ic], hn[ic + 1], hn[ic + 2], hn[ic + 3], wq, v);
            }
            v = sigm(v);
            const int oy = 2 * py + dy, ox = 2 * px + dx;
            out[rbase + c * 64 + oy * 8 + ox] = v;
            const float d = v - xb[c * 1024 + (pr + oy) * 32 + (pc + ox)];
            err = fmaf(d, d, err);
        }
    }

    const float es = wred(err);
    if (lane == 0) sRed[wid][0] = es;
    __syncthreads();
    if (tid == 0)
        atomicAdd(&out[O_NLL], sRed[0][0] + sRed[1][0] + sRed[2][0] + sRed[3][0]);
}

// ==================== host ====================
extern "C" void kernel_launch(void* const* d_in, const int* in_sizes, int n_in,
                              void* d_out, int out_size, void* d_ws, size_t ws_size,
                              hipStream_t stream)
{
    const float* x    = (const float*)d_in[0];
    const float* act  = (const float*)d_in[1];
    const int*   pos  = (const int*)d_in[2];
    const float* s0   = (const float*)d_in[3];
    const float* nobs = (const float*)d_in[4];
    const float* nprd = (const float*)d_in[5];
    const float* eps  = (const float*)d_in[6];
    const float* Wa   = (const float*)d_in[7];
    const float* Ws1  = (const float*)d_in[8];
    const float* bs1  = (const float*)d_in[9];
    const float* Ws2  = (const float*)d_in[10];
    const float* bs2  = (const float*)d_in[11];
    const float* Wc1  = (const float*)d_in[12];
    const float* bc1  = (const float*)d_in[13];
    const float* g1   = (const float*)d_in[14];
    const float* be1  = (const float*)d_in[15];
    const float* Wc2  = (const float*)d_in[16];
    const float* bc2  = (const float*)d_in[17];
    const float* g2   = (const float*)d_in[18];
    const float* be2  = (const float*)d_in[19];
    const float* Wzm  = (const float*)d_in[20];
    const float* bzm  = (const float*)d_in[21];
    const float* Wzs  = (const float*)d_in[22];
    const float* bzs  = (const float*)d_in[23];
    const float* Wd1  = (const float*)d_in[24];
    const float* bd1  = (const float*)d_in[25];
    const float* gd1  = (const float*)d_in[26];
    const float* bed1 = (const float*)d_in[27];
    const float* Wd2  = (const float*)d_in[28];
    const float* bd2  = (const float*)d_in[29];
    const float* gd2  = (const float*)d_in[30];
    const float* bed2 = (const float*)d_in[31];
    const float* Wt1  = (const float*)d_in[32];
    const float* bt1  = (const float*)d_in[33];
    const float* gt1  = (const float*)d_in[34];
    const float* bet1 = (const float*)d_in[35];
    const float* Wt2  = (const float*)d_in[36];
    const float* bt2  = (const float*)d_in[37];
    float* out = (float*)d_out;
    float* ws  = (float*)d_ws;

    const size_t need_fast = (POOL_FLOATS + 147456) * sizeof(float);  // 19.46 MB

    if (ws_size >= need_fast) {
        // fast path: pool staged in ws; U beyond pool; H2N/P3 reuse pool region after k_enc
        float* ws_pool = ws;
        float* ws_u    = ws + POOL_FLOATS;
        float* ws_h2n  = ws;                 // written by k_dec1 (after k_enc consumed pool)
        float* ws_p3   = ws + 1048576;

        k_pre<<<dim3(256), dim3(288), 0, stream>>>(act, Wa, ws_u);
        k_patch<<<dim3(1281), dim3(256), 0, stream>>>(
            x, pos, s0, nobs, nprd, Ws1, bs1, Ws2, bs2, Wc1, bc1, ws_u, ws_pool, out);
        k_enc<<<dim3(288), dim3(256), 0, stream>>>(
            g1, be1, Wc2, bc2, g2, be2, Wzm, bzm, Wzs, bzs, ws_pool, out);
        k_dec1<<<dim3(128), dim3(256), 0, stream>>>(
            eps, Wd1, bd1, gd1, bed1, Wd2, bd2, gd2, bed2, Wt1, bt1, out, ws_h2n, ws_p3);
        k_dec2<<<dim3(128), dim3(256), 0, stream>>>(
            x, pos, Wt1, bt1, gt1, bet1, Wt2, bt2, out, ws_h2n, ws_p3);
    } else {
        // fallback: 4.8 MB layout (validated in rounds 2-5)
        float* ws_u   = ws;
        float* ws_h2n = ws + 147456;
        float* ws_p3  = ws + 1196032;

        k_pre<<<dim3(256), dim3(288), 0, stream>>>(act, Wa, ws_u);
        k_enc_full<<<dim3(289), dim3(256), 0, stream>>>(
            x, pos, s0, nobs, nprd, Ws1, bs1, Ws2, bs2,
            Wc1, bc1, g1, be1, Wc2, bc2, g2, be2, Wzm, bzm, Wzs, bzs, ws_u, out);
        k_dec1<<<dim3(128), dim3(256), 0, stream>>>(
            eps, Wd1, bd1, gd1, bed1, Wd2, bd2, gd2, bed2, Wt1, bt1, out, ws_h2n, ws_p3);
        k_dec2<<<dim3(128), dim3(256), 0, stream>>>(
            x, pos, Wt1, bt1, gt1, bet1, Wt2, bt2, out, ws_h2n, ws_p3);
    }
}

// Round 8
// 272.753 us; speedup vs baseline: 1.8252x; 1.2314x over previous
//
#include <hip/hip_runtime.h>
#include <hip/hip_bf16.h>
#include <math.h>

// ---------------- problem constants ----------------
#define NB   256
#define NT   288
#define NOBS 256
#define NTP  32

// output offsets (floats)
#define O_ST_OBS   0
#define O_ST_PRED  131072
#define O_ZM_OBS   147456
#define O_ZS_OBS   1196032
#define O_ZM_PRED  2244608
#define O_ZS_PRED  2375680
#define O_XREC     2506752
#define O_NLL      4079616

#define POOL_FLOATS ((size_t)288 * 256 * 64)   // 4,718,592 floats = 18.9 MB

__device__ __forceinline__ float wred(float v) {
    v += __shfl_down(v, 32); v += __shfl_down(v, 16); v += __shfl_down(v, 8);
    v += __shfl_down(v, 4);  v += __shfl_down(v, 2);  v += __shfl_down(v, 1);
    return v;
}
__device__ __forceinline__ float sigm(float x) { return 1.0f / (1.0f + __expf(-x)); }

// fast reciprocal (v_rcp_f32, ~1 ulp) with safe fallback
__device__ __forceinline__ float frcp(float x) {
#if __has_builtin(__builtin_amdgcn_rcpf)
    return __builtin_amdgcn_rcpf(x);
#else
    return 1.0f / x;
#endif
}
__device__ __forceinline__ float tanh_fast(float x) {
    x = fminf(fmaxf(x, -15.0f), 15.0f);
    return fmaf(-2.0f, frcp(__expf(2.0f * x) + 1.0f), 1.0f);
}
__device__ __forceinline__ float sigm_fast(float x) {
    return frcp(1.0f + __expf(-x));
}

// NOTE: no macro parameter may be named x/y/z/w (member-access collision!)
#define FMA4(ax,ay,az,aw,wv,acc) fmaf((ax),(wv).x,fmaf((ay),(wv).y,fmaf((az),(wv).z,fmaf((aw),(wv).w,(acc)))))

// ==================== recurrence (device fn; one 256-thread block, thread = b) ====================
// depth-8 software prefetch over the coalesced [t][b] streams + rcp-based activations
__device__ __forceinline__ void run_recurrence(
    int b, const float* __restrict__ s0,
    const float* __restrict__ nobs, const float* __restrict__ npred,
    const float* __restrict__ Ws1, const float* __restrict__ bs1,
    const float* __restrict__ Ws2, const float* __restrict__ bs2,
    const float* __restrict__ ws_u, float* __restrict__ out)
{
    float w1[10], w2[10], c1[5], c2_0, c2_1;
#pragma unroll
    for (int i = 0; i < 10; i++) { w1[i] = Ws1[i]; w2[i] = Ws2[i]; }
#pragma unroll
    for (int i = 0; i < 5; i++) c1[i] = bs1[i];
    c2_0 = bs2[0]; c2_1 = bs2[1];

    float sv0 = s0[b * 2 + 0], sv1 = s0[b * 2 + 1];
    ((float2*)(out + O_ST_OBS))[b] = make_float2(sv0, sv1);
    if (b == 0) out[O_NLL] = 0.0f;   // re-zeroed every call; stream-ordered before k_dec2

    const float2* Up   = (const float2*)ws_u;
    const float2* Nobs = (const float2*)nobs;
    const float2* Nprd = (const float2*)npred;

    auto LD = [&](int t, float2& u, float2& nz) {
        t = (t > 287) ? 287 : t;              // clamp: no over-read, values unused
        u  = Up[t * 256 + b];
        nz = (t < 256) ? Nobs[(t - 1) * 256 + b] : Nprd[(t - 256) * 256 + b];
    };
    auto STEP = [&](float2 u, float2 nz, int t) {
        const float v0 = sv0 + u.x, v1 = sv1 + u.y;
        const float h0 = tanh_fast(fmaf(v1, w1[1], fmaf(v0, w1[0], c1[0])));
        const float h1 = tanh_fast(fmaf(v1, w1[3], fmaf(v0, w1[2], c1[1])));
        const float h2 = tanh_fast(fmaf(v1, w1[5], fmaf(v0, w1[4], c1[2])));
        const float h3 = tanh_fast(fmaf(v1, w1[7], fmaf(v0, w1[6], c1[3])));
        const float h4 = tanh_fast(fmaf(v1, w1[9], fmaf(v0, w1[8], c1[4])));
        float a0 = fmaf(h0, w2[0], fmaf(h1, w2[1], c2_0));
        const float a0b = fmaf(h2, w2[2], h3 * w2[3]);
        a0 = fmaf(h4, w2[4], a0 + a0b);
        float a1 = fmaf(h0, w2[5], fmaf(h1, w2[6], c2_1));
        const float a1b = fmaf(h2, w2[7], h3 * w2[8]);
        a1 = fmaf(h4, w2[9], a1 + a1b);
        sv0 = fmaf(u.x, sigm_fast(a0), sv0) + nz.x;
        sv1 = fmaf(u.y, sigm_fast(a1), sv1) + nz.y;
        if (t < 256) ((float2*)(out + O_ST_OBS))[t * 256 + b] = make_float2(sv0, sv1);
        else         ((float2*)(out + O_ST_PRED))[(t - 256) * 256 + b] = make_float2(sv0, sv1);
    };

    float2 cu[8], cn[8];
#pragma unroll
    for (int j = 0; j < 8; j++) LD(1 + j, cu[j], cn[j]);

#pragma unroll 1
    for (int base = 1; base < 288; base += 8) {
        float2 nu[8], nn[8];
#pragma unroll
        for (int j = 0; j < 8; j++) LD(base + 8 + j, nu[j], nn[j]);   // 16 loads in flight
#pragma unroll
        for (int j = 0; j < 8; j++) {
            if (base + j < 288) STEP(cu[j], cn[j], base + j);
        }
#pragma unroll
        for (int j = 0; j < 8; j++) { cu[j] = nu[j]; cn[j] = nn[j]; }
    }
}

// ==================== Kernel 0: U[t][b][2] = act^T . Wa ====================
extern "C" __global__ void __launch_bounds__(288)
k_pre(const float* __restrict__ act, const float* __restrict__ Wa, float* __restrict__ ws_u)
{
    const int b = blockIdx.x;     // 0..255
    const int t = threadIdx.x;    // 0..287
    float u0 = 0.f, u1 = 0.f;
#pragma unroll
    for (int a = 0; a < 5; a++) {
        const float av = act[(b * 5 + a) * 288 + t];
        u0 = fmaf(av, Wa[a], u0);
        u1 = fmaf(av, Wa[5 + a], u1);
    }
    ws_u[(t * 256 + b) * 2 + 0] = u0;
    ws_u[(t * 256 + b) * 2 + 1] = u1;
}

// ==================== Kernel 1a (fast path): conv1+maxpool, work = (b, t, posq) ====================
// grid 1 + 256*5: block 0 = recurrence; else b = (bid-1)/5, t-chunk c = (bid-1)%5
// thread: t_local = tid>>2 (0..63), posq = tid&3. pool layout: [b][t][posq][16]
extern "C" __global__ void __launch_bounds__(256)
k_patch(const float* __restrict__ x, const int* __restrict__ pos,
        const float* __restrict__ s0, const float* __restrict__ nobs,
        const float* __restrict__ npred,
        const float* __restrict__ Ws1, const float* __restrict__ bs1,
        const float* __restrict__ Ws2, const float* __restrict__ bs2,
        const float* __restrict__ Wc1, const float* __restrict__ bc1,
        const float* __restrict__ ws_u, float* __restrict__ ws_pool,
        float* __restrict__ out)
{
    const int tid = threadIdx.x;
    if (blockIdx.x == 0) {
        run_recurrence(tid, s0, nobs, npred, Ws1, bs1, Ws2, bs2, ws_u, out);
        return;
    }
    const int bid = blockIdx.x - 1;
    const int b = bid / 5, c = bid % 5;

    __shared__ __align__(16) float sImg[3 * 1056];   // rows padded to stride 33
    __shared__ float sWc1[192];
    __shared__ float sB1[16];

    for (int i = tid; i < 3072; i += 256) {
        const int ic = i >> 10, r = (i >> 5) & 31, cc = i & 31;
        sImg[ic * 1056 + r * 33 + cc] = x[b * 3072 + i];
    }
    if (tid < 192) sWc1[tid] = Wc1[tid];
    if (tid < 16) sB1[tid] = bc1[tid];
    __syncthreads();

    const int t = c * 64 + (tid >> 2);
    if (t >= 288) return;                 // c==4 chunk has 32 t's
    const int posq = tid & 3;
    const int py = posq >> 1, px = posq & 1;

    const int pr = 3 * pos[(b * 2 + 0) * 288 + t];
    const int pc = 3 * pos[(b * 2 + 1) * 288 + t];

    float p16[16];
#pragma unroll
    for (int i = 0; i < 16; i++) p16[i] = 0.f;       // relu >= 0 => 0-init == true max

#pragma unroll 2
    for (int d = 0; d < 4; d++) {
        const int rbase = pr + 4 * py + 2 * (d >> 1);
        const int cbase = pc + 4 * px + 2 * (d & 1);
        float in[12];
#pragma unroll
        for (int ic = 0; ic < 3; ic++)
#pragma unroll
        for (int ky = 0; ky < 2; ky++)
#pragma unroll
        for (int kx = 0; kx < 2; kx++)
            in[ic * 4 + ky * 2 + kx] = sImg[ic * 1056 + (rbase + ky) * 33 + (cbase + kx)];
#pragma unroll
        for (int oc = 0; oc < 16; oc++) {
            const float4 wq0 = *(const float4*)&sWc1[oc * 12 + 0];
            const float4 wq1 = *(const float4*)&sWc1[oc * 12 + 4];
            const float4 wq2 = *(const float4*)&sWc1[oc * 12 + 8];
            float v = sB1[oc];
            v = FMA4(in[0], in[1], in[2], in[3], wq0, v);
            v = FMA4(in[4], in[5], in[6], in[7], wq1, v);
            v = FMA4(in[8], in[9], in[10], in[11], wq2, v);
            p16[oc] = fmaxf(p16[oc], fmaxf(v, 0.f));
        }
    }

    float4* dst = (float4*)(ws_pool + (((size_t)b * 288 + t) * 4 + posq) * 16);
    dst[0] = make_float4(p16[0], p16[1], p16[2], p16[3]);
    dst[1] = make_float4(p16[4], p16[5], p16[6], p16[7]);
    dst[2] = make_float4(p16[8], p16[9], p16[10], p16[11]);
    dst[3] = make_float4(p16[12], p16[13], p16[14], p16[15]);
}

// ==================== Kernel 1b (fast path): BN1 + conv2 + BN2 + heads ====================
// grid 288: block = timestep t; thread = batch b. pooled row layout: [pos(4)][ch(16)]
extern "C" __global__ void __launch_bounds__(256)
k_enc(const float* __restrict__ g1,   const float* __restrict__ be1,
      const float* __restrict__ Wc2,  const float* __restrict__ bc2,
      const float* __restrict__ g2,   const float* __restrict__ be2,
      const float* __restrict__ Wzm,  const float* __restrict__ bzm,
      const float* __restrict__ Wzs,  const float* __restrict__ bzs,
      const float* __restrict__ ws_pool, float* __restrict__ out)
{
    const int t = blockIdx.x, tid = threadIdx.x, b = tid;
    const int wid = tid >> 6, lane = tid & 63;

    __shared__ __align__(16) float pooledL[256 * 68];   // [b][pos*16+ch], stride 68
    __shared__ __align__(16) float sWc2r[2048];          // remapped [oc][q][ic]
    __shared__ __align__(16) float sWzm[512];
    __shared__ __align__(16) float sWzs[512];
    __shared__ __align__(16) float sM1[16], sS1[16], sE1[16];
    __shared__ float sB2[32], sE2[32], sBzm[16], sBzs[16];
    __shared__ float sM2[32], sS2[32];
    __shared__ float sRed[4][64];

    for (int i = tid; i < 2048; i += 256) {
        const int oc = i >> 6, rem = i & 63, ic = rem >> 2, q = rem & 3;
        sWc2r[oc * 64 + q * 16 + ic] = Wc2[i];
    }
    for (int i = tid; i < 512; i += 256) { sWzm[i] = Wzm[i]; sWzs[i] = Wzs[i]; }
    if (tid < 16) { sE1[tid] = be1[tid]; sBzm[tid] = bzm[tid]; sBzs[tid] = bzs[tid]; }
    if (tid < 32) { sB2[tid] = bc2[tid]; sE2[tid] = be2[tid]; }

    // load my pooled row (64 floats, [pos][ch]) from ws ([b][t] layout)
    float* myrow = &pooledL[b * 68];
    {
        const float4* src = (const float4*)(ws_pool + ((size_t)b * 288 + t) * 64);
#pragma unroll
        for (int q = 0; q < 16; q++) *(float4*)&myrow[4 * q] = src[q];
    }
    __syncthreads();

    // ---- BN1 stats: per channel over (b, 4 pos) = 1024; column partial sums ----
    {
        const int col = tid & 63, q = tid >> 6;
        float s = 0.f, ss = 0.f;
        const float* cp = &pooledL[(q * 64) * 68 + col];
#pragma unroll 4
        for (int i = 0; i < 64; i++) { const float v = cp[i * 68]; s += v; ss = fmaf(v, v, ss); }
        sRed[q][col] = s;
        __syncthreads();
        float ssum = 0.f;
        if (tid < 16) {
#pragma unroll
            for (int p = 0; p < 4; p++)
#pragma unroll
            for (int qq = 0; qq < 4; qq++) ssum += sRed[qq][p * 16 + tid];
        }
        __syncthreads();
        sRed[q][col] = ss;
        __syncthreads();
        if (tid < 16) {
            float sssum = 0.f;
#pragma unroll
            for (int p = 0; p < 4; p++)
#pragma unroll
            for (int qq = 0; qq < 4; qq++) sssum += sRed[qq][p * 16 + tid];
            const float m = ssum * (1.f / 1024.f);
            const float var = fmaf(-m, m, sssum * (1.f / 1024.f));
            sM1[tid] = m; sS1[tid] = g1[tid] * rsqrtf(var + 1e-5f);
        }
    }
    __syncthreads();

    // ---- normalize own row (quad tq: ch-quad = tq&3) ----
#pragma unroll 4
    for (int tq = 0; tq < 16; tq++) {
        const int ic0 = (tq & 3) * 4;
        float4 v = *(float4*)&myrow[4 * tq];
        const float4 mq = *(const float4*)&sM1[ic0];
        const float4 sq = *(const float4*)&sS1[ic0];
        const float4 eq = *(const float4*)&sE1[ic0];
        v.x = fmaf(v.x - mq.x, sq.x, eq.x);
        v.y = fmaf(v.y - mq.y, sq.y, eq.y);
        v.z = fmaf(v.z - mq.z, sq.z, eq.z);
        v.w = fmaf(v.w - mq.w, sq.w, eq.w);
        *(float4*)&myrow[4 * tq] = v;
    }

    // ---- conv2 (16ch x 4pos -> 32) + relu, register-blocked JB=8 ----
    float h2v[32];
#pragma unroll
    for (int og = 0; og < 4; og++) {
        float acc[8];
#pragma unroll
        for (int jj = 0; jj < 8; jj++) acc[jj] = sB2[og * 8 + jj];
#pragma unroll 2
        for (int tq = 0; tq < 16; tq++) {
            const float4 hq = *(const float4*)&myrow[4 * tq];
#pragma unroll
            for (int jj = 0; jj < 8; jj++) {
                const float4 wv = *(const float4*)&sWc2r[(og * 8 + jj) * 64 + 4 * tq];
                acc[jj] = FMA4(hq.x, hq.y, hq.z, hq.w, wv, acc[jj]);
            }
        }
#pragma unroll
        for (int jj = 0; jj < 8; jj++) h2v[og * 8 + jj] = fmaxf(acc[jj], 0.f);
    }

    // ---- BN2: per-channel over b (single-pass wred; 32ch -> 64 slots) ----
#pragma unroll
    for (int oc = 0; oc < 32; oc++) {
        float s = wred(h2v[oc]), ss = wred(h2v[oc] * h2v[oc]);
        if (lane == 0) { sRed[wid][2 * oc] = s; sRed[wid][2 * oc + 1] = ss; }
    }
    __syncthreads();
    if (tid < 32) {
        const float s  = sRed[0][2 * tid] + sRed[1][2 * tid] + sRed[2][2 * tid] + sRed[3][2 * tid];
        const float ss = sRed[0][2 * tid + 1] + sRed[1][2 * tid + 1] + sRed[2][2 * tid + 1] + sRed[3][2 * tid + 1];
        const float m = s * (1.f / 256.f);
        const float var = fmaf(-m, m, ss * (1.f / 256.f));
        sM2[tid] = m; sS2[tid] = g2[tid] * rsqrtf(var + 1e-5f);
    }
    __syncthreads();
#pragma unroll
    for (int oc = 0; oc < 32; oc++) h2v[oc] = fmaf(h2v[oc] - sM2[oc], sS2[oc], sE2[oc]);

    // ---- zm / zs heads (32 -> 16 each) ----
    const int obase_m = (t < 256) ? (O_ZM_OBS + (t * 256 + b) * 16) : (O_ZM_PRED + ((t - 256) * 256 + b) * 16);
    const int obase_s = (t < 256) ? (O_ZS_OBS + (t * 256 + b) * 16) : (O_ZS_PRED + ((t - 256) * 256 + b) * 16);
#pragma unroll 2
    for (int k = 0; k < 16; k++) {
        float vm = sBzm[k], vs = sBzs[k];
#pragma unroll
        for (int c = 0; c < 32; c += 4) {
            const float4 wm = *(const float4*)&sWzm[k * 32 + c];
            const float4 wsq = *(const float4*)&sWzs[k * 32 + c];
            vm = FMA4(h2v[c], h2v[c + 1], h2v[c + 2], h2v[c + 3], wm, vm);
            vs = FMA4(h2v[c], h2v[c + 1], h2v[c + 2], h2v[c + 3], wsq, vs);
        }
        out[obase_m + k] = vm;
        out[obase_s + k] = __expf(vs);
    }
}

// ==================== Kernel 1 (fallback): fused encoder with global gathers (R4-proven) ====================
extern "C" __global__ void __launch_bounds__(256)
k_enc_full(const float* __restrict__ x,
           const int*   __restrict__ pos,  const float* __restrict__ s0,
           const float* __restrict__ nobs, const float* __restrict__ npred,
           const float* __restrict__ Ws1,  const float* __restrict__ bs1,
           const float* __restrict__ Ws2,  const float* __restrict__ bs2,
           const float* __restrict__ Wc1,  const float* __restrict__ bc1,
           const float* __restrict__ g1,   const float* __restrict__ be1,
           const float* __restrict__ Wc2,  const float* __restrict__ bc2,
           const float* __restrict__ g2,   const float* __restrict__ be2,
           const float* __restrict__ Wzm,  const float* __restrict__ bzm,
           const float* __restrict__ Wzs,  const float* __restrict__ bzs,
           const float* __restrict__ ws_u, float* __restrict__ out)
{
    const int tid = threadIdx.x;
    if (blockIdx.x == 0) {
        run_recurrence(tid, s0, nobs, npred, Ws1, bs1, Ws2, bs2, ws_u, out);
        return;
    }
    const int t = blockIdx.x - 1;
    __shared__ __align__(16) float sWc1[192];
    __shared__ __align__(16) float sWc2r[2048];
    __shared__ __align__(16) float sWzm[512];
    __shared__ __align__(16) float sWzs[512];
    __shared__ __align__(16) float sM1[16], sS1[16], sE1[16];
    __shared__ float sB1[16], sB2[32], sE2[32], sBzm[16], sBzs[16];
    __shared__ float sM2[32], sS2[32];
    __shared__ float sRed[4][64];
    __shared__ __align__(16) float pooledL[256 * 68];

    for (int i = tid; i < 192; i += 256) sWc1[i] = Wc1[i];
    for (int i = tid; i < 2048; i += 256) {
        const int oc = i >> 6, rem = i & 63, ic = rem >> 2, q = rem & 3;
        sWc2r[oc * 64 + q * 16 + ic] = Wc2[i];
    }
    for (int i = tid; i < 512; i += 256) { sWzm[i] = Wzm[i]; sWzs[i] = Wzs[i]; }
    if (tid < 16) { sB1[tid] = bc1[tid]; sE1[tid] = be1[tid]; sBzm[tid] = bzm[tid]; sBzs[tid] = bzs[tid]; }
    if (tid < 32) { sB2[tid] = bc2[tid]; sE2[tid] = be2[tid]; }
    __syncthreads();

    const int b = tid;
    const int wid = tid >> 6, lane = tid & 63;
    const float* xb = x + b * 3072;
    const int pr = 3 * pos[(b * 2 + 0) * 288 + t];
    const int pc = 3 * pos[(b * 2 + 1) * 288 + t];
    float* myrow = &pooledL[b * 68];

#pragma unroll
    for (int py = 0; py < 2; py++)
#pragma unroll
    for (int px = 0; px < 2; px++) {
        float p16[16];
#pragma unroll
        for (int i = 0; i < 16; i++) p16[i] = 0.f;
#pragma unroll 2
        for (int d = 0; d < 4; d++) {
            const int rbase = pr + 4 * py + 2 * (d >> 1);
            const int cbase = pc + 4 * px + 2 * (d & 1);
            float in[12];
#pragma unroll
            for (int ic = 0; ic < 3; ic++)
#pragma unroll
            for (int ky = 0; ky < 2; ky++)
#pragma unroll
            for (int kx = 0; kx < 2; kx++)
                in[ic * 4 + ky * 2 + kx] = xb[ic * 1024 + (rbase + ky) * 32 + (cbase + kx)];
#pragma unroll
            for (int oc = 0; oc < 16; oc++) {
                const float4 wq0 = *(const float4*)&sWc1[oc * 12 + 0];
                const float4 wq1 = *(const float4*)&sWc1[oc * 12 + 4];
                const float4 wq2 = *(const float4*)&sWc1[oc * 12 + 8];
                float v = sB1[oc];
                v = FMA4(in[0], in[1], in[2], in[3], wq0, v);
                v = FMA4(in[4], in[5], in[6], in[7], wq1, v);
                v = FMA4(in[8], in[9], in[10], in[11], wq2, v);
                p16[oc] = fmaxf(p16[oc], fmaxf(v, 0.f));
            }
        }
        const int pbase = (py * 2 + px) * 16;
        *(float4*)&myrow[pbase + 0]  = make_float4(p16[0], p16[1], p16[2], p16[3]);
        *(float4*)&myrow[pbase + 4]  = make_float4(p16[4], p16[5], p16[6], p16[7]);
        *(float4*)&myrow[pbase + 8]  = make_float4(p16[8], p16[9], p16[10], p16[11]);
        *(float4*)&myrow[pbase + 12] = make_float4(p16[12], p16[13], p16[14], p16[15]);
    }
    __syncthreads();

    // BN1 column partials (two LDS rounds via sRed[4][64])
    {
        const int col = tid & 63, q = tid >> 6;
        float s = 0.f, ss = 0.f;
        const float* cp = &pooledL[(q * 64) * 68 + col];
#pragma unroll 4
        for (int i = 0; i < 64; i++) { const float v = cp[i * 68]; s += v; ss = fmaf(v, v, ss); }
        sRed[q][col] = s;
        __syncthreads();
        float ssum = 0.f;
        if (tid < 16) {
#pragma unroll
            for (int p = 0; p < 4; p++)
#pragma unroll
            for (int qq = 0; qq < 4; qq++) ssum += sRed[qq][p * 16 + tid];
        }
        __syncthreads();
        sRed[q][col] = ss;
        __syncthreads();
        if (tid < 16) {
            float sssum = 0.f;
#pragma unroll
            for (int p = 0; p < 4; p++)
#pragma unroll
            for (int qq = 0; qq < 4; qq++) sssum += sRed[qq][p * 16 + tid];
            const float m = ssum * (1.f / 1024.f);
            const float var = fmaf(-m, m, sssum * (1.f / 1024.f));
            sM1[tid] = m; sS1[tid] = g1[tid] * rsqrtf(var + 1e-5f);
        }
    }
    __syncthreads();

#pragma unroll 4
    for (int tq = 0; tq < 16; tq++) {
        const int ic0 = (tq & 3) * 4;
        float4 v = *(float4*)&myrow[4 * tq];
        const float4 mq = *(const float4*)&sM1[ic0];
        const float4 sq = *(const float4*)&sS1[ic0];
        const float4 eq = *(const float4*)&sE1[ic0];
        v.x = fmaf(v.x - mq.x, sq.x, eq.x);
        v.y = fmaf(v.y - mq.y, sq.y, eq.y);
        v.z = fmaf(v.z - mq.z, sq.z, eq.z);
        v.w = fmaf(v.w - mq.w, sq.w, eq.w);
        *(float4*)&myrow[4 * tq] = v;
    }

    float h2v[32];
#pragma unroll
    for (int og = 0; og < 4; og++) {
        float acc[8];
#pragma unroll
        for (int jj = 0; jj < 8; jj++) acc[jj] = sB2[og * 8 + jj];
#pragma unroll 2
        for (int tq = 0; tq < 16; tq++) {
            const float4 hq = *(const float4*)&myrow[4 * tq];
#pragma unroll
            for (int jj = 0; jj < 8; jj++) {
                const float4 wv = *(const float4*)&sWc2r[(og * 8 + jj) * 64 + 4 * tq];
                acc[jj] = FMA4(hq.x, hq.y, hq.z, hq.w, wv, acc[jj]);
            }
        }
#pragma unroll
        for (int jj = 0; jj < 8; jj++) h2v[og * 8 + jj] = fmaxf(acc[jj], 0.f);
    }

#pragma unroll
    for (int oc = 0; oc < 32; oc++) {
        float s = wred(h2v[oc]), ss = wred(h2v[oc] * h2v[oc]);
        if (lane == 0) { sRed[wid][2 * oc] = s; sRed[wid][2 * oc + 1] = ss; }
    }
    __syncthreads();
    if (tid < 32) {
        const float s  = sRed[0][2 * tid] + sRed[1][2 * tid] + sRed[2][2 * tid] + sRed[3][2 * tid];
        const float ss = sRed[0][2 * tid + 1] + sRed[1][2 * tid + 1] + sRed[2][2 * tid + 1] + sRed[3][2 * tid + 1];
        const float m = s * (1.f / 256.f);
        const float var = fmaf(-m, m, ss * (1.f / 256.f));
        sM2[tid] = m; sS2[tid] = g2[tid] * rsqrtf(var + 1e-5f);
    }
    __syncthreads();
#pragma unroll
    for (int oc = 0; oc < 32; oc++) h2v[oc] = fmaf(h2v[oc] - sM2[oc], sS2[oc], sE2[oc]);

    const int obase_m = (t < 256) ? (O_ZM_OBS + (t * 256 + b) * 16) : (O_ZM_PRED + ((t - 256) * 256 + b) * 16);
    const int obase_s = (t < 256) ? (O_ZS_OBS + (t * 256 + b) * 16) : (O_ZS_PRED + ((t - 256) * 256 + b) * 16);
#pragma unroll 2
    for (int k = 0; k < 16; k++) {
        float vm = sBzm[k], vs = sBzs[k];
#pragma unroll
        for (int c = 0; c < 32; c += 4) {
            const float4 wm = *(const float4*)&sWzm[k * 32 + c];
            const float4 wsq = *(const float4*)&sWzs[k * 32 + c];
            vm = FMA4(h2v[c], h2v[c + 1], h2v[c + 2], h2v[c + 3], wm, vm);
            vs = FMA4(h2v[c], h2v[c + 1], h2v[c + 2], h2v[c + 3], wsq, vs);
        }
        out[obase_m + k] = vm;
        out[obase_s + k] = __expf(vs);
    }
}

// ==================== Kernel 2: z + fc1 + BN1 + fc2(g) + BN2 + convT1(g) stats ====================
// grid = 128: tp = bid>>2, quadrant g = bid&3
extern "C" __global__ void __launch_bounds__(256)
k_dec1(const float* __restrict__ eps,
       const float* __restrict__ Wd1,  const float* __restrict__ bd1,
       const float* __restrict__ gd1,  const float* __restrict__ bed1,
       const float* __restrict__ Wd2,  const float* __restrict__ bd2,
       const float* __restrict__ gd2,  const float* __restrict__ bed2,
       const float* __restrict__ Wt1,  const float* __restrict__ bt1,
       const float* __restrict__ out,
       float* __restrict__ ws_h2n, float* __restrict__ ws_p3)
{
    const int tp = blockIdx.x >> 2, g = blockIdx.x & 3;
    const int tid = threadIdx.x, b = tid;
    const int wid = tid >> 6, lane = tid & 63;

    __shared__ __align__(16) float sWd1[1024];
    __shared__ __align__(16) float sWd2g[2048];
    __shared__ __align__(16) float sWt1g[2048];
    __shared__ __align__(16) float sM1[64], sS1[64], sE1[64];
    __shared__ float sBd1[64], sBd2g[32], sBt1[16];
    __shared__ float sRed[4][128];
    __shared__ float sM2[32], sS2[32], sE2[32];

    for (int i = tid; i < 1024; i += 256) sWd1[i] = Wd1[i];
    for (int i = tid; i < 2048; i += 256) {
        const int ic = i >> 6, k = i & 63;
        sWd2g[i] = Wd2[(4 * ic + g) * 64 + k];
    }
    for (int i = tid; i < 2048; i += 256) {
        const int dp = i >> 9, rem = i & 511, oc = rem >> 5, ic = i & 31;
        const int py = (g >> 1) * 2 + (dp >> 1), px = (g & 1) * 2 + (dp & 1);
        const int k9 = ((py + 1) % 3) * 3 + ((px + 1) % 3);
        sWt1g[(dp * 16 + oc) * 32 + ic] = Wt1[ic * 144 + oc * 9 + k9];
    }
    if (tid < 64) sBd1[tid] = bd1[tid];
    if (tid < 32) sBd2g[tid] = bd2[4 * tid + g];
    if (tid < 16) sBt1[tid] = bt1[tid];
    __syncthreads();

    float4 zA, zB, zC, zD;
    {
        const int base = (tp * 256 + b) * 16;
        const float4 e0 = *(const float4*)&eps[base + 0],  e1 = *(const float4*)&eps[base + 4];
        const float4 e2 = *(const float4*)&eps[base + 8],  e3 = *(const float4*)&eps[base + 12];
        const float4 s0v = *(const float4*)&out[O_ZS_PRED + base + 0],  s1v = *(const float4*)&out[O_ZS_PRED + base + 4];
        const float4 s2v = *(const float4*)&out[O_ZS_PRED + base + 8],  s3v = *(const float4*)&out[O_ZS_PRED + base + 12];
        const float4 m0 = *(const float4*)&out[O_ZM_PRED + base + 0],  m1 = *(const float4*)&out[O_ZM_PRED + base + 4];
        const float4 m2 = *(const float4*)&out[O_ZM_PRED + base + 8],  m3 = *(const float4*)&out[O_ZM_PRED + base + 12];
        zA = make_float4(fmaf(e0.x,s0v.x,m0.x), fmaf(e0.y,s0v.y,m0.y), fmaf(e0.z,s0v.z,m0.z), fmaf(e0.w,s0v.w,m0.w));
        zB = make_float4(fmaf(e1.x,s1v.x,m1.x), fmaf(e1.y,s1v.y,m1.y), fmaf(e1.z,s1v.z,m1.z), fmaf(e1.w,s1v.w,m1.w));
        zC = make_float4(fmaf(e2.x,s2v.x,m2.x), fmaf(e2.y,s2v.y,m2.y), fmaf(e2.z,s2v.z,m2.z), fmaf(e2.w,s2v.w,m2.w));
        zD = make_float4(fmaf(e3.x,s3v.x,m3.x), fmaf(e3.y,s3v.y,m3.y), fmaf(e3.z,s3v.z,m3.z), fmaf(e3.w,s3v.w,m3.w));
    }

    float h1[64];
#pragma unroll 2
    for (int jg = 0; jg < 8; jg++) {
        const int j0 = jg * 8;
#pragma unroll
        for (int jj = 0; jj < 8; jj++) {
            const float4 wq0 = *(const float4*)&sWd1[(j0 + jj) * 16 + 0];
            const float4 wq1 = *(const float4*)&sWd1[(j0 + jj) * 16 + 4];
            const float4 wq2 = *(const float4*)&sWd1[(j0 + jj) * 16 + 8];
            const float4 wq3 = *(const float4*)&sWd1[(j0 + jj) * 16 + 12];
            float v = sBd1[j0 + jj];
            v = FMA4(zA.x, zA.y, zA.z, zA.w, wq0, v);
            v = FMA4(zB.x, zB.y, zB.z, zB.w, wq1, v);
            v = FMA4(zC.x, zC.y, zC.z, zC.w, wq2, v);
            v = FMA4(zD.x, zD.y, zD.z, zD.w, wq3, v);
            h1[j0 + jj] = fmaxf(v, 0.f);
        }
    }

#pragma unroll
    for (int j = 0; j < 64; j++) {
        float s = wred(h1[j]), ss = wred(h1[j] * h1[j]);
        if (lane == 0) { sRed[wid][2 * j] = s; sRed[wid][2 * j + 1] = ss; }
    }
    __syncthreads();
    if (tid < 64) {
        const float s  = sRed[0][2 * tid] + sRed[1][2 * tid] + sRed[2][2 * tid] + sRed[3][2 * tid];
        const float ss = sRed[0][2 * tid + 1] + sRed[1][2 * tid + 1] + sRed[2][2 * tid + 1] + sRed[3][2 * tid + 1];
        const float m = s * (1.f / 256.f);
        const float var = fmaf(-m, m, ss * (1.f / 256.f));
        sM1[tid] = m; sS1[tid] = gd1[tid] * rsqrtf(var + 1e-5f); sE1[tid] = bed1[tid];
    }
    __syncthreads();
#pragma unroll
    for (int j = 0; j < 64; j++) h1[j] = fmaf(h1[j] - sM1[j], sS1[j], sE1[j]);

    float h2g[32];
#pragma unroll 1
    for (int icg = 0; icg < 4; icg++) {
        const int ic0 = icg * 8;
        float acc[8];
#pragma unroll
        for (int jj = 0; jj < 8; jj++) acc[jj] = sBd2g[ic0 + jj];
#pragma unroll 2
        for (int k4 = 0; k4 < 16; k4++) {
#pragma unroll
            for (int jj = 0; jj < 8; jj++) {
                const float4 wv = *(const float4*)&sWd2g[(ic0 + jj) * 64 + 4 * k4];
                acc[jj] = FMA4(h1[4*k4], h1[4*k4+1], h1[4*k4+2], h1[4*k4+3], wv, acc[jj]);
            }
        }
#pragma unroll
        for (int jj = 0; jj < 8; jj++) h2g[ic0 + jj] = fmaxf(acc[jj], 0.f);
    }

#pragma unroll
    for (int ic = 0; ic < 32; ic++) {
        float s = wred(h2g[ic]), ss = wred(h2g[ic] * h2g[ic]);
        if (lane == 0) { sRed[wid][2 * ic] = s; sRed[wid][2 * ic + 1] = ss; }
    }
    __syncthreads();
    if (tid < 32) {
        const float s  = sRed[0][2 * tid] + sRed[1][2 * tid] + sRed[2][2 * tid] + sRed[3][2 * tid];
        const float ss = sRed[0][2 * tid + 1] + sRed[1][2 * tid + 1] + sRed[2][2 * tid + 1] + sRed[3][2 * tid + 1];
        const float m = s * (1.f / 256.f);
        const float var = fmaf(-m, m, ss * (1.f / 256.f));
        sM2[tid] = m;
        sS2[tid] = gd2[4 * tid + g] * rsqrtf(var + 1e-5f);
        sE2[tid] = bed2[4 * tid + g];
    }
    __syncthreads();
#pragma unroll
    for (int ic = 0; ic < 32; ic++) h2g[ic] = fmaf(h2g[ic] - sM2[ic], sS2[ic], sE2[ic]);

    {
        float* dst = ws_h2n + (((size_t)(tp * 4 + g) * 256 + b) * 32);
#pragma unroll
        for (int ic = 0; ic < 32; ic += 4)
            *(float4*)&dst[ic] = make_float4(h2g[ic], h2g[ic + 1], h2g[ic + 2], h2g[ic + 3]);
    }

    float ls[16], lss[16];
#pragma unroll
    for (int i = 0; i < 16; i++) { ls[i] = 0.f; lss[i] = 0.f; }
#pragma unroll 1
    for (int dp = 0; dp < 4; dp++) {
#pragma unroll
        for (int og = 0; og < 4; og++) {
            float acc[4];
#pragma unroll
            for (int jj = 0; jj < 4; jj++) acc[jj] = sBt1[og * 4 + jj];
#pragma unroll
            for (int i4 = 0; i4 < 8; i4++) {
#pragma unroll
                for (int jj = 0; jj < 4; jj++) {
                    const float4 wv = *(const float4*)&sWt1g[(dp * 16 + og * 4 + jj) * 32 + 4 * i4];
                    acc[jj] = FMA4(h2g[4*i4], h2g[4*i4+1], h2g[4*i4+2], h2g[4*i4+3], wv, acc[jj]);
                }
            }
#pragma unroll
            for (int jj = 0; jj < 4; jj++) {
                const float v = fmaxf(acc[jj], 0.f);
                ls[og * 4 + jj] += v; lss[og * 4 + jj] = fmaf(v, v, lss[og * 4 + jj]);
            }
        }
    }
#pragma unroll
    for (int oc = 0; oc < 16; oc++) {
        float s = wred(ls[oc]), ss = wred(lss[oc]);
        if (lane == 0) { sRed[wid][2 * oc] = s; sRed[wid][2 * oc + 1] = ss; }
    }
    __syncthreads();
    if (tid < 16) {
        const float s  = sRed[0][2 * tid] + sRed[1][2 * tid] + sRed[2][2 * tid] + sRed[3][2 * tid];
        const float ss = sRed[0][2 * tid + 1] + sRed[1][2 * tid + 1] + sRed[2][2 * tid + 1] + sRed[3][2 * tid + 1];
        ws_p3[(tp * 4 + g) * 32 + 2 * tid + 0] = s;
        ws_p3[(tp * 4 + g) * 32 + 2 * tid + 1] = ss;
    }
}

// ==================== Kernel 3: BN3 finalize + convT1 recompute + convT2 + nll ====================
extern "C" __global__ void __launch_bounds__(256)
k_dec2(const float* __restrict__ x,    const int* __restrict__ pos,
       const float* __restrict__ Wt1,  const float* __restrict__ bt1,
       const float* __restrict__ gt1,  const float* __restrict__ bet1,
       const float* __restrict__ Wt2,  const float* __restrict__ bt2,
       float* __restrict__ out,
       const float* __restrict__ ws_h2n, const float* __restrict__ ws_p3)
{
    const int tp = blockIdx.x >> 2, g = blockIdx.x & 3;
    const int tid = threadIdx.x, b = tid;
    const int wid = tid >> 6, lane = tid & 63;

    __shared__ __align__(16) float sWt1g[2048];
    __shared__ __align__(16) float sWt2[192];
    __shared__ float sBt1[16], sBt2[3];
    __shared__ float sRed[4][64];
    __shared__ float sM3[16], sS3[16], sE3[16];

    for (int i = tid; i < 2048; i += 256) {
        const int dp = i >> 9, rem = i & 511, oc = rem >> 5, ic = i & 31;
        const int py = (g >> 1) * 2 + (dp >> 1), px = (g & 1) * 2 + (dp & 1);
        const int k9 = ((py + 1) % 3) * 3 + ((px + 1) % 3);
        sWt1g[(dp * 16 + oc) * 32 + ic] = Wt1[ic * 144 + oc * 9 + k9];
    }
    if (tid < 192) { const int ic = tid / 12, r = tid % 12; sWt2[r * 16 + ic] = Wt2[tid]; }
    if (tid < 16) sBt1[tid] = bt1[tid];
    if (tid < 3) sBt2[tid] = bt2[tid];
    if (tid < 16) {
        float s = 0.f, ss = 0.f;
#pragma unroll
        for (int gg = 0; gg < 4; gg++) {
            s  += ws_p3[(tp * 4 + gg) * 32 + 2 * tid + 0];
            ss += ws_p3[(tp * 4 + gg) * 32 + 2 * tid + 1];
        }
        const float m = s * (1.f / 4096.f);
        const float var = fmaf(-m, m, ss * (1.f / 4096.f));
        sM3[tid] = m; sS3[tid] = gt1[tid] * rsqrtf(var + 1e-5f); sE3[tid] = bet1[tid];
    }
    __syncthreads();

    float h2g[32];
    {
        const float* src = ws_h2n + (((size_t)(tp * 4 + g) * 256 + b) * 32);
#pragma unroll
        for (int i4 = 0; i4 < 8; i4++) {
            const float4 v4 = *(const float4*)&src[4 * i4];
            h2g[4 * i4] = v4.x; h2g[4 * i4 + 1] = v4.y; h2g[4 * i4 + 2] = v4.z; h2g[4 * i4 + 3] = v4.w;
        }
    }

    const int t = 256 + tp;
    const int pr = 3 * pos[(b * 2 + 0) * 288 + t];
    const int pc = 3 * pos[(b * 2 + 1) * 288 + t];
    const float* xb = x + b * 3072;
    const int rbase = O_XREC + (tp * 256 + b) * 192;
    const int py0 = (g >> 1) * 2, px0 = (g & 1) * 2;
    float err = 0.f;

#pragma unroll 1
    for (int dp = 0; dp < 4; dp++) {
        const int py = py0 + (dp >> 1), px = px0 + (dp & 1);
        float hn[16];
#pragma unroll
        for (int og = 0; og < 4; og++) {
            float acc[4];
#pragma unroll
            for (int jj = 0; jj < 4; jj++) acc[jj] = sBt1[og * 4 + jj];
#pragma unroll
            for (int i4 = 0; i4 < 8; i4++) {
#pragma unroll
                for (int jj = 0; jj < 4; jj++) {
                    const float4 wv = *(const float4*)&sWt1g[(dp * 16 + og * 4 + jj) * 32 + 4 * i4];
                    acc[jj] = FMA4(h2g[4*i4], h2g[4*i4+1], h2g[4*i4+2], h2g[4*i4+3], wv, acc[jj]);
                }
            }
#pragma unroll
            for (int jj = 0; jj < 4; jj++) {
                const int oc = og * 4 + jj;
                hn[oc] = fmaf(fmaxf(acc[jj], 0.f) - sM3[oc], sS3[oc], sE3[oc]);
            }
        }
#pragma unroll
        for (int c = 0; c < 3; c++)
#pragma unroll
        for (int dy = 0; dy < 2; dy++)
#pragma unroll
        for (int dx = 0; dx < 2; dx++) {
            const float* wp = &sWt2[(c * 4 + dy * 2 + dx) * 16];
            float v = sBt2[c];
#pragma unroll
            for (int ic = 0; ic < 16; ic += 4) {
                const float4 wq = *(const float4*)&wp[ic];
                v = FMA4(hn[ic], hn[ic + 1], hn[ic + 2], hn[ic + 3], wq, v);
            }
            v = sigm(v);
            const int oy = 2 * py + dy, ox = 2 * px + dx;
            out[rbase + c * 64 + oy * 8 + ox] = v;
            const float d = v - xb[c * 1024 + (pr + oy) * 32 + (pc + ox)];
            err = fmaf(d, d, err);
        }
    }

    const float es = wred(err);
    if (lane == 0) sRed[wid][0] = es;
    __syncthreads();
    if (tid == 0)
        atomicAdd(&out[O_NLL], sRed[0][0] + sRed[1][0] + sRed[2][0] + sRed[3][0]);
}

// ==================== host ====================
extern "C" void kernel_launch(void* const* d_in, const int* in_sizes, int n_in,
                              void* d_out, int out_size, void* d_ws, size_t ws_size,
                              hipStream_t stream)
{
    const float* x    = (const float*)d_in[0];
    const float* act  = (const float*)d_in[1];
    const int*   pos  = (const int*)d_in[2];
    const float* s0   = (const float*)d_in[3];
    const float* nobs = (const float*)d_in[4];
    const float* nprd = (const float*)d_in[5];
    const float* eps  = (const float*)d_in[6];
    const float* Wa   = (const float*)d_in[7];
    const float* Ws1  = (const float*)d_in[8];
    const float* bs1  = (const float*)d_in[9];
    const float* Ws2  = (const float*)d_in[10];
    const float* bs2  = (const float*)d_in[11];
    const float* Wc1  = (const float*)d_in[12];
    const float* bc1  = (const float*)d_in[13];
    const float* g1   = (const float*)d_in[14];
    const float* be1  = (const float*)d_in[15];
    const float* Wc2  = (const float*)d_in[16];
    const float* bc2  = (const float*)d_in[17];
    const float* g2   = (const float*)d_in[18];
    const float* be2  = (const float*)d_in[19];
    const float* Wzm  = (const float*)d_in[20];
    const float* bzm  = (const float*)d_in[21];
    const float* Wzs  = (const float*)d_in[22];
    const float* bzs  = (const float*)d_in[23];
    const float* Wd1  = (const float*)d_in[24];
    const float* bd1  = (const float*)d_in[25];
    const float* gd1  = (const float*)d_in[26];
    const float* bed1 = (const float*)d_in[27];
    const float* Wd2  = (const float*)d_in[28];
    const float* bd2  = (const float*)d_in[29];
    const float* gd2  = (const float*)d_in[30];
    const float* bed2 = (const float*)d_in[31];
    const float* Wt1  = (const float*)d_in[32];
    const float* bt1  = (const float*)d_in[33];
    const float* gt1  = (const float*)d_in[34];
    const float* bet1 = (const float*)d_in[35];
    const float* Wt2  = (const float*)d_in[36];
    const float* bt2  = (const float*)d_in[37];
    float* out = (float*)d_out;
    float* ws  = (float*)d_ws;

    const size_t need_fast = (POOL_FLOATS + 147456) * sizeof(float);  // 19.46 MB

    if (ws_size >= need_fast) {
        // fast path: pool staged in ws; U beyond pool; H2N/P3 reuse pool region after k_enc
        float* ws_pool = ws;
        float* ws_u    = ws + POOL_FLOATS;
        float* ws_h2n  = ws;                 // written by k_dec1 (after k_enc consumed pool)
        float* ws_p3   = ws + 1048576;

        k_pre<<<dim3(256), dim3(288), 0, stream>>>(act, Wa, ws_u);
        k_patch<<<dim3(1281), dim3(256), 0, stream>>>(
            x, pos, s0, nobs, nprd, Ws1, bs1, Ws2, bs2, Wc1, bc1, ws_u, ws_pool, out);
        k_enc<<<dim3(288), dim3(256), 0, stream>>>(
            g1, be1, Wc2, bc2, g2, be2, Wzm, bzm, Wzs, bzs, ws_pool, out);
        k_dec1<<<dim3(128), dim3(256), 0, stream>>>(
            eps, Wd1, bd1, gd1, bed1, Wd2, bd2, gd2, bed2, Wt1, bt1, out, ws_h2n, ws_p3);
        k_dec2<<<dim3(128), dim3(256), 0, stream>>>(
            x, pos, Wt1, bt1, gt1, bet1, Wt2, bt2, out, ws_h2n, ws_p3);
    } else {
        // fallback: 4.8 MB layout (validated in rounds 2-5)
        float* ws_u   = ws;
        float* ws_h2n = ws + 147456;
        float* ws_p3  = ws + 1196032;

        k_pre<<<dim3(256), dim3(288), 0, stream>>>(act, Wa, ws_u);
        k_enc_full<<<dim3(289), dim3(256), 0, stream>>>(
            x, pos, s0, nobs, nprd, Ws1, bs1, Ws2, bs2,
            Wc1, bc1, g1, be1, Wc2, bc2, g2, be2, Wzm, bzm, Wzs, bzs, ws_u, out);
        k_dec1<<<dim3(128), dim3(256), 0, stream>>>(
            eps, Wd1, bd1, gd1, bed1, Wd2, bd2, gd2, bed2, Wt1, bt1, out, ws_h2n, ws_p3);
        k_dec2<<<dim3(128), dim3(256), 0, stream>>>(
            x, pos, Wt1, bt1, gt1, bet1, Wt2, bt2, out, ws_h2n, ws_p3);
    }
}

// Round 9
// 217.147 us; speedup vs baseline: 2.2925x; 1.2561x over previous
//
#include <hip/hip_runtime.h>
#include <hip/hip_bf16.h>
#include <math.h>

// ---------------- problem constants ----------------
#define NB   256
#define NT   288
#define NOBS 256
#define NTP  32

// output offsets (floats)
#define O_ST_OBS   0
#define O_ST_PRED  131072
#define O_ZM_OBS   147456
#define O_ZS_OBS   1196032
#define O_ZM_PRED  2244608
#define O_ZS_PRED  2375680
#define O_XREC     2506752
#define O_NLL      4079616

#define POOL_FLOATS ((size_t)288 * 256 * 64)   // 4,718,592 floats = 18.9 MB

__device__ __forceinline__ float wred(float v) {
    v += __shfl_down(v, 32); v += __shfl_down(v, 16); v += __shfl_down(v, 8);
    v += __shfl_down(v, 4);  v += __shfl_down(v, 2);  v += __shfl_down(v, 1);
    return v;
}
__device__ __forceinline__ float sigm(float x) { return 1.0f / (1.0f + __expf(-x)); }

// fast reciprocal (v_rcp_f32, ~1 ulp) with safe fallback
__device__ __forceinline__ float frcp(float x) {
#if __has_builtin(__builtin_amdgcn_rcpf)
    return __builtin_amdgcn_rcpf(x);
#else
    return 1.0f / x;
#endif
}
__device__ __forceinline__ float tanh_fast(float x) {
    x = fminf(fmaxf(x, -15.0f), 15.0f);
    return fmaf(-2.0f, frcp(__expf(2.0f * x) + 1.0f), 1.0f);
}
__device__ __forceinline__ float sigm_fast(float x) {
    return frcp(1.0f + __expf(-x));
}

// NOTE: no macro parameter may be named x/y/z/w (member-access collision!)
#define FMA4(ax,ay,az,aw,wv,acc) fmaf((ax),(wv).x,fmaf((ay),(wv).y,fmaf((az),(wv).z,fmaf((aw),(wv).w,(acc)))))

// ==================== recurrence (device fn; one 256-thread block, thread = b) ====================
__device__ __forceinline__ void run_recurrence(
    int b, const float* __restrict__ s0,
    const float* __restrict__ nobs, const float* __restrict__ npred,
    const float* __restrict__ Ws1, const float* __restrict__ bs1,
    const float* __restrict__ Ws2, const float* __restrict__ bs2,
    const float* __restrict__ ws_u, float* __restrict__ out)
{
    float w1[10], w2[10], c1[5], c2_0, c2_1;
#pragma unroll
    for (int i = 0; i < 10; i++) { w1[i] = Ws1[i]; w2[i] = Ws2[i]; }
#pragma unroll
    for (int i = 0; i < 5; i++) c1[i] = bs1[i];
    c2_0 = bs2[0]; c2_1 = bs2[1];

    float sv0 = s0[b * 2 + 0], sv1 = s0[b * 2 + 1];
    ((float2*)(out + O_ST_OBS))[b] = make_float2(sv0, sv1);
    if (b == 0) out[O_NLL] = 0.0f;   // re-zeroed every call; stream-ordered before k_dec2

    const float2* Up   = (const float2*)ws_u;
    const float2* Nobs = (const float2*)nobs;
    const float2* Nprd = (const float2*)npred;

    auto LD = [&](int t, float2& u, float2& nz) {
        t = (t > 287) ? 287 : t;
        u  = Up[t * 256 + b];
        nz = (t < 256) ? Nobs[(t - 1) * 256 + b] : Nprd[(t - 256) * 256 + b];
    };
    auto STEP = [&](float2 u, float2 nz, int t) {
        const float v0 = sv0 + u.x, v1 = sv1 + u.y;
        const float h0 = tanh_fast(fmaf(v1, w1[1], fmaf(v0, w1[0], c1[0])));
        const float h1 = tanh_fast(fmaf(v1, w1[3], fmaf(v0, w1[2], c1[1])));
        const float h2 = tanh_fast(fmaf(v1, w1[5], fmaf(v0, w1[4], c1[2])));
        const float h3 = tanh_fast(fmaf(v1, w1[7], fmaf(v0, w1[6], c1[3])));
        const float h4 = tanh_fast(fmaf(v1, w1[9], fmaf(v0, w1[8], c1[4])));
        float a0 = fmaf(h0, w2[0], fmaf(h1, w2[1], c2_0));
        const float a0b = fmaf(h2, w2[2], h3 * w2[3]);
        a0 = fmaf(h4, w2[4], a0 + a0b);
        float a1 = fmaf(h0, w2[5], fmaf(h1, w2[6], c2_1));
        const float a1b = fmaf(h2, w2[7], h3 * w2[8]);
        a1 = fmaf(h4, w2[9], a1 + a1b);
        sv0 = fmaf(u.x, sigm_fast(a0), sv0) + nz.x;
        sv1 = fmaf(u.y, sigm_fast(a1), sv1) + nz.y;
        if (t < 256) ((float2*)(out + O_ST_OBS))[t * 256 + b] = make_float2(sv0, sv1);
        else         ((float2*)(out + O_ST_PRED))[(t - 256) * 256 + b] = make_float2(sv0, sv1);
    };

    float2 cu[8], cn[8];
#pragma unroll
    for (int j = 0; j < 8; j++) LD(1 + j, cu[j], cn[j]);

#pragma unroll 1
    for (int base = 1; base < 288; base += 8) {
        float2 nu[8], nn[8];
#pragma unroll
        for (int j = 0; j < 8; j++) LD(base + 8 + j, nu[j], nn[j]);
#pragma unroll
        for (int j = 0; j < 8; j++) {
            if (base + j < 288) STEP(cu[j], cn[j], base + j);
        }
#pragma unroll
        for (int j = 0; j < 8; j++) { cu[j] = nu[j]; cn[j] = nn[j]; }
    }
}

// ==================== Kernel 0: U[t][b][2] = act^T . Wa ====================
extern "C" __global__ void __launch_bounds__(288)
k_pre(const float* __restrict__ act, const float* __restrict__ Wa, float* __restrict__ ws_u)
{
    const int b = blockIdx.x;
    const int t = threadIdx.x;
    float u0 = 0.f, u1 = 0.f;
#pragma unroll
    for (int a = 0; a < 5; a++) {
        const float av = act[(b * 5 + a) * 288 + t];
        u0 = fmaf(av, Wa[a], u0);
        u1 = fmaf(av, Wa[5 + a], u1);
    }
    ws_u[(t * 256 + b) * 2 + 0] = u0;
    ws_u[(t * 256 + b) * 2 + 1] = u1;
}

// ==================== Kernel 1a (fast path): conv1+maxpool, work = (b, t, posq) ====================
extern "C" __global__ void __launch_bounds__(256)
k_patch(const float* __restrict__ x, const int* __restrict__ pos,
        const float* __restrict__ s0, const float* __restrict__ nobs,
        const float* __restrict__ npred,
        const float* __restrict__ Ws1, const float* __restrict__ bs1,
        const float* __restrict__ Ws2, const float* __restrict__ bs2,
        const float* __restrict__ Wc1, const float* __restrict__ bc1,
        const float* __restrict__ ws_u, float* __restrict__ ws_pool,
        float* __restrict__ out)
{
    const int tid = threadIdx.x;
    if (blockIdx.x == 0) {
        run_recurrence(tid, s0, nobs, npred, Ws1, bs1, Ws2, bs2, ws_u, out);
        return;
    }
    const int bid = blockIdx.x - 1;
    const int b = bid / 5, c = bid % 5;

    __shared__ __align__(16) float sImg[3 * 1056];
    __shared__ float sWc1[192];
    __shared__ float sB1[16];

    for (int i = tid; i < 3072; i += 256) {
        const int ic = i >> 10, r = (i >> 5) & 31, cc = i & 31;
        sImg[ic * 1056 + r * 33 + cc] = x[b * 3072 + i];
    }
    if (tid < 192) sWc1[tid] = Wc1[tid];
    if (tid < 16) sB1[tid] = bc1[tid];
    __syncthreads();

    const int t = c * 64 + (tid >> 2);
    if (t >= 288) return;
    const int posq = tid & 3;
    const int py = posq >> 1, px = posq & 1;

    const int pr = 3 * pos[(b * 2 + 0) * 288 + t];
    const int pc = 3 * pos[(b * 2 + 1) * 288 + t];

    float p16[16];
#pragma unroll
    for (int i = 0; i < 16; i++) p16[i] = 0.f;

#pragma unroll 2
    for (int d = 0; d < 4; d++) {
        const int rbase = pr + 4 * py + 2 * (d >> 1);
        const int cbase = pc + 4 * px + 2 * (d & 1);
        float in[12];
#pragma unroll
        for (int ic = 0; ic < 3; ic++)
#pragma unroll
        for (int ky = 0; ky < 2; ky++)
#pragma unroll
        for (int kx = 0; kx < 2; kx++)
            in[ic * 4 + ky * 2 + kx] = sImg[ic * 1056 + (rbase + ky) * 33 + (cbase + kx)];
#pragma unroll
        for (int oc = 0; oc < 16; oc++) {
            const float4 wq0 = *(const float4*)&sWc1[oc * 12 + 0];
            const float4 wq1 = *(const float4*)&sWc1[oc * 12 + 4];
            const float4 wq2 = *(const float4*)&sWc1[oc * 12 + 8];
            float v = sB1[oc];
            v = FMA4(in[0], in[1], in[2], in[3], wq0, v);
            v = FMA4(in[4], in[5], in[6], in[7], wq1, v);
            v = FMA4(in[8], in[9], in[10], in[11], wq2, v);
            p16[oc] = fmaxf(p16[oc], fmaxf(v, 0.f));
        }
    }

    float4* dst = (float4*)(ws_pool + (((size_t)b * 288 + t) * 4 + posq) * 16);
    dst[0] = make_float4(p16[0], p16[1], p16[2], p16[3]);
    dst[1] = make_float4(p16[4], p16[5], p16[6], p16[7]);
    dst[2] = make_float4(p16[8], p16[9], p16[10], p16[11]);
    dst[3] = make_float4(p16[12], p16[13], p16[14], p16[15]);
}

// ==================== Kernel 1b (fast path): BN1 + conv2 + BN2 + heads ====================
extern "C" __global__ void __launch_bounds__(256)
k_enc(const float* __restrict__ g1,   const float* __restrict__ be1,
      const float* __restrict__ Wc2,  const float* __restrict__ bc2,
      const float* __restrict__ g2,   const float* __restrict__ be2,
      const float* __restrict__ Wzm,  const float* __restrict__ bzm,
      const float* __restrict__ Wzs,  const float* __restrict__ bzs,
      const float* __restrict__ ws_pool, float* __restrict__ out)
{
    const int t = blockIdx.x, tid = threadIdx.x, b = tid;
    const int wid = tid >> 6, lane = tid & 63;

    __shared__ __align__(16) float pooledL[256 * 68];
    __shared__ __align__(16) float sWc2r[2048];
    __shared__ __align__(16) float sWzm[512];
    __shared__ __align__(16) float sWzs[512];
    __shared__ __align__(16) float sM1[16], sS1[16], sE1[16];
    __shared__ float sB2[32], sE2[32], sBzm[16], sBzs[16];
    __shared__ float sM2[32], sS2[32];
    __shared__ float sRed[4][64];

    for (int i = tid; i < 2048; i += 256) {
        const int oc = i >> 6, rem = i & 63, ic = rem >> 2, q = rem & 3;
        sWc2r[oc * 64 + q * 16 + ic] = Wc2[i];
    }
    for (int i = tid; i < 512; i += 256) { sWzm[i] = Wzm[i]; sWzs[i] = Wzs[i]; }
    if (tid < 16) { sE1[tid] = be1[tid]; sBzm[tid] = bzm[tid]; sBzs[tid] = bzs[tid]; }
    if (tid < 32) { sB2[tid] = bc2[tid]; sE2[tid] = be2[tid]; }

    float* myrow = &pooledL[b * 68];
    {
        const float4* src = (const float4*)(ws_pool + ((size_t)b * 288 + t) * 64);
#pragma unroll
        for (int q = 0; q < 16; q++) *(float4*)&myrow[4 * q] = src[q];
    }
    __syncthreads();

    {
        const int col = tid & 63, q = tid >> 6;
        float s = 0.f, ss = 0.f;
        const float* cp = &pooledL[(q * 64) * 68 + col];
#pragma unroll 4
        for (int i = 0; i < 64; i++) { const float v = cp[i * 68]; s += v; ss = fmaf(v, v, ss); }
        sRed[q][col] = s;
        __syncthreads();
        float ssum = 0.f;
        if (tid < 16) {
#pragma unroll
            for (int p = 0; p < 4; p++)
#pragma unroll
            for (int qq = 0; qq < 4; qq++) ssum += sRed[qq][p * 16 + tid];
        }
        __syncthreads();
        sRed[q][col] = ss;
        __syncthreads();
        if (tid < 16) {
            float sssum = 0.f;
#pragma unroll
            for (int p = 0; p < 4; p++)
#pragma unroll
            for (int qq = 0; qq < 4; qq++) sssum += sRed[qq][p * 16 + tid];
            const float m = ssum * (1.f / 1024.f);
            const float var = fmaf(-m, m, sssum * (1.f / 1024.f));
            sM1[tid] = m; sS1[tid] = g1[tid] * rsqrtf(var + 1e-5f);
        }
    }
    __syncthreads();

#pragma unroll 4
    for (int tq = 0; tq < 16; tq++) {
        const int ic0 = (tq & 3) * 4;
        float4 v = *(float4*)&myrow[4 * tq];
        const float4 mq = *(const float4*)&sM1[ic0];
        const float4 sq = *(const float4*)&sS1[ic0];
        const float4 eq = *(const float4*)&sE1[ic0];
        v.x = fmaf(v.x - mq.x, sq.x, eq.x);
        v.y = fmaf(v.y - mq.y, sq.y, eq.y);
        v.z = fmaf(v.z - mq.z, sq.z, eq.z);
        v.w = fmaf(v.w - mq.w, sq.w, eq.w);
        *(float4*)&myrow[4 * tq] = v;
    }

    float h2v[32];
#pragma unroll
    for (int og = 0; og < 4; og++) {
        float acc[8];
#pragma unroll
        for (int jj = 0; jj < 8; jj++) acc[jj] = sB2[og * 8 + jj];
#pragma unroll 2
        for (int tq = 0; tq < 16; tq++) {
            const float4 hq = *(const float4*)&myrow[4 * tq];
#pragma unroll
            for (int jj = 0; jj < 8; jj++) {
                const float4 wv = *(const float4*)&sWc2r[(og * 8 + jj) * 64 + 4 * tq];
                acc[jj] = FMA4(hq.x, hq.y, hq.z, hq.w, wv, acc[jj]);
            }
        }
#pragma unroll
        for (int jj = 0; jj < 8; jj++) h2v[og * 8 + jj] = fmaxf(acc[jj], 0.f);
    }

#pragma unroll
    for (int oc = 0; oc < 32; oc++) {
        float s = wred(h2v[oc]), ss = wred(h2v[oc] * h2v[oc]);
        if (lane == 0) { sRed[wid][2 * oc] = s; sRed[wid][2 * oc + 1] = ss; }
    }
    __syncthreads();
    if (tid < 32) {
        const float s  = sRed[0][2 * tid] + sRed[1][2 * tid] + sRed[2][2 * tid] + sRed[3][2 * tid];
        const float ss = sRed[0][2 * tid + 1] + sRed[1][2 * tid + 1] + sRed[2][2 * tid + 1] + sRed[3][2 * tid + 1];
        const float m = s * (1.f / 256.f);
        const float var = fmaf(-m, m, ss * (1.f / 256.f));
        sM2[tid] = m; sS2[tid] = g2[tid] * rsqrtf(var + 1e-5f);
    }
    __syncthreads();
#pragma unroll
    for (int oc = 0; oc < 32; oc++) h2v[oc] = fmaf(h2v[oc] - sM2[oc], sS2[oc], sE2[oc]);

    const int obase_m = (t < 256) ? (O_ZM_OBS + (t * 256 + b) * 16) : (O_ZM_PRED + ((t - 256) * 256 + b) * 16);
    const int obase_s = (t < 256) ? (O_ZS_OBS + (t * 256 + b) * 16) : (O_ZS_PRED + ((t - 256) * 256 + b) * 16);
#pragma unroll 2
    for (int k = 0; k < 16; k++) {
        float vm = sBzm[k], vs = sBzs[k];
#pragma unroll
        for (int c = 0; c < 32; c += 4) {
            const float4 wm = *(const float4*)&sWzm[k * 32 + c];
            const float4 wsq = *(const float4*)&sWzs[k * 32 + c];
            vm = FMA4(h2v[c], h2v[c + 1], h2v[c + 2], h2v[c + 3], wm, vm);
            vs = FMA4(h2v[c], h2v[c + 1], h2v[c + 2], h2v[c + 3], wsq, vs);
        }
        out[obase_m + k] = vm;
        out[obase_s + k] = __expf(vs);
    }
}

// ==================== Kernel 1 (fallback): fused encoder with global gathers ====================
extern "C" __global__ void __launch_bounds__(256)
k_enc_full(const float* __restrict__ x,
           const int*   __restrict__ pos,  const float* __restrict__ s0,
           const float* __restrict__ nobs, const float* __restrict__ npred,
           const float* __restrict__ Ws1,  const float* __restrict__ bs1,
           const float* __restrict__ Ws2,  const float* __restrict__ bs2,
           const float* __restrict__ Wc1,  const float* __restrict__ bc1,
           const float* __restrict__ g1,   const float* __restrict__ be1,
           const float* __restrict__ Wc2,  const float* __restrict__ bc2,
           const float* __restrict__ g2,   const float* __restrict__ be2,
           const float* __restrict__ Wzm,  const float* __restrict__ bzm,
           const float* __restrict__ Wzs,  const float* __restrict__ bzs,
           const float* __restrict__ ws_u, float* __restrict__ out)
{
    const int tid = threadIdx.x;
    if (blockIdx.x == 0) {
        run_recurrence(tid, s0, nobs, npred, Ws1, bs1, Ws2, bs2, ws_u, out);
        return;
    }
    const int t = blockIdx.x - 1;
    __shared__ __align__(16) float sWc1[192];
    __shared__ __align__(16) float sWc2r[2048];
    __shared__ __align__(16) float sWzm[512];
    __shared__ __align__(16) float sWzs[512];
    __shared__ __align__(16) float sM1[16], sS1[16], sE1[16];
    __shared__ float sB1[16], sB2[32], sE2[32], sBzm[16], sBzs[16];
    __shared__ float sM2[32], sS2[32];
    __shared__ float sRed[4][64];
    __shared__ __align__(16) float pooledL[256 * 68];

    for (int i = tid; i < 192; i += 256) sWc1[i] = Wc1[i];
    for (int i = tid; i < 2048; i += 256) {
        const int oc = i >> 6, rem = i & 63, ic = rem >> 2, q = rem & 3;
        sWc2r[oc * 64 + q * 16 + ic] = Wc2[i];
    }
    for (int i = tid; i < 512; i += 256) { sWzm[i] = Wzm[i]; sWzs[i] = Wzs[i]; }
    if (tid < 16) { sB1[tid] = bc1[tid]; sE1[tid] = be1[tid]; sBzm[tid] = bzm[tid]; sBzs[tid] = bzs[tid]; }
    if (tid < 32) { sB2[tid] = bc2[tid]; sE2[tid] = be2[tid]; }
    __syncthreads();

    const int b = tid;
    const int wid = tid >> 6, lane = tid & 63;
    const float* xb = x + b * 3072;
    const int pr = 3 * pos[(b * 2 + 0) * 288 + t];
    const int pc = 3 * pos[(b * 2 + 1) * 288 + t];
    float* myrow = &pooledL[b * 68];

#pragma unroll
    for (int py = 0; py < 2; py++)
#pragma unroll
    for (int px = 0; px < 2; px++) {
        float p16[16];
#pragma unroll
        for (int i = 0; i < 16; i++) p16[i] = 0.f;
#pragma unroll 2
        for (int d = 0; d < 4; d++) {
            const int rbase = pr + 4 * py + 2 * (d >> 1);
            const int cbase = pc + 4 * px + 2 * (d & 1);
            float in[12];
#pragma unroll
            for (int ic = 0; ic < 3; ic++)
#pragma unroll
            for (int ky = 0; ky < 2; ky++)
#pragma unroll
            for (int kx = 0; kx < 2; kx++)
                in[ic * 4 + ky * 2 + kx] = xb[ic * 1024 + (rbase + ky) * 32 + (cbase + kx)];
#pragma unroll
            for (int oc = 0; oc < 16; oc++) {
                const float4 wq0 = *(const float4*)&sWc1[oc * 12 + 0];
                const float4 wq1 = *(const float4*)&sWc1[oc * 12 + 4];
                const float4 wq2 = *(const float4*)&sWc1[oc * 12 + 8];
                float v = sB1[oc];
                v = FMA4(in[0], in[1], in[2], in[3], wq0, v);
                v = FMA4(in[4], in[5], in[6], in[7], wq1, v);
                v = FMA4(in[8], in[9], in[10], in[11], wq2, v);
                p16[oc] = fmaxf(p16[oc], fmaxf(v, 0.f));
            }
        }
        const int pbase = (py * 2 + px) * 16;
        *(float4*)&myrow[pbase + 0]  = make_float4(p16[0], p16[1], p16[2], p16[3]);
        *(float4*)&myrow[pbase + 4]  = make_float4(p16[4], p16[5], p16[6], p16[7]);
        *(float4*)&myrow[pbase + 8]  = make_float4(p16[8], p16[9], p16[10], p16[11]);
        *(float4*)&myrow[pbase + 12] = make_float4(p16[12], p16[13], p16[14], p16[15]);
    }
    __syncthreads();

    {
        const int col = tid & 63, q = tid >> 6;
        float s = 0.f, ss = 0.f;
        const float* cp = &pooledL[(q * 64) * 68 + col];
#pragma unroll 4
        for (int i = 0; i < 64; i++) { const float v = cp[i * 68]; s += v; ss = fmaf(v, v, ss); }
        sRed[q][col] = s;
        __syncthreads();
        float ssum = 0.f;
        if (tid < 16) {
#pragma unroll
            for (int p = 0; p < 4; p++)
#pragma unroll
            for (int qq = 0; qq < 4; qq++) ssum += sRed[qq][p * 16 + tid];
        }
        __syncthreads();
        sRed[q][col] = ss;
        __syncthreads();
        if (tid < 16) {
            float sssum = 0.f;
#pragma unroll
            for (int p = 0; p < 4; p++)
#pragma unroll
            for (int qq = 0; qq < 4; qq++) sssum += sRed[qq][p * 16 + tid];
            const float m = ssum * (1.f / 1024.f);
            const float var = fmaf(-m, m, sssum * (1.f / 1024.f));
            sM1[tid] = m; sS1[tid] = g1[tid] * rsqrtf(var + 1e-5f);
        }
    }
    __syncthreads();

#pragma unroll 4
    for (int tq = 0; tq < 16; tq++) {
        const int ic0 = (tq & 3) * 4;
        float4 v = *(float4*)&myrow[4 * tq];
        const float4 mq = *(const float4*)&sM1[ic0];
        const float4 sq = *(const float4*)&sS1[ic0];
        const float4 eq = *(const float4*)&sE1[ic0];
        v.x = fmaf(v.x - mq.x, sq.x, eq.x);
        v.y = fmaf(v.y - mq.y, sq.y, eq.y);
        v.z = fmaf(v.z - mq.z, sq.z, eq.z);
        v.w = fmaf(v.w - mq.w, sq.w, eq.w);
        *(float4*)&myrow[4 * tq] = v;
    }

    float h2v[32];
#pragma unroll
    for (int og = 0; og < 4; og++) {
        float acc[8];
#pragma unroll
        for (int jj = 0; jj < 8; jj++) acc[jj] = sB2[og * 8 + jj];
#pragma unroll 2
        for (int tq = 0; tq < 16; tq++) {
            const float4 hq = *(const float4*)&myrow[4 * tq];
#pragma unroll
            for (int jj = 0; jj < 8; jj++) {
                const float4 wv = *(const float4*)&sWc2r[(og * 8 + jj) * 64 + 4 * tq];
                acc[jj] = FMA4(hq.x, hq.y, hq.z, hq.w, wv, acc[jj]);
            }
        }
#pragma unroll
        for (int jj = 0; jj < 8; jj++) h2v[og * 8 + jj] = fmaxf(acc[jj], 0.f);
    }

#pragma unroll
    for (int oc = 0; oc < 32; oc++) {
        float s = wred(h2v[oc]), ss = wred(h2v[oc] * h2v[oc]);
        if (lane == 0) { sRed[wid][2 * oc] = s; sRed[wid][2 * oc + 1] = ss; }
    }
    __syncthreads();
    if (tid < 32) {
        const float s  = sRed[0][2 * tid] + sRed[1][2 * tid] + sRed[2][2 * tid] + sRed[3][2 * tid];
        const float ss = sRed[0][2 * tid + 1] + sRed[1][2 * tid + 1] + sRed[2][2 * tid + 1] + sRed[3][2 * tid + 1];
        const float m = s * (1.f / 256.f);
        const float var = fmaf(-m, m, ss * (1.f / 256.f));
        sM2[tid] = m; sS2[tid] = g2[tid] * rsqrtf(var + 1e-5f);
    }
    __syncthreads();
#pragma unroll
    for (int oc = 0; oc < 32; oc++) h2v[oc] = fmaf(h2v[oc] - sM2[oc], sS2[oc], sE2[oc]);

    const int obase_m = (t < 256) ? (O_ZM_OBS + (t * 256 + b) * 16) : (O_ZM_PRED + ((t - 256) * 256 + b) * 16);
    const int obase_s = (t < 256) ? (O_ZS_OBS + (t * 256 + b) * 16) : (O_ZS_PRED + ((t - 256) * 256 + b) * 16);
#pragma unroll 2
    for (int k = 0; k < 16; k++) {
        float vm = sBzm[k], vs = sBzs[k];
#pragma unroll
        for (int c = 0; c < 32; c += 4) {
            const float4 wm = *(const float4*)&sWzm[k * 32 + c];
            const float4 wsq = *(const float4*)&sWzs[k * 32 + c];
            vm = FMA4(h2v[c], h2v[c + 1], h2v[c + 2], h2v[c + 3], wm, vm);
            vs = FMA4(h2v[c], h2v[c + 1], h2v[c + 2], h2v[c + 3], wsq, vs);
        }
        out[obase_m + k] = vm;
        out[obase_s + k] = __expf(vs);
    }
}

// ==================== Kernel 2: 512-thread loop-based decoder front half ====================
// grid 128: (tp = bid>>2, g = bid&3). tid: b = tid&255, half = tid>>8.
// fc1 split 32ch/half -> h1L; BN1/BN2 via LDS column partials; fc2 16ch/half;
// convT1 stats: half handles dp = half*2 + {0,1}, per-oc wred accumulated in LDS.
extern "C" __global__ void __launch_bounds__(512)
k_dec1(const float* __restrict__ eps,
       const float* __restrict__ Wd1,  const float* __restrict__ bd1,
       const float* __restrict__ gd1,  const float* __restrict__ bed1,
       const float* __restrict__ Wd2,  const float* __restrict__ bd2,
       const float* __restrict__ gd2,  const float* __restrict__ bed2,
       const float* __restrict__ Wt1,  const float* __restrict__ bt1,
       const float* __restrict__ out,
       float* __restrict__ ws_h2n, float* __restrict__ ws_p3)
{
    const int tp = blockIdx.x >> 2, g = blockIdx.x & 3;
    const int tid = threadIdx.x;
    const int b = tid & 255, half = tid >> 8;
    const int wid = tid >> 6, lane = tid & 63;

    __shared__ __align__(16) float sWd1[1024];    // [j][16]
    __shared__ __align__(16) float sWd2g[2048];   // [ic][64], rows j=4*ic+g
    __shared__ __align__(16) float sWt1g[2048];   // [(dp*16+oc)][32]
    __shared__ float h1L[256 * 65];               // stride 65: conflict-free scalar access
    __shared__ float h2L[256 * 33];               // stride 33
    __shared__ float sRed[8][128];                // 1024 slots (also used flat)
    __shared__ float sAcc[8][32];                 // convT1 stats accumulators per wave
    __shared__ float sM1[64], sS1[64], sE1[64];
    __shared__ float sM2[32], sS2[32], sE2[32];
    __shared__ float sBd1[64], sBd2g[32], sBt1[16];
    float* sRedF = &sRed[0][0];

    for (int i = tid; i < 1024; i += 512) sWd1[i] = Wd1[i];
    for (int i = tid; i < 2048; i += 512) {
        const int ic = i >> 6, k = i & 63;
        sWd2g[i] = Wd2[(4 * ic + g) * 64 + k];
    }
    for (int i = tid; i < 2048; i += 512) {
        const int dp = i >> 9, rem = i & 511, oc = rem >> 5, ic = i & 31;
        const int py = (g >> 1) * 2 + (dp >> 1), px = (g & 1) * 2 + (dp & 1);
        const int k9 = ((py + 1) % 3) * 3 + ((px + 1) % 3);
        sWt1g[(dp * 16 + oc) * 32 + ic] = Wt1[ic * 144 + oc * 9 + k9];
    }
    if (tid < 64) sBd1[tid] = bd1[tid];
    if (tid < 32) sBd2g[tid] = bd2[4 * tid + g];
    if (tid < 16) sBt1[tid] = bt1[tid];
    if (tid < 256) ((float*)sAcc)[tid] = 0.f;
    __syncthreads();

    // ---- z sample (per thread; each half loads the same b's z) ----
    float4 zA, zB, zC, zD;
    {
        const int base = (tp * 256 + b) * 16;
        const float4 e0 = *(const float4*)&eps[base + 0],  e1 = *(const float4*)&eps[base + 4];
        const float4 e2 = *(const float4*)&eps[base + 8],  e3 = *(const float4*)&eps[base + 12];
        const float4 s0v = *(const float4*)&out[O_ZS_PRED + base + 0],  s1v = *(const float4*)&out[O_ZS_PRED + base + 4];
        const float4 s2v = *(const float4*)&out[O_ZS_PRED + base + 8],  s3v = *(const float4*)&out[O_ZS_PRED + base + 12];
        const float4 m0 = *(const float4*)&out[O_ZM_PRED + base + 0],  m1 = *(const float4*)&out[O_ZM_PRED + base + 4];
        const float4 m2 = *(const float4*)&out[O_ZM_PRED + base + 8],  m3 = *(const float4*)&out[O_ZM_PRED + base + 12];
        zA = make_float4(fmaf(e0.x,s0v.x,m0.x), fmaf(e0.y,s0v.y,m0.y), fmaf(e0.z,s0v.z,m0.z), fmaf(e0.w,s0v.w,m0.w));
        zB = make_float4(fmaf(e1.x,s1v.x,m1.x), fmaf(e1.y,s1v.y,m1.y), fmaf(e1.z,s1v.z,m1.z), fmaf(e1.w,s1v.w,m1.w));
        zC = make_float4(fmaf(e2.x,s2v.x,m2.x), fmaf(e2.y,s2v.y,m2.y), fmaf(e2.z,s2v.z,m2.z), fmaf(e2.w,s2v.w,m2.w));
        zD = make_float4(fmaf(e3.x,s3v.x,m3.x), fmaf(e3.y,s3v.y,m3.y), fmaf(e3.z,s3v.z,m3.z), fmaf(e3.w,s3v.w,m3.w));
    }

    // ---- fc1: 32 outputs per half -> h1L ----
#pragma unroll 4
    for (int jj = 0; jj < 32; ++jj) {
        const int j = half * 32 + jj;
        const float4 wq0 = *(const float4*)&sWd1[j * 16 + 0];
        const float4 wq1 = *(const float4*)&sWd1[j * 16 + 4];
        const float4 wq2 = *(const float4*)&sWd1[j * 16 + 8];
        const float4 wq3 = *(const float4*)&sWd1[j * 16 + 12];
        float v = sBd1[j];
        v = FMA4(zA.x, zA.y, zA.z, zA.w, wq0, v);
        v = FMA4(zB.x, zB.y, zB.z, zB.w, wq1, v);
        v = FMA4(zC.x, zC.y, zC.z, zC.w, wq2, v);
        v = FMA4(zD.x, zD.y, zD.z, zD.w, wq3, v);
        h1L[b * 65 + j] = fmaxf(v, 0.f);
    }
    __syncthreads();

    // ---- BN1 stats: column partials (64 ch x 8 groups of 32 rows) ----
    {
        const int col = tid & 63, q = tid >> 6;
        float s = 0.f, ss = 0.f;
        const float* cp = &h1L[(q * 32) * 65 + col];
#pragma unroll 4
        for (int i = 0; i < 32; i++) { const float v = cp[i * 65]; s += v; ss = fmaf(v, v, ss); }
        sRed[q][2 * col] = s; sRed[q][2 * col + 1] = ss;
    }
    __syncthreads();
    if (tid < 64) {
        float s = 0.f, ss = 0.f;
#pragma unroll
        for (int q = 0; q < 8; q++) { s += sRed[q][2 * tid]; ss += sRed[q][2 * tid + 1]; }
        const float m = s * (1.f / 256.f);
        const float var = fmaf(-m, m, ss * (1.f / 256.f));
        sM1[tid] = m; sS1[tid] = gd1[tid] * rsqrtf(var + 1e-5f); sE1[tid] = bed1[tid];
    }
    __syncthreads();

    // ---- normalize own half's 32 entries of own row ----
#pragma unroll 4
    for (int jj = 0; jj < 32; ++jj) {
        const int j = half * 32 + jj;
        h1L[b * 65 + j] = fmaf(h1L[b * 65 + j] - sM1[j], sS1[j], sE1[j]);
    }
    __syncthreads();

    // ---- copy full normalized row to registers ----
    float hr[64];
#pragma unroll
    for (int k = 0; k < 64; ++k) hr[k] = h1L[b * 65 + k];

    // ---- fc2: 16 channels per half (rolled loop, unrolled inner) ----
#pragma unroll 1
    for (int ic = 0; ic < 16; ++ic) {
        const int icg = half * 16 + ic;
        float v = sBd2g[icg];
#pragma unroll
        for (int k4 = 0; k4 < 16; ++k4) {
            const float4 wv = *(const float4*)&sWd2g[icg * 64 + 4 * k4];
            v = FMA4(hr[4*k4], hr[4*k4+1], hr[4*k4+2], hr[4*k4+3], wv, v);
        }
        h2L[b * 33 + icg] = fmaxf(v, 0.f);
    }
    __syncthreads();

    // ---- BN2 stats: column partials (32 ch x 16 groups of 16 rows), two rounds ----
    {
        const int col = tid & 31, q = tid >> 5;
        float s = 0.f, ss = 0.f;
        const float* cp = &h2L[(q * 16) * 33 + col];
#pragma unroll 4
        for (int i = 0; i < 16; i++) { const float v = cp[i * 33]; s += v; ss = fmaf(v, v, ss); }
        sRedF[q * 32 + col] = s;
        __syncthreads();
        float ssum = 0.f;
        if (tid < 32) {
#pragma unroll
            for (int qq = 0; qq < 16; qq++) ssum += sRedF[qq * 32 + tid];
        }
        __syncthreads();
        sRedF[q * 32 + col] = ss;
        __syncthreads();
        if (tid < 32) {
            float sssum = 0.f;
#pragma unroll
            for (int qq = 0; qq < 16; qq++) sssum += sRedF[qq * 32 + tid];
            const float m = ssum * (1.f / 256.f);
            const float var = fmaf(-m, m, sssum * (1.f / 256.f));
            sM2[tid] = m;
            sS2[tid] = gd2[4 * tid + g] * rsqrtf(var + 1e-5f);
            sE2[tid] = bed2[4 * tid + g];
        }
    }
    __syncthreads();

    // ---- normalize own 16 channels in h2L ----
#pragma unroll 4
    for (int ic = 0; ic < 16; ++ic) {
        const int icg = half * 16 + ic;
        h2L[b * 33 + icg] = fmaf(h2L[b * 33 + icg] - sM2[icg], sS2[icg], sE2[icg]);
    }
    __syncthreads();

    // ---- copy full normalized h2 row to registers; write h2n to global ----
    float h2r[32];
#pragma unroll
    for (int k = 0; k < 32; ++k) h2r[k] = h2L[b * 33 + k];
    {
        float* dst = ws_h2n + (((size_t)(tp * 4 + g) * 256 + b) * 32 + half * 16);
        const int o = half * 16;
        *(float4*)&dst[0]  = make_float4(h2r[o+0],  h2r[o+1],  h2r[o+2],  h2r[o+3]);
        *(float4*)&dst[4]  = make_float4(h2r[o+4],  h2r[o+5],  h2r[o+6],  h2r[o+7]);
        *(float4*)&dst[8]  = make_float4(h2r[o+8],  h2r[o+9],  h2r[o+10], h2r[o+11]);
        *(float4*)&dst[12] = make_float4(h2r[o+12], h2r[o+13], h2r[o+14], h2r[o+15]);
    }

    // ---- convT1 stats: half handles dp = half*2 + {0,1}; per-oc wred -> sAcc ----
#pragma unroll 1
    for (int d2 = 0; d2 < 2; ++d2) {
        const int dp = half * 2 + d2;
#pragma unroll 1
        for (int oc = 0; oc < 16; ++oc) {
            float v = sBt1[oc];
            const float* wrow = &sWt1g[(dp * 16 + oc) * 32];
#pragma unroll
            for (int i4 = 0; i4 < 8; ++i4) {
                const float4 wv = *(const float4*)&wrow[4 * i4];
                v = FMA4(h2r[4*i4], h2r[4*i4+1], h2r[4*i4+2], h2r[4*i4+3], wv, v);
            }
            v = fmaxf(v, 0.f);
            const float s = wred(v), ss = wred(v * v);
            if (lane == 0) { sAcc[wid][2 * oc] += s; sAcc[wid][2 * oc + 1] += ss; }
        }
    }
    __syncthreads();
    if (tid < 16) {
        float s = 0.f, ss = 0.f;
#pragma unroll
        for (int w = 0; w < 8; w++) { s += sAcc[w][2 * tid]; ss += sAcc[w][2 * tid + 1]; }
        ws_p3[(tp * 4 + g) * 32 + 2 * tid + 0] = s;
        ws_p3[(tp * 4 + g) * 32 + 2 * tid + 1] = ss;
    }
}

// ==================== Kernel 3: BN3 finalize + convT1 recompute + convT2 + nll ====================
extern "C" __global__ void __launch_bounds__(256)
k_dec2(const float* __restrict__ x,    const int* __restrict__ pos,
       const float* __restrict__ Wt1,  const float* __restrict__ bt1,
       const float* __restrict__ gt1,  const float* __restrict__ bet1,
       const float* __restrict__ Wt2,  const float* __restrict__ bt2,
       float* __restrict__ out,
       const float* __restrict__ ws_h2n, const float* __restrict__ ws_p3)
{
    const int tp = blockIdx.x >> 2, g = blockIdx.x & 3;
    const int tid = threadIdx.x, b = tid;
    const int wid = tid >> 6, lane = tid & 63;

    __shared__ __align__(16) float sWt1g[2048];
    __shared__ __align__(16) float sWt2[192];
    __shared__ float sBt1[16], sBt2[3];
    __shared__ float sRed[4][64];
    __shared__ float sM3[16], sS3[16], sE3[16];

    for (int i = tid; i < 2048; i += 256) {
        const int dp = i >> 9, rem = i & 511, oc = rem >> 5, ic = i & 31;
        const int py = (g >> 1) * 2 + (dp >> 1), px = (g & 1) * 2 + (dp & 1);
        const int k9 = ((py + 1) % 3) * 3 + ((px + 1) % 3);
        sWt1g[(dp * 16 + oc) * 32 + ic] = Wt1[ic * 144 + oc * 9 + k9];
    }
    if (tid < 192) { const int ic = tid / 12, r = tid % 12; sWt2[r * 16 + ic] = Wt2[tid]; }
    if (tid < 16) sBt1[tid] = bt1[tid];
    if (tid < 3) sBt2[tid] = bt2[tid];
    if (tid < 16) {
        float s = 0.f, ss = 0.f;
#pragma unroll
        for (int gg = 0; gg < 4; gg++) {
            s  += ws_p3[(tp * 4 + gg) * 32 + 2 * tid + 0];
            ss += ws_p3[(tp * 4 + gg) * 32 + 2 * tid + 1];
        }
        const float m = s * (1.f / 4096.f);
        const float var = fmaf(-m, m, ss * (1.f / 4096.f));
        sM3[tid] = m; sS3[tid] = gt1[tid] * rsqrtf(var + 1e-5f); sE3[tid] = bet1[tid];
    }
    __syncthreads();

    float h2g[32];
    {
        const float* src = ws_h2n + (((size_t)(tp * 4 + g) * 256 + b) * 32);
#pragma unroll
        for (int i4 = 0; i4 < 8; i4++) {
            const float4 v4 = *(const float4*)&src[4 * i4];
            h2g[4 * i4] = v4.x; h2g[4 * i4 + 1] = v4.y; h2g[4 * i4 + 2] = v4.z; h2g[4 * i4 + 3] = v4.w;
        }
    }

    const int t = 256 + tp;
    const int pr = 3 * pos[(b * 2 + 0) * 288 + t];
    const int pc = 3 * pos[(b * 2 + 1) * 288 + t];
    const float* xb = x + b * 3072;
    const int rbase = O_XREC + (tp * 256 + b) * 192;
    const int py0 = (g >> 1) * 2, px0 = (g & 1) * 2;
    float err = 0.f;

#pragma unroll 1
    for (int dp = 0; dp < 4; dp++) {
        const int py = py0 + (dp >> 1), px = px0 + (dp & 1);
        float hn[16];
#pragma unroll
        for (int og = 0; og < 4; og++) {
            float acc[4];
#pragma unroll
            for (int jj = 0; jj < 4; jj++) acc[jj] = sBt1[og * 4 + jj];
#pragma unroll
            for (int i4 = 0; i4 < 8; i4++) {
#pragma unroll
                for (int jj = 0; jj < 4; jj++) {
                    const float4 wv = *(const float4*)&sWt1g[(dp * 16 + og * 4 + jj) * 32 + 4 * i4];
                    acc[jj] = FMA4(h2g[4*i4], h2g[4*i4+1], h2g[4*i4+2], h2g[4*i4+3], wv, acc[jj]);
                }
            }
#pragma unroll
            for (int jj = 0; jj < 4; jj++) {
                const int oc = og * 4 + jj;
                hn[oc] = fmaf(fmaxf(acc[jj], 0.f) - sM3[oc], sS3[oc], sE3[oc]);
            }
        }
#pragma unroll
        for (int c = 0; c < 3; c++)
#pragma unroll
        for (int dy = 0; dy < 2; dy++)
#pragma unroll
        for (int dx = 0; dx < 2; dx++) {
            const float* wp = &sWt2[(c * 4 + dy * 2 + dx) * 16];
            float v = sBt2[c];
#pragma unroll
            for (int ic = 0; ic < 16; ic += 4) {
                const float4 wq = *(const float4*)&wp[ic];
                v = FMA4(hn[ic], hn[ic + 1], hn[ic + 2], hn[ic + 3], wq, v);
            }
            v = sigm(v);
            const int oy = 2 * py + dy, ox = 2 * px + dx;
            out[rbase + c * 64 + oy * 8 + ox] = v;
            const float d = v - xb[c * 1024 + (pr + oy) * 32 + (pc + ox)];
            err = fmaf(d, d, err);
        }
    }

    const float es = wred(err);
    if (lane == 0) sRed[wid][0] = es;
    __syncthreads();
    if (tid == 0)
        atomicAdd(&out[O_NLL], sRed[0][0] + sRed[1][0] + sRed[2][0] + sRed[3][0]);
}

// ==================== host ====================
extern "C" void kernel_launch(void* const* d_in, const int* in_sizes, int n_in,
                              void* d_out, int out_size, void* d_ws, size_t ws_size,
                              hipStream_t stream)
{
    const float* x    = (const float*)d_in[0];
    const float* act  = (const float*)d_in[1];
    const int*   pos  = (const int*)d_in[2];
    const float* s0   = (const float*)d_in[3];
    const float* nobs = (const float*)d_in[4];
    const float* nprd = (const float*)d_in[5];
    const float* eps  = (const float*)d_in[6];
    const float* Wa   = (const float*)d_in[7];
    const float* Ws1  = (const float*)d_in[8];
    const float* bs1  = (const float*)d_in[9];
    const float* Ws2  = (const float*)d_in[10];
    const float* bs2  = (const float*)d_in[11];
    const float* Wc1  = (const float*)d_in[12];
    const float* bc1  = (const float*)d_in[13];
    const float* g1   = (const float*)d_in[14];
    const float* be1  = (const float*)d_in[15];
    const float* Wc2  = (const float*)d_in[16];
    const float* bc2  = (const float*)d_in[17];
    const float* g2   = (const float*)d_in[18];
    const float* be2  = (const float*)d_in[19];
    const float* Wzm  = (const float*)d_in[20];
    const float* bzm  = (const float*)d_in[21];
    const float* Wzs  = (const float*)d_in[22];
    const float* bzs  = (const float*)d_in[23];
    const float* Wd1  = (const float*)d_in[24];
    const float* bd1  = (const float*)d_in[25];
    const float* gd1  = (const float*)d_in[26];
    const float* bed1 = (const float*)d_in[27];
    const float* Wd2  = (const float*)d_in[28];
    const float* bd2  = (const float*)d_in[29];
    const float* gd2  = (const float*)d_in[30];
    const float* bed2 = (const float*)d_in[31];
    const float* Wt1  = (const float*)d_in[32];
    const float* bt1  = (const float*)d_in[33];
    const float* gt1  = (const float*)d_in[34];
    const float* bet1 = (const float*)d_in[35];
    const float* Wt2  = (const float*)d_in[36];
    const float* bt2  = (const float*)d_in[37];
    float* out = (float*)d_out;
    float* ws  = (float*)d_ws;

    const size_t need_fast = (POOL_FLOATS + 147456) * sizeof(float);  // 19.46 MB

    if (ws_size >= need_fast) {
        float* ws_pool = ws;
        float* ws_u    = ws + POOL_FLOATS;
        float* ws_h2n  = ws;                 // reuses pool region after k_enc consumed it
        float* ws_p3   = ws + 1048576;

        k_pre<<<dim3(256), dim3(288), 0, stream>>>(act, Wa, ws_u);
        k_patch<<<dim3(1281), dim3(256), 0, stream>>>(
            x, pos, s0, nobs, nprd, Ws1, bs1, Ws2, bs2, Wc1, bc1, ws_u, ws_pool, out);
        k_enc<<<dim3(288), dim3(256), 0, stream>>>(
            g1, be1, Wc2, bc2, g2, be2, Wzm, bzm, Wzs, bzs, ws_pool, out);
        k_dec1<<<dim3(128), dim3(512), 0, stream>>>(
            eps, Wd1, bd1, gd1, bed1, Wd2, bd2, gd2, bed2, Wt1, bt1, out, ws_h2n, ws_p3);
        k_dec2<<<dim3(128), dim3(256), 0, stream>>>(
            x, pos, Wt1, bt1, gt1, bet1, Wt2, bt2, out, ws_h2n, ws_p3);
    } else {
        float* ws_u   = ws;
        float* ws_h2n = ws + 147456;
        float* ws_p3  = ws + 1196032;

        k_pre<<<dim3(256), dim3(288), 0, stream>>>(act, Wa, ws_u);
        k_enc_full<<<dim3(289), dim3(256), 0, stream>>>(
            x, pos, s0, nobs, nprd, Ws1, bs1, Ws2, bs2,
            Wc1, bc1, g1, be1, Wc2, bc2, g2, be2, Wzm, bzm, Wzs, bzs, ws_u, out);
        k_dec1<<<dim3(128), dim3(512), 0, stream>>>(
            eps, Wd1, bd1, gd1, bed1, Wd2, bd2, gd2, bed2, Wt1, bt1, out, ws_h2n, ws_p3);
        k_dec2<<<dim3(128), dim3(256), 0, stream>>>(
            x, pos, Wt1, bt1, gt1, bet1, Wt2, bt2, out, ws_h2n, ws_p3);
    }
}

// Round 10
// 181.247 us; speedup vs baseline: 2.7466x; 1.1981x over previous
//
#include <hip/hip_runtime.h>
#include <hip/hip_bf16.h>
#include <math.h>

// ---------------- problem constants ----------------
#define NB   256
#define NT   288
#define NOBS 256
#define NTP  32

// output offsets (floats)
#define O_ST_OBS   0
#define O_ST_PRED  131072
#define O_ZM_OBS   147456
#define O_ZS_OBS   1196032
#define O_ZM_PRED  2244608
#define O_ZS_PRED  2375680
#define O_XREC     2506752
#define O_NLL      4079616

#define POOL_FLOATS ((size_t)288 * 256 * 64)   // 4,718,592 floats = 18.9 MB

__device__ __forceinline__ float wred(float v) {
    v += __shfl_down(v, 32); v += __shfl_down(v, 16); v += __shfl_down(v, 8);
    v += __shfl_down(v, 4);  v += __shfl_down(v, 2);  v += __shfl_down(v, 1);
    return v;
}
__device__ __forceinline__ float sigm(float x) { return 1.0f / (1.0f + __expf(-x)); }

// fast reciprocal (v_rcp_f32, ~1 ulp) with safe fallback
__device__ __forceinline__ float frcp(float x) {
#if __has_builtin(__builtin_amdgcn_rcpf)
    return __builtin_amdgcn_rcpf(x);
#else
    return 1.0f / x;
#endif
}
__device__ __forceinline__ float tanh_fast(float x) {
    x = fminf(fmaxf(x, -15.0f), 15.0f);
    return fmaf(-2.0f, frcp(__expf(2.0f * x) + 1.0f), 1.0f);
}
__device__ __forceinline__ float sigm_fast(float x) {
    return frcp(1.0f + __expf(-x));
}

// NOTE: no macro parameter may be named x/y/z/w (member-access collision!)
#define FMA4(ax,ay,az,aw,wv,acc) fmaf((ax),(wv).x,fmaf((ay),(wv).y,fmaf((az),(wv).z,fmaf((aw),(wv).w,(acc)))))

// ==================== recurrence (device fn; one 256-thread block, thread = b) ====================
__device__ __forceinline__ void run_recurrence(
    int b, const float* __restrict__ s0,
    const float* __restrict__ nobs, const float* __restrict__ npred,
    const float* __restrict__ Ws1, const float* __restrict__ bs1,
    const float* __restrict__ Ws2, const float* __restrict__ bs2,
    const float* __restrict__ ws_u, float* __restrict__ out)
{
    float w1[10], w2[10], c1[5], c2_0, c2_1;
#pragma unroll
    for (int i = 0; i < 10; i++) { w1[i] = Ws1[i]; w2[i] = Ws2[i]; }
#pragma unroll
    for (int i = 0; i < 5; i++) c1[i] = bs1[i];
    c2_0 = bs2[0]; c2_1 = bs2[1];

    float sv0 = s0[b * 2 + 0], sv1 = s0[b * 2 + 1];
    ((float2*)(out + O_ST_OBS))[b] = make_float2(sv0, sv1);
    if (b == 0) out[O_NLL] = 0.0f;   // re-zeroed every call; stream-ordered before k_dec2

    const float2* Up   = (const float2*)ws_u;
    const float2* Nobs = (const float2*)nobs;
    const float2* Nprd = (const float2*)npred;

    auto LD = [&](int t, float2& u, float2& nz) {
        t = (t > 287) ? 287 : t;
        u  = Up[t * 256 + b];
        nz = (t < 256) ? Nobs[(t - 1) * 256 + b] : Nprd[(t - 256) * 256 + b];
    };
    auto STEP = [&](float2 u, float2 nz, int t) {
        const float v0 = sv0 + u.x, v1 = sv1 + u.y;
        const float h0 = tanh_fast(fmaf(v1, w1[1], fmaf(v0, w1[0], c1[0])));
        const float h1 = tanh_fast(fmaf(v1, w1[3], fmaf(v0, w1[2], c1[1])));
        const float h2 = tanh_fast(fmaf(v1, w1[5], fmaf(v0, w1[4], c1[2])));
        const float h3 = tanh_fast(fmaf(v1, w1[7], fmaf(v0, w1[6], c1[3])));
        const float h4 = tanh_fast(fmaf(v1, w1[9], fmaf(v0, w1[8], c1[4])));
        float a0 = fmaf(h0, w2[0], fmaf(h1, w2[1], c2_0));
        const float a0b = fmaf(h2, w2[2], h3 * w2[3]);
        a0 = fmaf(h4, w2[4], a0 + a0b);
        float a1 = fmaf(h0, w2[5], fmaf(h1, w2[6], c2_1));
        const float a1b = fmaf(h2, w2[7], h3 * w2[8]);
        a1 = fmaf(h4, w2[9], a1 + a1b);
        sv0 = fmaf(u.x, sigm_fast(a0), sv0) + nz.x;
        sv1 = fmaf(u.y, sigm_fast(a1), sv1) + nz.y;
        if (t < 256) ((float2*)(out + O_ST_OBS))[t * 256 + b] = make_float2(sv0, sv1);
        else         ((float2*)(out + O_ST_PRED))[(t - 256) * 256 + b] = make_float2(sv0, sv1);
    };

    float2 cu[8], cn[8];
#pragma unroll
    for (int j = 0; j < 8; j++) LD(1 + j, cu[j], cn[j]);

#pragma unroll 1
    for (int base = 1; base < 288; base += 8) {
        float2 nu[8], nn[8];
#pragma unroll
        for (int j = 0; j < 8; j++) LD(base + 8 + j, nu[j], nn[j]);
#pragma unroll
        for (int j = 0; j < 8; j++) {
            if (base + j < 288) STEP(cu[j], cn[j], base + j);
        }
#pragma unroll
        for (int j = 0; j < 8; j++) { cu[j] = nu[j]; cn[j] = nn[j]; }
    }
}

// ==================== Kernel 0: U[t][b][2] = act^T . Wa ====================
extern "C" __global__ void __launch_bounds__(288)
k_pre(const float* __restrict__ act, const float* __restrict__ Wa, float* __restrict__ ws_u)
{
    const int b = blockIdx.x;
    const int t = threadIdx.x;
    float u0 = 0.f, u1 = 0.f;
#pragma unroll
    for (int a = 0; a < 5; a++) {
        const float av = act[(b * 5 + a) * 288 + t];
        u0 = fmaf(av, Wa[a], u0);
        u1 = fmaf(av, Wa[5 + a], u1);
    }
    ws_u[(t * 256 + b) * 2 + 0] = u0;
    ws_u[(t * 256 + b) * 2 + 1] = u1;
}

// ==================== Kernel 1a (fast path): conv1+maxpool, work = (b, t, posq) ====================
extern "C" __global__ void __launch_bounds__(256)
k_patch(const float* __restrict__ x, const int* __restrict__ pos,
        const float* __restrict__ s0, const float* __restrict__ nobs,
        const float* __restrict__ npred,
        const float* __restrict__ Ws1, const float* __restrict__ bs1,
        const float* __restrict__ Ws2, const float* __restrict__ bs2,
        const float* __restrict__ Wc1, const float* __restrict__ bc1,
        const float* __restrict__ ws_u, float* __restrict__ ws_pool,
        float* __restrict__ out)
{
    const int tid = threadIdx.x;
    if (blockIdx.x == 0) {
        run_recurrence(tid, s0, nobs, npred, Ws1, bs1, Ws2, bs2, ws_u, out);
        return;
    }
    const int bid = blockIdx.x - 1;
    const int b = bid / 5, c = bid % 5;

    __shared__ __align__(16) float sImg[3 * 1056];
    __shared__ float sWc1[192];
    __shared__ float sB1[16];

    for (int i = tid; i < 3072; i += 256) {
        const int ic = i >> 10, r = (i >> 5) & 31, cc = i & 31;
        sImg[ic * 1056 + r * 33 + cc] = x[b * 3072 + i];
    }
    if (tid < 192) sWc1[tid] = Wc1[tid];
    if (tid < 16) sB1[tid] = bc1[tid];
    __syncthreads();

    const int t = c * 64 + (tid >> 2);
    if (t >= 288) return;
    const int posq = tid & 3;
    const int py = posq >> 1, px = posq & 1;

    const int pr = 3 * pos[(b * 2 + 0) * 288 + t];
    const int pc = 3 * pos[(b * 2 + 1) * 288 + t];

    float p16[16];
#pragma unroll
    for (int i = 0; i < 16; i++) p16[i] = 0.f;

#pragma unroll 2
    for (int d = 0; d < 4; d++) {
        const int rbase = pr + 4 * py + 2 * (d >> 1);
        const int cbase = pc + 4 * px + 2 * (d & 1);
        float in[12];
#pragma unroll
        for (int ic = 0; ic < 3; ic++)
#pragma unroll
        for (int ky = 0; ky < 2; ky++)
#pragma unroll
        for (int kx = 0; kx < 2; kx++)
            in[ic * 4 + ky * 2 + kx] = sImg[ic * 1056 + (rbase + ky) * 33 + (cbase + kx)];
#pragma unroll
        for (int oc = 0; oc < 16; oc++) {
            const float4 wq0 = *(const float4*)&sWc1[oc * 12 + 0];
            const float4 wq1 = *(const float4*)&sWc1[oc * 12 + 4];
            const float4 wq2 = *(const float4*)&sWc1[oc * 12 + 8];
            float v = sB1[oc];
            v = FMA4(in[0], in[1], in[2], in[3], wq0, v);
            v = FMA4(in[4], in[5], in[6], in[7], wq1, v);
            v = FMA4(in[8], in[9], in[10], in[11], wq2, v);
            p16[oc] = fmaxf(p16[oc], fmaxf(v, 0.f));
        }
    }

    float4* dst = (float4*)(ws_pool + (((size_t)b * 288 + t) * 4 + posq) * 16);
    dst[0] = make_float4(p16[0], p16[1], p16[2], p16[3]);
    dst[1] = make_float4(p16[4], p16[5], p16[6], p16[7]);
    dst[2] = make_float4(p16[8], p16[9], p16[10], p16[11]);
    dst[3] = make_float4(p16[12], p16[13], p16[14], p16[15]);
}

// ==================== Kernel 1b (fast path): BN1 + conv2 + BN2 + heads ====================
// grid 288: block = timestep t; thread = batch b. zm/zs weights read wave-uniform from global
// (scalar-load broadcast) so LDS fits 2 blocks/CU (<= 81,920 B).
extern "C" __global__ void __launch_bounds__(256)
k_enc(const float* __restrict__ g1,   const float* __restrict__ be1,
      const float* __restrict__ Wc2,  const float* __restrict__ bc2,
      const float* __restrict__ g2,   const float* __restrict__ be2,
      const float* __restrict__ Wzm,  const float* __restrict__ bzm,
      const float* __restrict__ Wzs,  const float* __restrict__ bzs,
      const float* __restrict__ ws_pool, float* __restrict__ out)
{
    const int t = blockIdx.x, tid = threadIdx.x, b = tid;
    const int wid = tid >> 6, lane = tid & 63;

    __shared__ __align__(16) float pooledL[256 * 68];
    __shared__ __align__(16) float sWc2r[2048];
    __shared__ __align__(16) float sM1[16], sS1[16], sE1[16];
    __shared__ float sB2[32], sE2[32];
    __shared__ float sM2[32], sS2[32];
    __shared__ float sRed[4][64];

    for (int i = tid; i < 2048; i += 256) {
        const int oc = i >> 6, rem = i & 63, ic = rem >> 2, q = rem & 3;
        sWc2r[oc * 64 + q * 16 + ic] = Wc2[i];
    }
    if (tid < 16) { sE1[tid] = be1[tid]; }
    if (tid < 32) { sB2[tid] = bc2[tid]; sE2[tid] = be2[tid]; }

    float* myrow = &pooledL[b * 68];
    {
        const float4* src = (const float4*)(ws_pool + ((size_t)b * 288 + t) * 64);
#pragma unroll
        for (int q = 0; q < 16; q++) *(float4*)&myrow[4 * q] = src[q];
    }
    __syncthreads();

    {
        const int col = tid & 63, q = tid >> 6;
        float s = 0.f, ss = 0.f;
        const float* cp = &pooledL[(q * 64) * 68 + col];
#pragma unroll 4
        for (int i = 0; i < 64; i++) { const float v = cp[i * 68]; s += v; ss = fmaf(v, v, ss); }
        sRed[q][col] = s;
        __syncthreads();
        float ssum = 0.f;
        if (tid < 16) {
#pragma unroll
            for (int p = 0; p < 4; p++)
#pragma unroll
            for (int qq = 0; qq < 4; qq++) ssum += sRed[qq][p * 16 + tid];
        }
        __syncthreads();
        sRed[q][col] = ss;
        __syncthreads();
        if (tid < 16) {
            float sssum = 0.f;
#pragma unroll
            for (int p = 0; p < 4; p++)
#pragma unroll
            for (int qq = 0; qq < 4; qq++) sssum += sRed[qq][p * 16 + tid];
            const float m = ssum * (1.f / 1024.f);
            const float var = fmaf(-m, m, sssum * (1.f / 1024.f));
            sM1[tid] = m; sS1[tid] = g1[tid] * rsqrtf(var + 1e-5f);
        }
    }
    __syncthreads();

#pragma unroll 4
    for (int tq = 0; tq < 16; tq++) {
        const int ic0 = (tq & 3) * 4;
        float4 v = *(float4*)&myrow[4 * tq];
        const float4 mq = *(const float4*)&sM1[ic0];
        const float4 sq = *(const float4*)&sS1[ic0];
        const float4 eq = *(const float4*)&sE1[ic0];
        v.x = fmaf(v.x - mq.x, sq.x, eq.x);
        v.y = fmaf(v.y - mq.y, sq.y, eq.y);
        v.z = fmaf(v.z - mq.z, sq.z, eq.z);
        v.w = fmaf(v.w - mq.w, sq.w, eq.w);
        *(float4*)&myrow[4 * tq] = v;
    }

    float h2v[32];
#pragma unroll
    for (int og = 0; og < 4; og++) {
        float acc[8];
#pragma unroll
        for (int jj = 0; jj < 8; jj++) acc[jj] = sB2[og * 8 + jj];
#pragma unroll 2
        for (int tq = 0; tq < 16; tq++) {
            const float4 hq = *(const float4*)&myrow[4 * tq];
#pragma unroll
            for (int jj = 0; jj < 8; jj++) {
                const float4 wv = *(const float4*)&sWc2r[(og * 8 + jj) * 64 + 4 * tq];
                acc[jj] = FMA4(hq.x, hq.y, hq.z, hq.w, wv, acc[jj]);
            }
        }
#pragma unroll
        for (int jj = 0; jj < 8; jj++) h2v[og * 8 + jj] = fmaxf(acc[jj], 0.f);
    }

#pragma unroll
    for (int oc = 0; oc < 32; oc++) {
        float s = wred(h2v[oc]), ss = wred(h2v[oc] * h2v[oc]);
        if (lane == 0) { sRed[wid][2 * oc] = s; sRed[wid][2 * oc + 1] = ss; }
    }
    __syncthreads();
    if (tid < 32) {
        const float s  = sRed[0][2 * tid] + sRed[1][2 * tid] + sRed[2][2 * tid] + sRed[3][2 * tid];
        const float ss = sRed[0][2 * tid + 1] + sRed[1][2 * tid + 1] + sRed[2][2 * tid + 1] + sRed[3][2 * tid + 1];
        const float m = s * (1.f / 256.f);
        const float var = fmaf(-m, m, ss * (1.f / 256.f));
        sM2[tid] = m; sS2[tid] = g2[tid] * rsqrtf(var + 1e-5f);
    }
    __syncthreads();
#pragma unroll
    for (int oc = 0; oc < 32; oc++) h2v[oc] = fmaf(h2v[oc] - sM2[oc], sS2[oc], sE2[oc]);

    // ---- zm / zs heads: weights read wave-uniform from global (s_load broadcast) ----
    const int obase_m = (t < 256) ? (O_ZM_OBS + (t * 256 + b) * 16) : (O_ZM_PRED + ((t - 256) * 256 + b) * 16);
    const int obase_s = (t < 256) ? (O_ZS_OBS + (t * 256 + b) * 16) : (O_ZS_PRED + ((t - 256) * 256 + b) * 16);
#pragma unroll 2
    for (int k = 0; k < 16; k++) {
        float vm = bzm[k], vs = bzs[k];
#pragma unroll
        for (int c = 0; c < 32; c += 4) {
            const float4 wm = *(const float4*)&Wzm[k * 32 + c];
            const float4 wsq = *(const float4*)&Wzs[k * 32 + c];
            vm = FMA4(h2v[c], h2v[c + 1], h2v[c + 2], h2v[c + 3], wm, vm);
            vs = FMA4(h2v[c], h2v[c + 1], h2v[c + 2], h2v[c + 3], wsq, vs);
        }
        out[obase_m + k] = vm;
        out[obase_s + k] = __expf(vs);
    }
}

// ==================== Kernel 1 (fallback): fused encoder with global gathers ====================
extern "C" __global__ void __launch_bounds__(256)
k_enc_full(const float* __restrict__ x,
           const int*   __restrict__ pos,  const float* __restrict__ s0,
           const float* __restrict__ nobs, const float* __restrict__ npred,
           const float* __restrict__ Ws1,  const float* __restrict__ bs1,
           const float* __restrict__ Ws2,  const float* __restrict__ bs2,
           const float* __restrict__ Wc1,  const float* __restrict__ bc1,
           const float* __restrict__ g1,   const float* __restrict__ be1,
           const float* __restrict__ Wc2,  const float* __restrict__ bc2,
           const float* __restrict__ g2,   const float* __restrict__ be2,
           const float* __restrict__ Wzm,  const float* __restrict__ bzm,
           const float* __restrict__ Wzs,  const float* __restrict__ bzs,
           const float* __restrict__ ws_u, float* __restrict__ out)
{
    const int tid = threadIdx.x;
    if (blockIdx.x == 0) {
        run_recurrence(tid, s0, nobs, npred, Ws1, bs1, Ws2, bs2, ws_u, out);
        return;
    }
    const int t = blockIdx.x - 1;
    __shared__ __align__(16) float sWc1[192];
    __shared__ __align__(16) float sWc2r[2048];
    __shared__ __align__(16) float sM1[16], sS1[16], sE1[16];
    __shared__ float sB1[16], sB2[32], sE2[32];
    __shared__ float sM2[32], sS2[32];
    __shared__ float sRed[4][64];
    __shared__ __align__(16) float pooledL[256 * 68];

    for (int i = tid; i < 192; i += 256) sWc1[i] = Wc1[i];
    for (int i = tid; i < 2048; i += 256) {
        const int oc = i >> 6, rem = i & 63, ic = rem >> 2, q = rem & 3;
        sWc2r[oc * 64 + q * 16 + ic] = Wc2[i];
    }
    if (tid < 16) { sB1[tid] = bc1[tid]; sE1[tid] = be1[tid]; }
    if (tid < 32) { sB2[tid] = bc2[tid]; sE2[tid] = be2[tid]; }
    __syncthreads();

    const int b = tid;
    const int wid = tid >> 6, lane = tid & 63;
    const float* xb = x + b * 3072;
    const int pr = 3 * pos[(b * 2 + 0) * 288 + t];
    const int pc = 3 * pos[(b * 2 + 1) * 288 + t];
    float* myrow = &pooledL[b * 68];

#pragma unroll
    for (int py = 0; py < 2; py++)
#pragma unroll
    for (int px = 0; px < 2; px++) {
        float p16[16];
#pragma unroll
        for (int i = 0; i < 16; i++) p16[i] = 0.f;
#pragma unroll 2
        for (int d = 0; d < 4; d++) {
            const int rbase = pr + 4 * py + 2 * (d >> 1);
            const int cbase = pc + 4 * px + 2 * (d & 1);
            float in[12];
#pragma unroll
            for (int ic = 0; ic < 3; ic++)
#pragma unroll
            for (int ky = 0; ky < 2; ky++)
#pragma unroll
            for (int kx = 0; kx < 2; kx++)
                in[ic * 4 + ky * 2 + kx] = xb[ic * 1024 + (rbase + ky) * 32 + (cbase + kx)];
#pragma unroll
            for (int oc = 0; oc < 16; oc++) {
                const float4 wq0 = *(const float4*)&sWc1[oc * 12 + 0];
                const float4 wq1 = *(const float4*)&sWc1[oc * 12 + 4];
                const float4 wq2 = *(const float4*)&sWc1[oc * 12 + 8];
                float v = sB1[oc];
                v = FMA4(in[0], in[1], in[2], in[3], wq0, v);
                v = FMA4(in[4], in[5], in[6], in[7], wq1, v);
                v = FMA4(in[8], in[9], in[10], in[11], wq2, v);
                p16[oc] = fmaxf(p16[oc], fmaxf(v, 0.f));
            }
        }
        const int pbase = (py * 2 + px) * 16;
        *(float4*)&myrow[pbase + 0]  = make_float4(p16[0], p16[1], p16[2], p16[3]);
        *(float4*)&myrow[pbase + 4]  = make_float4(p16[4], p16[5], p16[6], p16[7]);
        *(float4*)&myrow[pbase + 8]  = make_float4(p16[8], p16[9], p16[10], p16[11]);
        *(float4*)&myrow[pbase + 12] = make_float4(p16[12], p16[13], p16[14], p16[15]);
    }
    __syncthreads();

    {
        const int col = tid & 63, q = tid >> 6;
        float s = 0.f, ss = 0.f;
        const float* cp = &pooledL[(q * 64) * 68 + col];
#pragma unroll 4
        for (int i = 0; i < 64; i++) { const float v = cp[i * 68]; s += v; ss = fmaf(v, v, ss); }
        sRed[q][col] = s;
        __syncthreads();
        float ssum = 0.f;
        if (tid < 16) {
#pragma unroll
            for (int p = 0; p < 4; p++)
#pragma unroll
            for (int qq = 0; qq < 4; qq++) ssum += sRed[qq][p * 16 + tid];
        }
        __syncthreads();
        sRed[q][col] = ss;
        __syncthreads();
        if (tid < 16) {
            float sssum = 0.f;
#pragma unroll
            for (int p = 0; p < 4; p++)
#pragma unroll
            for (int qq = 0; qq < 4; qq++) sssum += sRed[qq][p * 16 + tid];
            const float m = ssum * (1.f / 1024.f);
            const float var = fmaf(-m, m, sssum * (1.f / 1024.f));
            sM1[tid] = m; sS1[tid] = g1[tid] * rsqrtf(var + 1e-5f);
        }
    }
    __syncthreads();

#pragma unroll 4
    for (int tq = 0; tq < 16; tq++) {
        const int ic0 = (tq & 3) * 4;
        float4 v = *(float4*)&myrow[4 * tq];
        const float4 mq = *(const float4*)&sM1[ic0];
        const float4 sq = *(const float4*)&sS1[ic0];
        const float4 eq = *(const float4*)&sE1[ic0];
        v.x = fmaf(v.x - mq.x, sq.x, eq.x);
        v.y = fmaf(v.y - mq.y, sq.y, eq.y);
        v.z = fmaf(v.z - mq.z, sq.z, eq.z);
        v.w = fmaf(v.w - mq.w, sq.w, eq.w);
        *(float4*)&myrow[4 * tq] = v;
    }

    float h2v[32];
#pragma unroll
    for (int og = 0; og < 4; og++) {
        float acc[8];
#pragma unroll
        for (int jj = 0; jj < 8; jj++) acc[jj] = sB2[og * 8 + jj];
#pragma unroll 2
        for (int tq = 0; tq < 16; tq++) {
            const float4 hq = *(const float4*)&myrow[4 * tq];
#pragma unroll
            for (int jj = 0; jj < 8; jj++) {
                const float4 wv = *(const float4*)&sWc2r[(og * 8 + jj) * 64 + 4 * tq];
                acc[jj] = FMA4(hq.x, hq.y, hq.z, hq.w, wv, acc[jj]);
            }
        }
#pragma unroll
        for (int jj = 0; jj < 8; jj++) h2v[og * 8 + jj] = fmaxf(acc[jj], 0.f);
    }

#pragma unroll
    for (int oc = 0; oc < 32; oc++) {
        float s = wred(h2v[oc]), ss = wred(h2v[oc] * h2v[oc]);
        if (lane == 0) { sRed[wid][2 * oc] = s; sRed[wid][2 * oc + 1] = ss; }
    }
    __syncthreads();
    if (tid < 32) {
        const float s  = sRed[0][2 * tid] + sRed[1][2 * tid] + sRed[2][2 * tid] + sRed[3][2 * tid];
        const float ss = sRed[0][2 * tid + 1] + sRed[1][2 * tid + 1] + sRed[2][2 * tid + 1] + sRed[3][2 * tid + 1];
        const float m = s * (1.f / 256.f);
        const float var = fmaf(-m, m, ss * (1.f / 256.f));
        sM2[tid] = m; sS2[tid] = g2[tid] * rsqrtf(var + 1e-5f);
    }
    __syncthreads();
#pragma unroll
    for (int oc = 0; oc < 32; oc++) h2v[oc] = fmaf(h2v[oc] - sM2[oc], sS2[oc], sE2[oc]);

    const int obase_m = (t < 256) ? (O_ZM_OBS + (t * 256 + b) * 16) : (O_ZM_PRED + ((t - 256) * 256 + b) * 16);
    const int obase_s = (t < 256) ? (O_ZS_OBS + (t * 256 + b) * 16) : (O_ZS_PRED + ((t - 256) * 256 + b) * 16);
#pragma unroll 2
    for (int k = 0; k < 16; k++) {
        float vm = bzm[k], vs = bzs[k];
#pragma unroll
        for (int c = 0; c < 32; c += 4) {
            const float4 wm = *(const float4*)&Wzm[k * 32 + c];
            const float4 wsq = *(const float4*)&Wzs[k * 32 + c];
            vm = FMA4(h2v[c], h2v[c + 1], h2v[c + 2], h2v[c + 3], wm, vm);
            vs = FMA4(h2v[c], h2v[c + 1], h2v[c + 2], h2v[c + 3], wsq, vs);
        }
        out[obase_m + k] = vm;
        out[obase_s + k] = __expf(vs);
    }
}

// ==================== Kernel 2: 512-thread loop-based decoder front half ====================
extern "C" __global__ void __launch_bounds__(512)
k_dec1(const float* __restrict__ eps,
       const float* __restrict__ Wd1,  const float* __restrict__ bd1,
       const float* __restrict__ gd1,  const float* __restrict__ bed1,
       const float* __restrict__ Wd2,  const float* __restrict__ bd2,
       const float* __restrict__ gd2,  const float* __restrict__ bed2,
       const float* __restrict__ Wt1,  const float* __restrict__ bt1,
       const float* __restrict__ out,
       float* __restrict__ ws_h2n, float* __restrict__ ws_p3)
{
    const int tp = blockIdx.x >> 2, g = blockIdx.x & 3;
    const int tid = threadIdx.x;
    const int b = tid & 255, half = tid >> 8;
    const int wid = tid >> 6, lane = tid & 63;

    __shared__ __align__(16) float sWd1[1024];
    __shared__ __align__(16) float sWd2g[2048];
    __shared__ __align__(16) float sWt1g[2048];
    __shared__ float h1L[256 * 65];
    __shared__ float h2L[256 * 33];
    __shared__ float sRed[8][128];
    __shared__ float sAcc[8][32];
    __shared__ float sM1[64], sS1[64], sE1[64];
    __shared__ float sM2[32], sS2[32], sE2[32];
    __shared__ float sBd1[64], sBd2g[32], sBt1[16];
    float* sRedF = &sRed[0][0];

    for (int i = tid; i < 1024; i += 512) sWd1[i] = Wd1[i];
    for (int i = tid; i < 2048; i += 512) {
        const int ic = i >> 6, k = i & 63;
        sWd2g[i] = Wd2[(4 * ic + g) * 64 + k];
    }
    for (int i = tid; i < 2048; i += 512) {
        const int dp = i >> 9, rem = i & 511, oc = rem >> 5, ic = i & 31;
        const int py = (g >> 1) * 2 + (dp >> 1), px = (g & 1) * 2 + (dp & 1);
        const int k9 = ((py + 1) % 3) * 3 + ((px + 1) % 3);
        sWt1g[(dp * 16 + oc) * 32 + ic] = Wt1[ic * 144 + oc * 9 + k9];
    }
    if (tid < 64) sBd1[tid] = bd1[tid];
    if (tid < 32) sBd2g[tid] = bd2[4 * tid + g];
    if (tid < 16) sBt1[tid] = bt1[tid];
    if (tid < 256) ((float*)sAcc)[tid] = 0.f;
    __syncthreads();

    float4 zA, zB, zC, zD;
    {
        const int base = (tp * 256 + b) * 16;
        const float4 e0 = *(const float4*)&eps[base + 0],  e1 = *(const float4*)&eps[base + 4];
        const float4 e2 = *(const float4*)&eps[base + 8],  e3 = *(const float4*)&eps[base + 12];
        const float4 s0v = *(const float4*)&out[O_ZS_PRED + base + 0],  s1v = *(const float4*)&out[O_ZS_PRED + base + 4];
        const float4 s2v = *(const float4*)&out[O_ZS_PRED + base + 8],  s3v = *(const float4*)&out[O_ZS_PRED + base + 12];
        const float4 m0 = *(const float4*)&out[O_ZM_PRED + base + 0],  m1 = *(const float4*)&out[O_ZM_PRED + base + 4];
        const float4 m2 = *(const float4*)&out[O_ZM_PRED + base + 8],  m3 = *(const float4*)&out[O_ZM_PRED + base + 12];
        zA = make_float4(fmaf(e0.x,s0v.x,m0.x), fmaf(e0.y,s0v.y,m0.y), fmaf(e0.z,s0v.z,m0.z), fmaf(e0.w,s0v.w,m0.w));
        zB = make_float4(fmaf(e1.x,s1v.x,m1.x), fmaf(e1.y,s1v.y,m1.y), fmaf(e1.z,s1v.z,m1.z), fmaf(e1.w,s1v.w,m1.w));
        zC = make_float4(fmaf(e2.x,s2v.x,m2.x), fmaf(e2.y,s2v.y,m2.y), fmaf(e2.z,s2v.z,m2.z), fmaf(e2.w,s2v.w,m2.w));
        zD = make_float4(fmaf(e3.x,s3v.x,m3.x), fmaf(e3.y,s3v.y,m3.y), fmaf(e3.z,s3v.z,m3.z), fmaf(e3.w,s3v.w,m3.w));
    }

#pragma unroll 4
    for (int jj = 0; jj < 32; ++jj) {
        const int j = half * 32 + jj;
        const float4 wq0 = *(const float4*)&sWd1[j * 16 + 0];
        const float4 wq1 = *(const float4*)&sWd1[j * 16 + 4];
        const float4 wq2 = *(const float4*)&sWd1[j * 16 + 8];
        const float4 wq3 = *(const float4*)&sWd1[j * 16 + 12];
        float v = sBd1[j];
        v = FMA4(zA.x, zA.y, zA.z, zA.w, wq0, v);
        v = FMA4(zB.x, zB.y, zB.z, zB.w, wq1, v);
        v = FMA4(zC.x, zC.y, zC.z, zC.w, wq2, v);
        v = FMA4(zD.x, zD.y, zD.z, zD.w, wq3, v);
        h1L[b * 65 + j] = fmaxf(v, 0.f);
    }
    __syncthreads();

    {
        const int col = tid & 63, q = tid >> 6;
        float s = 0.f, ss = 0.f;
        const float* cp = &h1L[(q * 32) * 65 + col];
#pragma unroll 4
        for (int i = 0; i < 32; i++) { const float v = cp[i * 65]; s += v; ss = fmaf(v, v, ss); }
        sRed[q][2 * col] = s; sRed[q][2 * col + 1] = ss;
    }
    __syncthreads();
    if (tid < 64) {
        float s = 0.f, ss = 0.f;
#pragma unroll
        for (int q = 0; q < 8; q++) { s += sRed[q][2 * tid]; ss += sRed[q][2 * tid + 1]; }
        const float m = s * (1.f / 256.f);
        const float var = fmaf(-m, m, ss * (1.f / 256.f));
        sM1[tid] = m; sS1[tid] = gd1[tid] * rsqrtf(var + 1e-5f); sE1[tid] = bed1[tid];
    }
    __syncthreads();

#pragma unroll 4
    for (int jj = 0; jj < 32; ++jj) {
        const int j = half * 32 + jj;
        h1L[b * 65 + j] = fmaf(h1L[b * 65 + j] - sM1[j], sS1[j], sE1[j]);
    }
    __syncthreads();

    float hr[64];
#pragma unroll
    for (int k = 0; k < 64; ++k) hr[k] = h1L[b * 65 + k];

#pragma unroll 1
    for (int ic = 0; ic < 16; ++ic) {
        const int icg = half * 16 + ic;
        float v = sBd2g[icg];
#pragma unroll
        for (int k4 = 0; k4 < 16; ++k4) {
            const float4 wv = *(const float4*)&sWd2g[icg * 64 + 4 * k4];
            v = FMA4(hr[4*k4], hr[4*k4+1], hr[4*k4+2], hr[4*k4+3], wv, v);
        }
        h2L[b * 33 + icg] = fmaxf(v, 0.f);
    }
    __syncthreads();

    {
        const int col = tid & 31, q = tid >> 5;
        float s = 0.f, ss = 0.f;
        const float* cp = &h2L[(q * 16) * 33 + col];
#pragma unroll 4
        for (int i = 0; i < 16; i++) { const float v = cp[i * 33]; s += v; ss = fmaf(v, v, ss); }
        sRedF[q * 32 + col] = s;
        __syncthreads();
        float ssum = 0.f;
        if (tid < 32) {
#pragma unroll
            for (int qq = 0; qq < 16; qq++) ssum += sRedF[qq * 32 + tid];
        }
        __syncthreads();
        sRedF[q * 32 + col] = ss;
        __syncthreads();
        if (tid < 32) {
            float sssum = 0.f;
#pragma unroll
            for (int qq = 0; qq < 16; qq++) sssum += sRedF[qq * 32 + tid];
            const float m = ssum * (1.f / 256.f);
            const float var = fmaf(-m, m, sssum * (1.f / 256.f));
            sM2[tid] = m;
            sS2[tid] = gd2[4 * tid + g] * rsqrtf(var + 1e-5f);
            sE2[tid] = bed2[4 * tid + g];
        }
    }
    __syncthreads();

#pragma unroll 4
    for (int ic = 0; ic < 16; ++ic) {
        const int icg = half * 16 + ic;
        h2L[b * 33 + icg] = fmaf(h2L[b * 33 + icg] - sM2[icg], sS2[icg], sE2[icg]);
    }
    __syncthreads();

    float h2r[32];
#pragma unroll
    for (int k = 0; k < 32; ++k) h2r[k] = h2L[b * 33 + k];
    {
        float* dst = ws_h2n + (((size_t)(tp * 4 + g) * 256 + b) * 32 + half * 16);
        const int o = half * 16;
        *(float4*)&dst[0]  = make_float4(h2r[o+0],  h2r[o+1],  h2r[o+2],  h2r[o+3]);
        *(float4*)&dst[4]  = make_float4(h2r[o+4],  h2r[o+5],  h2r[o+6],  h2r[o+7]);
        *(float4*)&dst[8]  = make_float4(h2r[o+8],  h2r[o+9],  h2r[o+10], h2r[o+11]);
        *(float4*)&dst[12] = make_float4(h2r[o+12], h2r[o+13], h2r[o+14], h2r[o+15]);
    }

#pragma unroll 1
    for (int d2 = 0; d2 < 2; ++d2) {
        const int dp = half * 2 + d2;
#pragma unroll 1
        for (int oc = 0; oc < 16; ++oc) {
            float v = sBt1[oc];
            const float* wrow = &sWt1g[(dp * 16 + oc) * 32];
#pragma unroll
            for (int i4 = 0; i4 < 8; ++i4) {
                const float4 wv = *(const float4*)&wrow[4 * i4];
                v = FMA4(h2r[4*i4], h2r[4*i4+1], h2r[4*i4+2], h2r[4*i4+3], wv, v);
            }
            v = fmaxf(v, 0.f);
            const float s = wred(v), ss = wred(v * v);
            if (lane == 0) { sAcc[wid][2 * oc] += s; sAcc[wid][2 * oc + 1] += ss; }
        }
    }
    __syncthreads();
    if (tid < 16) {
        float s = 0.f, ss = 0.f;
#pragma unroll
        for (int w = 0; w < 8; w++) { s += sAcc[w][2 * tid]; ss += sAcc[w][2 * tid + 1]; }
        ws_p3[(tp * 4 + g) * 32 + 2 * tid + 0] = s;
        ws_p3[(tp * 4 + g) * 32 + 2 * tid + 1] = ss;
    }
}

// ==================== Kernel 3: BN3 finalize + convT1 recompute + convT2 + nll ====================
// grid 256: bid -> tp = bid>>3, g = (bid>>1)&3, hf = bid&1; each block does dp = hf*2 + {0,1}
extern "C" __global__ void __launch_bounds__(256)
k_dec2(const float* __restrict__ x,    const int* __restrict__ pos,
       const float* __restrict__ Wt1,  const float* __restrict__ bt1,
       const float* __restrict__ gt1,  const float* __restrict__ bet1,
       const float* __restrict__ Wt2,  const float* __restrict__ bt2,
       float* __restrict__ out,
       const float* __restrict__ ws_h2n, const float* __restrict__ ws_p3)
{
    const int tp = blockIdx.x >> 3, g = (blockIdx.x >> 1) & 3, hf = blockIdx.x & 1;
    const int tid = threadIdx.x, b = tid;
    const int wid = tid >> 6, lane = tid & 63;

    __shared__ __align__(16) float sWt1g[1024];   // [(d2*16+oc)][32] for this block's 2 dp
    __shared__ __align__(16) float sWt2[192];
    __shared__ float sBt1[16], sBt2[3];
    __shared__ float sRed[4][64];
    __shared__ float sM3[16], sS3[16], sE3[16];

    for (int i = tid; i < 1024; i += 256) {
        const int d2 = i >> 9, rem = i & 511, oc = rem >> 5, ic = i & 31;
        const int dp = hf * 2 + d2;
        const int py = (g >> 1) * 2 + (dp >> 1), px = (g & 1) * 2 + (dp & 1);
        const int k9 = ((py + 1) % 3) * 3 + ((px + 1) % 3);
        sWt1g[(d2 * 16 + oc) * 32 + ic] = Wt1[ic * 144 + oc * 9 + k9];
    }
    if (tid < 192) { const int ic = tid / 12, r = tid % 12; sWt2[r * 16 + ic] = Wt2[tid]; }
    if (tid < 16) sBt1[tid] = bt1[tid];
    if (tid < 3) sBt2[tid] = bt2[tid];
    if (tid < 16) {
        float s = 0.f, ss = 0.f;
#pragma unroll
        for (int gg = 0; gg < 4; gg++) {
            s  += ws_p3[(tp * 4 + gg) * 32 + 2 * tid + 0];
            ss += ws_p3[(tp * 4 + gg) * 32 + 2 * tid + 1];
        }
        const float m = s * (1.f / 4096.f);
        const float var = fmaf(-m, m, ss * (1.f / 4096.f));
        sM3[tid] = m; sS3[tid] = gt1[tid] * rsqrtf(var + 1e-5f); sE3[tid] = bet1[tid];
    }
    __syncthreads();

    float h2g[32];
    {
        const float* src = ws_h2n + (((size_t)(tp * 4 + g) * 256 + b) * 32);
#pragma unroll
        for (int i4 = 0; i4 < 8; i4++) {
            const float4 v4 = *(const float4*)&src[4 * i4];
            h2g[4 * i4] = v4.x; h2g[4 * i4 + 1] = v4.y; h2g[4 * i4 + 2] = v4.z; h2g[4 * i4 + 3] = v4.w;
        }
    }

    const int t = 256 + tp;
    const int pr = 3 * pos[(b * 2 + 0) * 288 + t];
    const int pc = 3 * pos[(b * 2 + 1) * 288 + t];
    const float* xb = x + b * 3072;
    const int rbase = O_XREC + (tp * 256 + b) * 192;
    const int py0 = (g >> 1) * 2, px0 = (g & 1) * 2;
    float err = 0.f;

#pragma unroll 1
    for (int d2 = 0; d2 < 2; d2++) {
        const int dp = hf * 2 + d2;
        const int py = py0 + (dp >> 1), px = px0 + (dp & 1);
        float hn[16];
#pragma unroll
        for (int og = 0; og < 4; og++) {
            float acc[4];
#pragma unroll
            for (int jj = 0; jj < 4; jj++) acc[jj] = sBt1[og * 4 + jj];
#pragma unroll
            for (int i4 = 0; i4 < 8; i4++) {
#pragma unroll
                for (int jj = 0; jj < 4; jj++) {
                    const float4 wv = *(const float4*)&sWt1g[(d2 * 16 + og * 4 + jj) * 32 + 4 * i4];
                    acc[jj] = FMA4(h2g[4*i4], h2g[4*i4+1], h2g[4*i4+2], h2g[4*i4+3], wv, acc[jj]);
                }
            }
#pragma unroll
            for (int jj = 0; jj < 4; jj++) {
                const int oc = og * 4 + jj;
                hn[oc] = fmaf(fmaxf(acc[jj], 0.f) - sM3[oc], sS3[oc], sE3[oc]);
            }
        }
#pragma unroll
        for (int c = 0; c < 3; c++)
#pragma unroll
        for (int dy = 0; dy < 2; dy++)
#pragma unroll
        for (int dx = 0; dx < 2; dx++) {
            const float* wp = &sWt2[(c * 4 + dy * 2 + dx) * 16];
            float v = sBt2[c];
#pragma unroll
            for (int ic = 0; ic < 16; ic += 4) {
                const float4 wq = *(const float4*)&wp[ic];
                v = FMA4(hn[ic], hn[ic + 1], hn[ic + 2], hn[ic + 3], wq, v);
            }
            v = sigm(v);
            const int oy = 2 * py + dy, ox = 2 * px + dx;
            out[rbase + c * 64 + oy * 8 + ox] = v;
            const float d = v - xb[c * 1024 + (pr + oy) * 32 + (pc + ox)];
            err = fmaf(d, d, err);
        }
    }

    const float es = wred(err);
    if (lane == 0) sRed[wid][0] = es;
    __syncthreads();
    if (tid == 0)
        atomicAdd(&out[O_NLL], sRed[0][0] + sRed[1][0] + sRed[2][0] + sRed[3][0]);
}

// ==================== host ====================
extern "C" void kernel_launch(void* const* d_in, const int* in_sizes, int n_in,
                              void* d_out, int out_size, void* d_ws, size_t ws_size,
                              hipStream_t stream)
{
    const float* x    = (const float*)d_in[0];
    const float* act  = (const float*)d_in[1];
    const int*   pos  = (const int*)d_in[2];
    const float* s0   = (const float*)d_in[3];
    const float* nobs = (const float*)d_in[4];
    const float* nprd = (const float*)d_in[5];
    const float* eps  = (const float*)d_in[6];
    const float* Wa   = (const float*)d_in[7];
    const float* Ws1  = (const float*)d_in[8];
    const float* bs1  = (const float*)d_in[9];
    const float* Ws2  = (const float*)d_in[10];
    const float* bs2  = (const float*)d_in[11];
    const float* Wc1  = (const float*)d_in[12];
    const float* bc1  = (const float*)d_in[13];
    const float* g1   = (const float*)d_in[14];
    const float* be1  = (const float*)d_in[15];
    const float* Wc2  = (const float*)d_in[16];
    const float* bc2  = (const float*)d_in[17];
    const float* g2   = (const float*)d_in[18];
    const float* be2  = (const float*)d_in[19];
    const float* Wzm  = (const float*)d_in[20];
    const float* bzm  = (const float*)d_in[21];
    const float* Wzs  = (const float*)d_in[22];
    const float* bzs  = (const float*)d_in[23];
    const float* Wd1  = (const float*)d_in[24];
    const float* bd1  = (const float*)d_in[25];
    const float* gd1  = (const float*)d_in[26];
    const float* bed1 = (const float*)d_in[27];
    const float* Wd2  = (const float*)d_in[28];
    const float* bd2  = (const float*)d_in[29];
    const float* gd2  = (const float*)d_in[30];
    const float* bed2 = (const float*)d_in[31];
    const float* Wt1  = (const float*)d_in[32];
    const float* bt1  = (const float*)d_in[33];
    const float* gt1  = (const float*)d_in[34];
    const float* bet1 = (const float*)d_in[35];
    const float* Wt2  = (const float*)d_in[36];
    const float* bt2  = (const float*)d_in[37];
    float* out = (float*)d_out;
    float* ws  = (float*)d_ws;

    const size_t need_fast = (POOL_FLOATS + 147456) * sizeof(float);  // 19.46 MB

    if (ws_size >= need_fast) {
        float* ws_pool = ws;
        float* ws_u    = ws + POOL_FLOATS;
        float* ws_h2n  = ws;                 // reuses pool region after k_enc consumed it
        float* ws_p3   = ws + 1048576;

        k_pre<<<dim3(256), dim3(288), 0, stream>>>(act, Wa, ws_u);
        k_patch<<<dim3(1281), dim3(256), 0, stream>>>(
            x, pos, s0, nobs, nprd, Ws1, bs1, Ws2, bs2, Wc1, bc1, ws_u, ws_pool, out);
        k_enc<<<dim3(288), dim3(256), 0, stream>>>(
            g1, be1, Wc2, bc2, g2, be2, Wzm, bzm, Wzs, bzs, ws_pool, out);
        k_dec1<<<dim3(128), dim3(512), 0, stream>>>(
            eps, Wd1, bd1, gd1, bed1, Wd2, bd2, gd2, bed2, Wt1, bt1, out, ws_h2n, ws_p3);
        k_dec2<<<dim3(256), dim3(256), 0, stream>>>(
            x, pos, Wt1, bt1, gt1, bet1, Wt2, bt2, out, ws_h2n, ws_p3);
    } else {
        float* ws_u   = ws;
        float* ws_h2n = ws + 147456;
        float* ws_p3  = ws + 1196032;

        k_pre<<<dim3(256), dim3(288), 0, stream>>>(act, Wa, ws_u);
        k_enc_full<<<dim3(289), dim3(256), 0, stream>>>(
            x, pos, s0, nobs, nprd, Ws1, bs1, Ws2, bs2,
            Wc1, bc1, g1, be1, Wc2, bc2, g2, be2, Wzm, bzm, Wzs, bzs, ws_u, out);
        k_dec1<<<dim3(128), dim3(512), 0, stream>>>(
            eps, Wd1, bd1, gd1, bed1, Wd2, bd2, gd2, bed2, Wt1, bt1, out, ws_h2n, ws_p3);
        k_dec2<<<dim3(256), dim3(256), 0, stream>>>(
            x, pos, Wt1, bt1, gt1, bet1, Wt2, bt2, out, ws_h2n, ws_p3);
    }
}

// Round 11
// 171.567 us; speedup vs baseline: 2.9016x; 1.0564x over previous
//
#include <hip/hip_runtime.h>
#include <hip/hip_bf16.h>
#include <math.h>

// ---------------- problem constants ----------------
#define NB   256
#define NT   288
#define NOBS 256
#define NTP  32

// output offsets (floats)
#define O_ST_OBS   0
#define O_ST_PRED  131072
#define O_ZM_OBS   147456
#define O_ZS_OBS   1196032
#define O_ZM_PRED  2244608
#define O_ZS_PRED  2375680
#define O_XREC     2506752
#define O_NLL      4079616

#define POOL_FLOATS ((size_t)288 * 256 * 64)   // 4,718,592 floats = 18.9 MB

__device__ __forceinline__ float wred(float v) {
    v += __shfl_down(v, 32); v += __shfl_down(v, 16); v += __shfl_down(v, 8);
    v += __shfl_down(v, 4);  v += __shfl_down(v, 2);  v += __shfl_down(v, 1);
    return v;
}
__device__ __forceinline__ float sigm(float x) { return 1.0f / (1.0f + __expf(-x)); }

// fast reciprocal (v_rcp_f32, ~1 ulp) with safe fallback
__device__ __forceinline__ float frcp(float x) {
#if __has_builtin(__builtin_amdgcn_rcpf)
    return __builtin_amdgcn_rcpf(x);
#else
    return 1.0f / x;
#endif
}
// clamp-free: e^{2x} overflow -> inf -> rcp -> 0 -> tanh=+1; underflow -> rcp(1)=1 -> -1.
__device__ __forceinline__ float tanh_fast(float x) {
    return fmaf(-2.0f, frcp(__expf(2.0f * x) + 1.0f), 1.0f);
}
__device__ __forceinline__ float sigm_fast(float x) {
    return frcp(1.0f + __expf(-x));
}

// NOTE: no macro parameter may be named x/y/z/w (member-access collision!)
#define FMA4(ax,ay,az,aw,wv,acc) fmaf((ax),(wv).x,fmaf((ay),(wv).y,fmaf((az),(wv).z,fmaf((aw),(wv).w,(acc)))))

// ==================== recurrence (device fn; one 256-thread block, thread = b) ====================
__device__ __forceinline__ void run_recurrence(
    int b, const float* __restrict__ s0,
    const float* __restrict__ nobs, const float* __restrict__ npred,
    const float* __restrict__ Ws1, const float* __restrict__ bs1,
    const float* __restrict__ Ws2, const float* __restrict__ bs2,
    const float* __restrict__ ws_u, float* __restrict__ out)
{
    float w1[10], w2[10], c1[5], c2_0, c2_1;
#pragma unroll
    for (int i = 0; i < 10; i++) { w1[i] = Ws1[i]; w2[i] = Ws2[i]; }
#pragma unroll
    for (int i = 0; i < 5; i++) c1[i] = bs1[i];
    c2_0 = bs2[0]; c2_1 = bs2[1];

    float sv0 = s0[b * 2 + 0], sv1 = s0[b * 2 + 1];
    ((float2*)(out + O_ST_OBS))[b] = make_float2(sv0, sv1);
    if (b == 0) out[O_NLL] = 0.0f;   // re-zeroed every call; stream-ordered before k_dec2

    const float2* Up   = (const float2*)ws_u;
    const float2* Nobs = (const float2*)nobs;
    const float2* Nprd = (const float2*)npred;

    auto LD = [&](int t, float2& u, float2& nz) {
        t = (t > 287) ? 287 : t;
        u  = Up[t * 256 + b];
        nz = (t < 256) ? Nobs[(t - 1) * 256 + b] : Nprd[(t - 256) * 256 + b];
    };
    auto STEP = [&](float2 u, float2 nz, int t) {
        const float v0 = sv0 + u.x, v1 = sv1 + u.y;
        const float h0 = tanh_fast(fmaf(v1, w1[1], fmaf(v0, w1[0], c1[0])));
        const float h1 = tanh_fast(fmaf(v1, w1[3], fmaf(v0, w1[2], c1[1])));
        const float h2 = tanh_fast(fmaf(v1, w1[5], fmaf(v0, w1[4], c1[2])));
        const float h3 = tanh_fast(fmaf(v1, w1[7], fmaf(v0, w1[6], c1[3])));
        const float h4 = tanh_fast(fmaf(v1, w1[9], fmaf(v0, w1[8], c1[4])));
        float a0 = fmaf(h0, w2[0], fmaf(h1, w2[1], c2_0));
        const float a0b = fmaf(h2, w2[2], h3 * w2[3]);
        a0 = fmaf(h4, w2[4], a0 + a0b);
        float a1 = fmaf(h0, w2[5], fmaf(h1, w2[6], c2_1));
        const float a1b = fmaf(h2, w2[7], h3 * w2[8]);
        a1 = fmaf(h4, w2[9], a1 + a1b);
        sv0 = fmaf(u.x, sigm_fast(a0), sv0) + nz.x;
        sv1 = fmaf(u.y, sigm_fast(a1), sv1) + nz.y;
        if (t < 256) ((float2*)(out + O_ST_OBS))[t * 256 + b] = make_float2(sv0, sv1);
        else         ((float2*)(out + O_ST_PRED))[(t - 256) * 256 + b] = make_float2(sv0, sv1);
    };

    float2 cu[8], cn[8];
#pragma unroll
    for (int j = 0; j < 8; j++) LD(1 + j, cu[j], cn[j]);

#pragma unroll 1
    for (int base = 1; base < 288; base += 8) {
        float2 nu[8], nn[8];
#pragma unroll
        for (int j = 0; j < 8; j++) LD(base + 8 + j, nu[j], nn[j]);
#pragma unroll
        for (int j = 0; j < 8; j++) {
            if (base + j < 288) STEP(cu[j], cn[j], base + j);
        }
#pragma unroll
        for (int j = 0; j < 8; j++) { cu[j] = nu[j]; cn[j] = nn[j]; }
    }
}

// ==================== Kernel 0 (fallback path only): U[t][b][2] = act^T . Wa ====================
extern "C" __global__ void __launch_bounds__(288)
k_pre(const float* __restrict__ act, const float* __restrict__ Wa, float* __restrict__ ws_u)
{
    const int b = blockIdx.x;
    const int t = threadIdx.x;
    float u0 = 0.f, u1 = 0.f;
#pragma unroll
    for (int a = 0; a < 5; a++) {
        const float av = act[(b * 5 + a) * 288 + t];
        u0 = fmaf(av, Wa[a], u0);
        u1 = fmaf(av, Wa[5 + a], u1);
    }
    ws_u[(t * 256 + b) * 2 + 0] = u0;
    ws_u[(t * 256 + b) * 2 + 1] = u1;
}

// ==================== Kernel 1a (fast path): U-precompute (blocks 0-255) + conv1+maxpool ====================
// grid 1536: blocks 0-255 = k_pre work (b = bid); blocks 256-1535: b = (bid-256)/5, chunk c = (bid-256)%5
extern "C" __global__ void __launch_bounds__(256)
k_patch(const float* __restrict__ x, const float* __restrict__ act,
        const int* __restrict__ pos, const float* __restrict__ Wa,
        const float* __restrict__ Wc1, const float* __restrict__ bc1,
        float* __restrict__ ws_u, float* __restrict__ ws_pool)
{
    const int tid = threadIdx.x;
    if (blockIdx.x < 256) {
        const int b = blockIdx.x;
        const float wa0 = Wa[0], wa1 = Wa[1], wa2 = Wa[2], wa3 = Wa[3], wa4 = Wa[4];
        const float wa5 = Wa[5], wa6 = Wa[6], wa7 = Wa[7], wa8 = Wa[8], wa9 = Wa[9];
#pragma unroll 1
        for (int t = tid; t < 288; t += 256) {
            float u0 = 0.f, u1 = 0.f;
            const float a0 = act[(b * 5 + 0) * 288 + t];
            const float a1 = act[(b * 5 + 1) * 288 + t];
            const float a2 = act[(b * 5 + 2) * 288 + t];
            const float a3 = act[(b * 5 + 3) * 288 + t];
            const float a4 = act[(b * 5 + 4) * 288 + t];
            u0 = fmaf(a4, wa4, fmaf(a3, wa3, fmaf(a2, wa2, fmaf(a1, wa1, a0 * wa0))));
            u1 = fmaf(a4, wa9, fmaf(a3, wa8, fmaf(a2, wa7, fmaf(a1, wa6, a0 * wa5))));
            ws_u[(t * 256 + b) * 2 + 0] = u0;
            ws_u[(t * 256 + b) * 2 + 1] = u1;
        }
        return;
    }
    const int bid = blockIdx.x - 256;
    const int b = bid / 5, c = bid % 5;

    __shared__ __align__(16) float sImg[3 * 1056];
    __shared__ float sWc1[192];
    __shared__ float sB1[16];

    for (int i = tid; i < 3072; i += 256) {
        const int ic = i >> 10, r = (i >> 5) & 31, cc = i & 31;
        sImg[ic * 1056 + r * 33 + cc] = x[b * 3072 + i];
    }
    if (tid < 192) sWc1[tid] = Wc1[tid];
    if (tid < 16) sB1[tid] = bc1[tid];
    __syncthreads();

    const int t = c * 64 + (tid >> 2);
    if (t >= 288) return;
    const int posq = tid & 3;
    const int py = posq >> 1, px = posq & 1;

    const int pr = 3 * pos[(b * 2 + 0) * 288 + t];
    const int pc = 3 * pos[(b * 2 + 1) * 288 + t];

    float p16[16];
#pragma unroll
    for (int i = 0; i < 16; i++) p16[i] = 0.f;

#pragma unroll 2
    for (int d = 0; d < 4; d++) {
        const int rbase = pr + 4 * py + 2 * (d >> 1);
        const int cbase = pc + 4 * px + 2 * (d & 1);
        float in[12];
#pragma unroll
        for (int ic = 0; ic < 3; ic++)
#pragma unroll
        for (int ky = 0; ky < 2; ky++)
#pragma unroll
        for (int kx = 0; kx < 2; kx++)
            in[ic * 4 + ky * 2 + kx] = sImg[ic * 1056 + (rbase + ky) * 33 + (cbase + kx)];
#pragma unroll
        for (int oc = 0; oc < 16; oc++) {
            const float4 wq0 = *(const float4*)&sWc1[oc * 12 + 0];
            const float4 wq1 = *(const float4*)&sWc1[oc * 12 + 4];
            const float4 wq2 = *(const float4*)&sWc1[oc * 12 + 8];
            float v = sB1[oc];
            v = FMA4(in[0], in[1], in[2], in[3], wq0, v);
            v = FMA4(in[4], in[5], in[6], in[7], wq1, v);
            v = FMA4(in[8], in[9], in[10], in[11], wq2, v);
            p16[oc] = fmaxf(p16[oc], fmaxf(v, 0.f));
        }
    }

    float4* dst = (float4*)(ws_pool + (((size_t)b * 288 + t) * 4 + posq) * 16);
    dst[0] = make_float4(p16[0], p16[1], p16[2], p16[3]);
    dst[1] = make_float4(p16[4], p16[5], p16[6], p16[7]);
    dst[2] = make_float4(p16[8], p16[9], p16[10], p16[11]);
    dst[3] = make_float4(p16[12], p16[13], p16[14], p16[15]);
}

// ==================== Kernel 1b (fast path): recurrence (block 0) + BN1 + conv2 + BN2 + heads ====================
// grid 289: block 0 = recurrence (hidden under 288 encoder blocks); block 1+i = timestep i.
extern "C" __global__ void __launch_bounds__(256)
k_enc(const float* __restrict__ s0,   const float* __restrict__ nobs,
      const float* __restrict__ npred,
      const float* __restrict__ Ws1,  const float* __restrict__ bs1,
      const float* __restrict__ Ws2,  const float* __restrict__ bs2,
      const float* __restrict__ g1,   const float* __restrict__ be1,
      const float* __restrict__ Wc2,  const float* __restrict__ bc2,
      const float* __restrict__ g2,   const float* __restrict__ be2,
      const float* __restrict__ Wzm,  const float* __restrict__ bzm,
      const float* __restrict__ Wzs,  const float* __restrict__ bzs,
      const float* __restrict__ ws_u, const float* __restrict__ ws_pool,
      float* __restrict__ out)
{
    const int tid = threadIdx.x;
    if (blockIdx.x == 0) {
        run_recurrence(tid, s0, nobs, npred, Ws1, bs1, Ws2, bs2, ws_u, out);
        return;
    }
    const int t = blockIdx.x - 1, b = tid;
    const int wid = tid >> 6, lane = tid & 63;

    __shared__ __align__(16) float pooledL[256 * 68];
    __shared__ __align__(16) float sWc2r[2048];
    __shared__ __align__(16) float sM1[16], sS1[16], sE1[16];
    __shared__ float sB2[32], sE2[32];
    __shared__ float sM2[32], sS2[32];
    __shared__ float sRed[4][64];

    for (int i = tid; i < 2048; i += 256) {
        const int oc = i >> 6, rem = i & 63, ic = rem >> 2, q = rem & 3;
        sWc2r[oc * 64 + q * 16 + ic] = Wc2[i];
    }
    if (tid < 16) { sE1[tid] = be1[tid]; }
    if (tid < 32) { sB2[tid] = bc2[tid]; sE2[tid] = be2[tid]; }

    float* myrow = &pooledL[b * 68];
    {
        const float4* src = (const float4*)(ws_pool + ((size_t)b * 288 + t) * 64);
#pragma unroll
        for (int q = 0; q < 16; q++) *(float4*)&myrow[4 * q] = src[q];
    }
    __syncthreads();

    {
        const int col = tid & 63, q = tid >> 6;
        float s = 0.f, ss = 0.f;
        const float* cp = &pooledL[(q * 64) * 68 + col];
#pragma unroll 4
        for (int i = 0; i < 64; i++) { const float v = cp[i * 68]; s += v; ss = fmaf(v, v, ss); }
        sRed[q][col] = s;
        __syncthreads();
        float ssum = 0.f;
        if (tid < 16) {
#pragma unroll
            for (int p = 0; p < 4; p++)
#pragma unroll
            for (int qq = 0; qq < 4; qq++) ssum += sRed[qq][p * 16 + tid];
        }
        __syncthreads();
        sRed[q][col] = ss;
        __syncthreads();
        if (tid < 16) {
            float sssum = 0.f;
#pragma unroll
            for (int p = 0; p < 4; p++)
#pragma unroll
            for (int qq = 0; qq < 4; qq++) sssum += sRed[qq][p * 16 + tid];
            const float m = ssum * (1.f / 1024.f);
            const float var = fmaf(-m, m, sssum * (1.f / 1024.f));
            sM1[tid] = m; sS1[tid] = g1[tid] * rsqrtf(var + 1e-5f);
        }
    }
    __syncthreads();

#pragma unroll 4
    for (int tq = 0; tq < 16; tq++) {
        const int ic0 = (tq & 3) * 4;
        float4 v = *(float4*)&myrow[4 * tq];
        const float4 mq = *(const float4*)&sM1[ic0];
        const float4 sq = *(const float4*)&sS1[ic0];
        const float4 eq = *(const float4*)&sE1[ic0];
        v.x = fmaf(v.x - mq.x, sq.x, eq.x);
        v.y = fmaf(v.y - mq.y, sq.y, eq.y);
        v.z = fmaf(v.z - mq.z, sq.z, eq.z);
        v.w = fmaf(v.w - mq.w, sq.w, eq.w);
        *(float4*)&myrow[4 * tq] = v;
    }

    float h2v[32];
#pragma unroll
    for (int og = 0; og < 4; og++) {
        float acc[8];
#pragma unroll
        for (int jj = 0; jj < 8; jj++) acc[jj] = sB2[og * 8 + jj];
#pragma unroll 2
        for (int tq = 0; tq < 16; tq++) {
            const float4 hq = *(const float4*)&myrow[4 * tq];
#pragma unroll
            for (int jj = 0; jj < 8; jj++) {
                const float4 wv = *(const float4*)&sWc2r[(og * 8 + jj) * 64 + 4 * tq];
                acc[jj] = FMA4(hq.x, hq.y, hq.z, hq.w, wv, acc[jj]);
            }
        }
#pragma unroll
        for (int jj = 0; jj < 8; jj++) h2v[og * 8 + jj] = fmaxf(acc[jj], 0.f);
    }

#pragma unroll
    for (int oc = 0; oc < 32; oc++) {
        float s = wred(h2v[oc]), ss = wred(h2v[oc] * h2v[oc]);
        if (lane == 0) { sRed[wid][2 * oc] = s; sRed[wid][2 * oc + 1] = ss; }
    }
    __syncthreads();
    if (tid < 32) {
        const float s  = sRed[0][2 * tid] + sRed[1][2 * tid] + sRed[2][2 * tid] + sRed[3][2 * tid];
        const float ss = sRed[0][2 * tid + 1] + sRed[1][2 * tid + 1] + sRed[2][2 * tid + 1] + sRed[3][2 * tid + 1];
        const float m = s * (1.f / 256.f);
        const float var = fmaf(-m, m, ss * (1.f / 256.f));
        sM2[tid] = m; sS2[tid] = g2[tid] * rsqrtf(var + 1e-5f);
    }
    __syncthreads();
#pragma unroll
    for (int oc = 0; oc < 32; oc++) h2v[oc] = fmaf(h2v[oc] - sM2[oc], sS2[oc], sE2[oc]);

    // zm/zs heads: weights read wave-uniform from global (scalar-load broadcast)
    const int obase_m = (t < 256) ? (O_ZM_OBS + (t * 256 + b) * 16) : (O_ZM_PRED + ((t - 256) * 256 + b) * 16);
    const int obase_s = (t < 256) ? (O_ZS_OBS + (t * 256 + b) * 16) : (O_ZS_PRED + ((t - 256) * 256 + b) * 16);
#pragma unroll 2
    for (int k = 0; k < 16; k++) {
        float vm = bzm[k], vs = bzs[k];
#pragma unroll
        for (int c = 0; c < 32; c += 4) {
            const float4 wm = *(const float4*)&Wzm[k * 32 + c];
            const float4 wsq = *(const float4*)&Wzs[k * 32 + c];
            vm = FMA4(h2v[c], h2v[c + 1], h2v[c + 2], h2v[c + 3], wm, vm);
            vs = FMA4(h2v[c], h2v[c + 1], h2v[c + 2], h2v[c + 3], wsq, vs);
        }
        out[obase_m + k] = vm;
        out[obase_s + k] = __expf(vs);
    }
}

// ==================== Kernel 1 (fallback): fused encoder with global gathers ====================
extern "C" __global__ void __launch_bounds__(256)
k_enc_full(const float* __restrict__ x,
           const int*   __restrict__ pos,  const float* __restrict__ s0,
           const float* __restrict__ nobs, const float* __restrict__ npred,
           const float* __restrict__ Ws1,  const float* __restrict__ bs1,
           const float* __restrict__ Ws2,  const float* __restrict__ bs2,
           const float* __restrict__ Wc1,  const float* __restrict__ bc1,
           const float* __restrict__ g1,   const float* __restrict__ be1,
           const float* __restrict__ Wc2,  const float* __restrict__ bc2,
           const float* __restrict__ g2,   const float* __restrict__ be2,
           const float* __restrict__ Wzm,  const float* __restrict__ bzm,
           const float* __restrict__ Wzs,  const float* __restrict__ bzs,
           const float* __restrict__ ws_u, float* __restrict__ out)
{
    const int tid = threadIdx.x;
    if (blockIdx.x == 0) {
        run_recurrence(tid, s0, nobs, npred, Ws1, bs1, Ws2, bs2, ws_u, out);
        return;
    }
    const int t = blockIdx.x - 1;
    __shared__ __align__(16) float sWc1[192];
    __shared__ __align__(16) float sWc2r[2048];
    __shared__ __align__(16) float sM1[16], sS1[16], sE1[16];
    __shared__ float sB1[16], sB2[32], sE2[32];
    __shared__ float sM2[32], sS2[32];
    __shared__ float sRed[4][64];
    __shared__ __align__(16) float pooledL[256 * 68];

    for (int i = tid; i < 192; i += 256) sWc1[i] = Wc1[i];
    for (int i = tid; i < 2048; i += 256) {
        const int oc = i >> 6, rem = i & 63, ic = rem >> 2, q = rem & 3;
        sWc2r[oc * 64 + q * 16 + ic] = Wc2[i];
    }
    if (tid < 16) { sB1[tid] = bc1[tid]; sE1[tid] = be1[tid]; }
    if (tid < 32) { sB2[tid] = bc2[tid]; sE2[tid] = be2[tid]; }
    __syncthreads();

    const int b = tid;
    const int wid = tid >> 6, lane = tid & 63;
    const float* xb = x + b * 3072;
    const int pr = 3 * pos[(b * 2 + 0) * 288 + t];
    const int pc = 3 * pos[(b * 2 + 1) * 288 + t];
    float* myrow = &pooledL[b * 68];

#pragma unroll
    for (int py = 0; py < 2; py++)
#pragma unroll
    for (int px = 0; px < 2; px++) {
        float p16[16];
#pragma unroll
        for (int i = 0; i < 16; i++) p16[i] = 0.f;
#pragma unroll 2
        for (int d = 0; d < 4; d++) {
            const int rbase = pr + 4 * py + 2 * (d >> 1);
            const int cbase = pc + 4 * px + 2 * (d & 1);
            float in[12];
#pragma unroll
            for (int ic = 0; ic < 3; ic++)
#pragma unroll
            for (int ky = 0; ky < 2; ky++)
#pragma unroll
            for (int kx = 0; kx < 2; kx++)
                in[ic * 4 + ky * 2 + kx] = xb[ic * 1024 + (rbase + ky) * 32 + (cbase + kx)];
#pragma unroll
            for (int oc = 0; oc < 16; oc++) {
                const float4 wq0 = *(const float4*)&sWc1[oc * 12 + 0];
                const float4 wq1 = *(const float4*)&sWc1[oc * 12 + 4];
                const float4 wq2 = *(const float4*)&sWc1[oc * 12 + 8];
                float v = sB1[oc];
                v = FMA4(in[0], in[1], in[2], in[3], wq0, v);
                v = FMA4(in[4], in[5], in[6], in[7], wq1, v);
                v = FMA4(in[8], in[9], in[10], in[11], wq2, v);
                p16[oc] = fmaxf(p16[oc], fmaxf(v, 0.f));
            }
        }
        const int pbase = (py * 2 + px) * 16;
        *(float4*)&myrow[pbase + 0]  = make_float4(p16[0], p16[1], p16[2], p16[3]);
        *(float4*)&myrow[pbase + 4]  = make_float4(p16[4], p16[5], p16[6], p16[7]);
        *(float4*)&myrow[pbase + 8]  = make_float4(p16[8], p16[9], p16[10], p16[11]);
        *(float4*)&myrow[pbase + 12] = make_float4(p16[12], p16[13], p16[14], p16[15]);
    }
    __syncthreads();

    {
        const int col = tid & 63, q = tid >> 6;
        float s = 0.f, ss = 0.f;
        const float* cp = &pooledL[(q * 64) * 68 + col];
#pragma unroll 4
        for (int i = 0; i < 64; i++) { const float v = cp[i * 68]; s += v; ss = fmaf(v, v, ss); }
        sRed[q][col] = s;
        __syncthreads();
        float ssum = 0.f;
        if (tid < 16) {
#pragma unroll
            for (int p = 0; p < 4; p++)
#pragma unroll
            for (int qq = 0; qq < 4; qq++) ssum += sRed[qq][p * 16 + tid];
        }
        __syncthreads();
        sRed[q][col] = ss;
        __syncthreads();
        if (tid < 16) {
            float sssum = 0.f;
#pragma unroll
            for (int p = 0; p < 4; p++)
#pragma unroll
            for (int qq = 0; qq < 4; qq++) sssum += sRed[qq][p * 16 + tid];
            const float m = ssum * (1.f / 1024.f);
            const float var = fmaf(-m, m, sssum * (1.f / 1024.f));
            sM1[tid] = m; sS1[tid] = g1[tid] * rsqrtf(var + 1e-5f);
        }
    }
    __syncthreads();

#pragma unroll 4
    for (int tq = 0; tq < 16; tq++) {
        const int ic0 = (tq & 3) * 4;
        float4 v = *(float4*)&myrow[4 * tq];
        const float4 mq = *(const float4*)&sM1[ic0];
        const float4 sq = *(const float4*)&sS1[ic0];
        const float4 eq = *(const float4*)&sE1[ic0];
        v.x = fmaf(v.x - mq.x, sq.x, eq.x);
        v.y = fmaf(v.y - mq.y, sq.y, eq.y);
        v.z = fmaf(v.z - mq.z, sq.z, eq.z);
        v.w = fmaf(v.w - mq.w, sq.w, eq.w);
        *(float4*)&myrow[4 * tq] = v;
    }

    float h2v[32];
#pragma unroll
    for (int og = 0; og < 4; og++) {
        float acc[8];
#pragma unroll
        for (int jj = 0; jj < 8; jj++) acc[jj] = sB2[og * 8 + jj];
#pragma unroll 2
        for (int tq = 0; tq < 16; tq++) {
            const float4 hq = *(const float4*)&myrow[4 * tq];
#pragma unroll
            for (int jj = 0; jj < 8; jj++) {
                const float4 wv = *(const float4*)&sWc2r[(og * 8 + jj) * 64 + 4 * tq];
                acc[jj] = FMA4(hq.x, hq.y, hq.z, hq.w, wv, acc[jj]);
            }
        }
#pragma unroll
        for (int jj = 0; jj < 8; jj++) h2v[og * 8 + jj] = fmaxf(acc[jj], 0.f);
    }

#pragma unroll
    for (int oc = 0; oc < 32; oc++) {
        float s = wred(h2v[oc]), ss = wred(h2v[oc] * h2v[oc]);
        if (lane == 0) { sRed[wid][2 * oc] = s; sRed[wid][2 * oc + 1] = ss; }
    }
    __syncthreads();
    if (tid < 32) {
        const float s  = sRed[0][2 * tid] + sRed[1][2 * tid] + sRed[2][2 * tid] + sRed[3][2 * tid];
        const float ss = sRed[0][2 * tid + 1] + sRed[1][2 * tid + 1] + sRed[2][2 * tid + 1] + sRed[3][2 * tid + 1];
        const float m = s * (1.f / 256.f);
        const float var = fmaf(-m, m, ss * (1.f / 256.f));
        sM2[tid] = m; sS2[tid] = g2[tid] * rsqrtf(var + 1e-5f);
    }
    __syncthreads();
#pragma unroll
    for (int oc = 0; oc < 32; oc++) h2v[oc] = fmaf(h2v[oc] - sM2[oc], sS2[oc], sE2[oc]);

    const int obase_m = (t < 256) ? (O_ZM_OBS + (t * 256 + b) * 16) : (O_ZM_PRED + ((t - 256) * 256 + b) * 16);
    const int obase_s = (t < 256) ? (O_ZS_OBS + (t * 256 + b) * 16) : (O_ZS_PRED + ((t - 256) * 256 + b) * 16);
#pragma unroll 2
    for (int k = 0; k < 16; k++) {
        float vm = bzm[k], vs = bzs[k];
#pragma unroll
        for (int c = 0; c < 32; c += 4) {
            const float4 wm = *(const float4*)&Wzm[k * 32 + c];
            const float4 wsq = *(const float4*)&Wzs[k * 32 + c];
            vm = FMA4(h2v[c], h2v[c + 1], h2v[c + 2], h2v[c + 3], wm, vm);
            vs = FMA4(h2v[c], h2v[c + 1], h2v[c + 2], h2v[c + 3], wsq, vs);
        }
        out[obase_m + k] = vm;
        out[obase_s + k] = __expf(vs);
    }
}

// ==================== Kernel 2: 512-thread loop-based decoder front half ====================
extern "C" __global__ void __launch_bounds__(512)
k_dec1(const float* __restrict__ eps,
       const float* __restrict__ Wd1,  const float* __restrict__ bd1,
       const float* __restrict__ gd1,  const float* __restrict__ bed1,
       const float* __restrict__ Wd2,  const float* __restrict__ bd2,
       const float* __restrict__ gd2,  const float* __restrict__ bed2,
       const float* __restrict__ Wt1,  const float* __restrict__ bt1,
       const float* __restrict__ out,
       float* __restrict__ ws_h2n, float* __restrict__ ws_p3)
{
    const int tp = blockIdx.x >> 2, g = blockIdx.x & 3;
    const int tid = threadIdx.x;
    const int b = tid & 255, half = tid >> 8;
    const int wid = tid >> 6, lane = tid & 63;

    __shared__ __align__(16) float sWd1[1024];
    __shared__ __align__(16) float sWd2g[2048];
    __shared__ __align__(16) float sWt1g[2048];
    __shared__ float h1L[256 * 65];
    __shared__ float h2L[256 * 33];
    __shared__ float sRed[8][128];
    __shared__ float sAcc[8][32];
    __shared__ float sM1[64], sS1[64], sE1[64];
    __shared__ float sM2[32], sS2[32], sE2[32];
    __shared__ float sBd1[64], sBd2g[32], sBt1[16];
    float* sRedF = &sRed[0][0];

    for (int i = tid; i < 1024; i += 512) sWd1[i] = Wd1[i];
    for (int i = tid; i < 2048; i += 512) {
        const int ic = i >> 6, k = i & 63;
        sWd2g[i] = Wd2[(4 * ic + g) * 64 + k];
    }
    for (int i = tid; i < 2048; i += 512) {
        const int dp = i >> 9, rem = i & 511, oc = rem >> 5, ic = i & 31;
        const int py = (g >> 1) * 2 + (dp >> 1), px = (g & 1) * 2 + (dp & 1);
        const int k9 = ((py + 1) % 3) * 3 + ((px + 1) % 3);
        sWt1g[(dp * 16 + oc) * 32 + ic] = Wt1[ic * 144 + oc * 9 + k9];
    }
    if (tid < 64) sBd1[tid] = bd1[tid];
    if (tid < 32) sBd2g[tid] = bd2[4 * tid + g];
    if (tid < 16) sBt1[tid] = bt1[tid];
    if (tid < 256) ((float*)sAcc)[tid] = 0.f;
    __syncthreads();

    float4 zA, zB, zC, zD;
    {
        const int base = (tp * 256 + b) * 16;
        const float4 e0 = *(const float4*)&eps[base + 0],  e1 = *(const float4*)&eps[base + 4];
        const float4 e2 = *(const float4*)&eps[base + 8],  e3 = *(const float4*)&eps[base + 12];
        const float4 s0v = *(const float4*)&out[O_ZS_PRED + base + 0],  s1v = *(const float4*)&out[O_ZS_PRED + base + 4];
        const float4 s2v = *(const float4*)&out[O_ZS_PRED + base + 8],  s3v = *(const float4*)&out[O_ZS_PRED + base + 12];
        const float4 m0 = *(const float4*)&out[O_ZM_PRED + base + 0],  m1 = *(const float4*)&out[O_ZM_PRED + base + 4];
        const float4 m2 = *(const float4*)&out[O_ZM_PRED + base + 8],  m3 = *(const float4*)&out[O_ZM_PRED + base + 12];
        zA = make_float4(fmaf(e0.x,s0v.x,m0.x), fmaf(e0.y,s0v.y,m0.y), fmaf(e0.z,s0v.z,m0.z), fmaf(e0.w,s0v.w,m0.w));
        zB = make_float4(fmaf(e1.x,s1v.x,m1.x), fmaf(e1.y,s1v.y,m1.y), fmaf(e1.z,s1v.z,m1.z), fmaf(e1.w,s1v.w,m1.w));
        zC = make_float4(fmaf(e2.x,s2v.x,m2.x), fmaf(e2.y,s2v.y,m2.y), fmaf(e2.z,s2v.z,m2.z), fmaf(e2.w,s2v.w,m2.w));
        zD = make_float4(fmaf(e3.x,s3v.x,m3.x), fmaf(e3.y,s3v.y,m3.y), fmaf(e3.z,s3v.z,m3.z), fmaf(e3.w,s3v.w,m3.w));
    }

#pragma unroll 4
    for (int jj = 0; jj < 32; ++jj) {
        const int j = half * 32 + jj;
        const float4 wq0 = *(const float4*)&sWd1[j * 16 + 0];
        const float4 wq1 = *(const float4*)&sWd1[j * 16 + 4];
        const float4 wq2 = *(const float4*)&sWd1[j * 16 + 8];
        const float4 wq3 = *(const float4*)&sWd1[j * 16 + 12];
        float v = sBd1[j];
        v = FMA4(zA.x, zA.y, zA.z, zA.w, wq0, v);
        v = FMA4(zB.x, zB.y, zB.z, zB.w, wq1, v);
        v = FMA4(zC.x, zC.y, zC.z, zC.w, wq2, v);
        v = FMA4(zD.x, zD.y, zD.z, zD.w, wq3, v);
        h1L[b * 65 + j] = fmaxf(v, 0.f);
    }
    __syncthreads();

    {
        const int col = tid & 63, q = tid >> 6;
        float s = 0.f, ss = 0.f;
        const float* cp = &h1L[(q * 32) * 65 + col];
#pragma unroll 4
        for (int i = 0; i < 32; i++) { const float v = cp[i * 65]; s += v; ss = fmaf(v, v, ss); }
        sRed[q][2 * col] = s; sRed[q][2 * col + 1] = ss;
    }
    __syncthreads();
    if (tid < 64) {
        float s = 0.f, ss = 0.f;
#pragma unroll
        for (int q = 0; q < 8; q++) { s += sRed[q][2 * tid]; ss += sRed[q][2 * tid + 1]; }
        const float m = s * (1.f / 256.f);
        const float var = fmaf(-m, m, ss * (1.f / 256.f));
        sM1[tid] = m; sS1[tid] = gd1[tid] * rsqrtf(var + 1e-5f); sE1[tid] = bed1[tid];
    }
    __syncthreads();

#pragma unroll 4
    for (int jj = 0; jj < 32; ++jj) {
        const int j = half * 32 + jj;
        h1L[b * 65 + j] = fmaf(h1L[b * 65 + j] - sM1[j], sS1[j], sE1[j]);
    }
    __syncthreads();

    float hr[64];
#pragma unroll
    for (int k = 0; k < 64; ++k) hr[k] = h1L[b * 65 + k];

#pragma unroll 1
    for (int ic = 0; ic < 16; ++ic) {
        const int icg = half * 16 + ic;
        float v = sBd2g[icg];
#pragma unroll
        for (int k4 = 0; k4 < 16; ++k4) {
            const float4 wv = *(const float4*)&sWd2g[icg * 64 + 4 * k4];
            v = FMA4(hr[4*k4], hr[4*k4+1], hr[4*k4+2], hr[4*k4+3], wv, v);
        }
        h2L[b * 33 + icg] = fmaxf(v, 0.f);
    }
    __syncthreads();

    {
        const int col = tid & 31, q = tid >> 5;
        float s = 0.f, ss = 0.f;
        const float* cp = &h2L[(q * 16) * 33 + col];
#pragma unroll 4
        for (int i = 0; i < 16; i++) { const float v = cp[i * 33]; s += v; ss = fmaf(v, v, ss); }
        sRedF[q * 32 + col] = s;
        __syncthreads();
        float ssum = 0.f;
        if (tid < 32) {
#pragma unroll
            for (int qq = 0; qq < 16; qq++) ssum += sRedF[qq * 32 + tid];
        }
        __syncthreads();
        sRedF[q * 32 + col] = ss;
        __syncthreads();
        if (tid < 32) {
            float sssum = 0.f;
#pragma unroll
            for (int qq = 0; qq < 16; qq++) sssum += sRedF[qq * 32 + tid];
            const float m = ssum * (1.f / 256.f);
            const float var = fmaf(-m, m, sssum * (1.f / 256.f));
            sM2[tid] = m;
            sS2[tid] = gd2[4 * tid + g] * rsqrtf(var + 1e-5f);
            sE2[tid] = bed2[4 * tid + g];
        }
    }
    __syncthreads();

#pragma unroll 4
    for (int ic = 0; ic < 16; ++ic) {
        const int icg = half * 16 + ic;
        h2L[b * 33 + icg] = fmaf(h2L[b * 33 + icg] - sM2[icg], sS2[icg], sE2[icg]);
    }
    __syncthreads();

    float h2r[32];
#pragma unroll
    for (int k = 0; k < 32; ++k) h2r[k] = h2L[b * 33 + k];
    {
        float* dst = ws_h2n + (((size_t)(tp * 4 + g) * 256 + b) * 32 + half * 16);
        const int o = half * 16;
        *(float4*)&dst[0]  = make_float4(h2r[o+0],  h2r[o+1],  h2r[o+2],  h2r[o+3]);
        *(float4*)&dst[4]  = make_float4(h2r[o+4],  h2r[o+5],  h2r[o+6],  h2r[o+7]);
        *(float4*)&dst[8]  = make_float4(h2r[o+8],  h2r[o+9],  h2r[o+10], h2r[o+11]);
        *(float4*)&dst[12] = make_float4(h2r[o+12], h2r[o+13], h2r[o+14], h2r[o+15]);
    }

#pragma unroll 1
    for (int d2 = 0; d2 < 2; ++d2) {
        const int dp = half * 2 + d2;
#pragma unroll 1
        for (int oc = 0; oc < 16; ++oc) {
            float v = sBt1[oc];
            const float* wrow = &sWt1g[(dp * 16 + oc) * 32];
#pragma unroll
            for (int i4 = 0; i4 < 8; ++i4) {
                const float4 wv = *(const float4*)&wrow[4 * i4];
                v = FMA4(h2r[4*i4], h2r[4*i4+1], h2r[4*i4+2], h2r[4*i4+3], wv, v);
            }
            v = fmaxf(v, 0.f);
            const float s = wred(v), ss = wred(v * v);
            if (lane == 0) { sAcc[wid][2 * oc] += s; sAcc[wid][2 * oc + 1] += ss; }
        }
    }
    __syncthreads();
    if (tid < 16) {
        float s = 0.f, ss = 0.f;
#pragma unroll
        for (int w = 0; w < 8; w++) { s += sAcc[w][2 * tid]; ss += sAcc[w][2 * tid + 1]; }
        ws_p3[(tp * 4 + g) * 32 + 2 * tid + 0] = s;
        ws_p3[(tp * 4 + g) * 32 + 2 * tid + 1] = ss;
    }
}

// ==================== Kernel 3: BN3 finalize + convT1 recompute + convT2 + nll ====================
// grid 256: bid -> tp = bid>>3, g = (bid>>1)&3, hf = bid&1
extern "C" __global__ void __launch_bounds__(256)
k_dec2(const float* __restrict__ x,    const int* __restrict__ pos,
       const float* __restrict__ Wt1,  const float* __restrict__ bt1,
       const float* __restrict__ gt1,  const float* __restrict__ bet1,
       const float* __restrict__ Wt2,  const float* __restrict__ bt2,
       float* __restrict__ out,
       const float* __restrict__ ws_h2n, const float* __restrict__ ws_p3)
{
    const int tp = blockIdx.x >> 3, g = (blockIdx.x >> 1) & 3, hf = blockIdx.x & 1;
    const int tid = threadIdx.x, b = tid;
    const int wid = tid >> 6, lane = tid & 63;

    __shared__ __align__(16) float sWt1g[1024];
    __shared__ __align__(16) float sWt2[192];
    __shared__ float sBt1[16], sBt2[3];
    __shared__ float sRed[4][64];
    __shared__ float sM3[16], sS3[16], sE3[16];

    for (int i = tid; i < 1024; i += 256) {
        const int d2 = i >> 9, rem = i & 511, oc = rem >> 5, ic = i & 31;
        const int dp = hf * 2 + d2;
        const int py = (g >> 1) * 2 + (dp >> 1), px = (g & 1) * 2 + (dp & 1);
        const int k9 = ((py + 1) % 3) * 3 + ((px + 1) % 3);
        sWt1g[(d2 * 16 + oc) * 32 + ic] = Wt1[ic * 144 + oc * 9 + k9];
    }
    if (tid < 192) { const int ic = tid / 12, r = tid % 12; sWt2[r * 16 + ic] = Wt2[tid]; }
    if (tid < 16) sBt1[tid] = bt1[tid];
    if (tid < 3) sBt2[tid] = bt2[tid];
    if (tid < 16) {
        float s = 0.f, ss = 0.f;
#pragma unroll
        for (int gg = 0; gg < 4; gg++) {
            s  += ws_p3[(tp * 4 + gg) * 32 + 2 * tid + 0];
            ss += ws_p3[(tp * 4 + gg) * 32 + 2 * tid + 1];
        }
        const float m = s * (1.f / 4096.f);
        const float var = fmaf(-m, m, ss * (1.f / 4096.f));
        sM3[tid] = m; sS3[tid] = gt1[tid] * rsqrtf(var + 1e-5f); sE3[tid] = bet1[tid];
    }
    __syncthreads();

    float h2g[32];
    {
        const float* src = ws_h2n + (((size_t)(tp * 4 + g) * 256 + b) * 32);
#pragma unroll
        for (int i4 = 0; i4 < 8; i4++) {
            const float4 v4 = *(const float4*)&src[4 * i4];
            h2g[4 * i4] = v4.x; h2g[4 * i4 + 1] = v4.y; h2g[4 * i4 + 2] = v4.z; h2g[4 * i4 + 3] = v4.w;
        }
    }

    const int t = 256 + tp;
    const int pr = 3 * pos[(b * 2 + 0) * 288 + t];
    const int pc = 3 * pos[(b * 2 + 1) * 288 + t];
    const float* xb = x + b * 3072;
    const int rbase = O_XREC + (tp * 256 + b) * 192;
    const int py0 = (g >> 1) * 2, px0 = (g & 1) * 2;
    float err = 0.f;

#pragma unroll 1
    for (int d2 = 0; d2 < 2; d2++) {
        const int dp = hf * 2 + d2;
        const int py = py0 + (dp >> 1), px = px0 + (dp & 1);
        float hn[16];
#pragma unroll
        for (int og = 0; og < 4; og++) {
            float acc[4];
#pragma unroll
            for (int jj = 0; jj < 4; jj++) acc[jj] = sBt1[og * 4 + jj];
#pragma unroll
            for (int i4 = 0; i4 < 8; i4++) {
#pragma unroll
                for (int jj = 0; jj < 4; jj++) {
                    const float4 wv = *(const float4*)&sWt1g[(d2 * 16 + og * 4 + jj) * 32 + 4 * i4];
                    acc[jj] = FMA4(h2g[4*i4], h2g[4*i4+1], h2g[4*i4+2], h2g[4*i4+3], wv, acc[jj]);
                }
            }
#pragma unroll
            for (int jj = 0; jj < 4; jj++) {
                const int oc = og * 4 + jj;
                hn[oc] = fmaf(fmaxf(acc[jj], 0.f) - sM3[oc], sS3[oc], sE3[oc]);
            }
        }
#pragma unroll
        for (int c = 0; c < 3; c++)
#pragma unroll
        for (int dy = 0; dy < 2; dy++)
#pragma unroll
        for (int dx = 0; dx < 2; dx++) {
            const float* wp = &sWt2[(c * 4 + dy * 2 + dx) * 16];
            float v = sBt2[c];
#pragma unroll
            for (int ic = 0; ic < 16; ic += 4) {
                const float4 wq = *(const float4*)&wp[ic];
                v = FMA4(hn[ic], hn[ic + 1], hn[ic + 2], hn[ic + 3], wq, v);
            }
            v = sigm(v);
            const int oy = 2 * py + dy, ox = 2 * px + dx;
            out[rbase + c * 64 + oy * 8 + ox] = v;
            const float d = v - xb[c * 1024 + (pr + oy) * 32 + (pc + ox)];
            err = fmaf(d, d, err);
        }
    }

    const float es = wred(err);
    if (lane == 0) sRed[wid][0] = es;
    __syncthreads();
    if (tid == 0)
        atomicAdd(&out[O_NLL], sRed[0][0] + sRed[1][0] + sRed[2][0] + sRed[3][0]);
}

// ==================== host ====================
extern "C" void kernel_launch(void* const* d_in, const int* in_sizes, int n_in,
                              void* d_out, int out_size, void* d_ws, size_t ws_size,
                              hipStream_t stream)
{
    const float* x    = (const float*)d_in[0];
    const float* act  = (const float*)d_in[1];
    const int*   pos  = (const int*)d_in[2];
    const float* s0   = (const float*)d_in[3];
    const float* nobs = (const float*)d_in[4];
    const float* nprd = (const float*)d_in[5];
    const float* eps  = (const float*)d_in[6];
    const float* Wa   = (const float*)d_in[7];
    const float* Ws1  = (const float*)d_in[8];
    const float* bs1  = (const float*)d_in[9];
    const float* Ws2  = (const float*)d_in[10];
    const float* bs2  = (const float*)d_in[11];
    const float* Wc1  = (const float*)d_in[12];
    const float* bc1  = (const float*)d_in[13];
    const float* g1   = (const float*)d_in[14];
    const float* be1  = (const float*)d_in[15];
    const float* Wc2  = (const float*)d_in[16];
    const float* bc2  = (const float*)d_in[17];
    const float* g2   = (const float*)d_in[18];
    const float* be2  = (const float*)d_in[19];
    const float* Wzm  = (const float*)d_in[20];
    const float* bzm  = (const float*)d_in[21];
    const float* Wzs  = (const float*)d_in[22];
    const float* bzs  = (const float*)d_in[23];
    const float* Wd1  = (const float*)d_in[24];
    const float* bd1  = (const float*)d_in[25];
    const float* gd1  = (const float*)d_in[26];
    const float* bed1 = (const float*)d_in[27];
    const float* Wd2  = (const float*)d_in[28];
    const float* bd2  = (const float*)d_in[29];
    const float* gd2  = (const float*)d_in[30];
    const float* bed2 = (const float*)d_in[31];
    const float* Wt1  = (const float*)d_in[32];
    const float* bt1  = (const float*)d_in[33];
    const float* gt1  = (const float*)d_in[34];
    const float* bet1 = (const float*)d_in[35];
    const float* Wt2  = (const float*)d_in[36];
    const float* bt2  = (const float*)d_in[37];
    float* out = (float*)d_out;
    float* ws  = (float*)d_ws;

    const size_t need_fast = (POOL_FLOATS + 147456) * sizeof(float);  // 19.46 MB

    if (ws_size >= need_fast) {
        float* ws_pool = ws;
        float* ws_u    = ws + POOL_FLOATS;
        float* ws_h2n  = ws;                 // reuses pool region after k_enc consumed it
        float* ws_p3   = ws + 1048576;

        k_patch<<<dim3(1536), dim3(256), 0, stream>>>(
            x, act, pos, Wa, Wc1, bc1, ws_u, ws_pool);
        k_enc<<<dim3(289), dim3(256), 0, stream>>>(
            s0, nobs, nprd, Ws1, bs1, Ws2, bs2,
            g1, be1, Wc2, bc2, g2, be2, Wzm, bzm, Wzs, bzs, ws_u, ws_pool, out);
        k_dec1<<<dim3(128), dim3(512), 0, stream>>>(
            eps, Wd1, bd1, gd1, bed1, Wd2, bd2, gd2, bed2, Wt1, bt1, out, ws_h2n, ws_p3);
        k_dec2<<<dim3(256), dim3(256), 0, stream>>>(
            x, pos, Wt1, bt1, gt1, bet1, Wt2, bt2, out, ws_h2n, ws_p3);
    } else {
        float* ws_u   = ws;
        float* ws_h2n = ws + 147456;
        float* ws_p3  = ws + 1196032;

        k_pre<<<dim3(256), dim3(288), 0, stream>>>(act, Wa, ws_u);
        k_enc_full<<<dim3(289), dim3(256), 0, stream>>>(
            x, pos, s0, nobs, nprd, Ws1, bs1, Ws2, bs2,
            Wc1, bc1, g1, be1, Wc2, bc2, g2, be2, Wzm, bzm, Wzs, bzs, ws_u, out);
        k_dec1<<<dim3(128), dim3(512), 0, stream>>>(
            eps, Wd1, bd1, gd1, bed1, Wd2, bd2, gd2, bed2, Wt1, bt1, out, ws_h2n, ws_p3);
        k_dec2<<<dim3(256), dim3(256), 0, stream>>>(
            x, pos, Wt1, bt1, gt1, bet1, Wt2, bt2, out, ws_h2n, ws_p3);
    }
}

// Round 13
// 161.053 us; speedup vs baseline: 3.0910x; 1.0653x over previous
//
#include <hip/hip_runtime.h>
#include <hip/hip_bf16.h>
#include <math.h>

// ---------------- problem constants ----------------
#define NB   256
#define NT   288
#define NOBS 256
#define NTP  32

// output offsets (floats)
#define O_ST_OBS   0
#define O_ST_PRED  131072
#define O_ZM_OBS   147456
#define O_ZS_OBS   1196032
#define O_ZM_PRED  2244608
#define O_ZS_PRED  2375680
#define O_XREC     2506752
#define O_NLL      4079616

#define POOL_FLOATS ((size_t)288 * 256 * 64)   // 4,718,592 floats = 18.9 MB

__device__ __forceinline__ float wred(float v) {
    v += __shfl_down(v, 32); v += __shfl_down(v, 16); v += __shfl_down(v, 8);
    v += __shfl_down(v, 4);  v += __shfl_down(v, 2);  v += __shfl_down(v, 1);
    return v;
}
__device__ __forceinline__ float sigm(float x) { return 1.0f / (1.0f + __expf(-x)); }

// fast reciprocal (v_rcp_f32, ~1 ulp) with safe fallback
__device__ __forceinline__ float frcp(float x) {
#if __has_builtin(__builtin_amdgcn_rcpf)
    return __builtin_amdgcn_rcpf(x);
#else
    return 1.0f / x;
#endif
}
// raw v_exp_f32 (computes 2^x)
__device__ __forceinline__ float fexp2(float x) {
#if __has_builtin(__builtin_amdgcn_exp2f)
    return __builtin_amdgcn_exp2f(x);
#else
    return exp2f(x);
#endif
}

// NOTE: no macro parameter may be named x/y/z/w (member-access collision!)
#define FMA4(ax,ay,az,aw,wv,acc) fmaf((ax),(wv).x,fmaf((ay),(wv).y,fmaf((az),(wv).z,fmaf((aw),(wv).w,(acc)))))

// ==================== recurrence SEGMENT (thread = b; state carried in ws_u row 0) ====================
// Runs steps t in [t0, t1). If t0==1: seed from s0, emit st_obs[0], zero NLL.
// If t1<288: persist sv into ws_u[0..511] (the t=0 U row — never read by the recurrence).
// Activations use exp2 with prefolded constants: tanh(x)=1-2/(1+2^(2*L2E*x)),
// sigm(a)=1/(1+2^(-L2E*a)) — scale factors folded into w1/c1 and w2/c2 at load time.
__device__ __forceinline__ void run_rec_seg(
    int b, int t0, int t1,
    const float* __restrict__ s0,
    const float* __restrict__ nobs, const float* __restrict__ npred,
    const float* __restrict__ Ws1, const float* __restrict__ bs1,
    const float* __restrict__ Ws2, const float* __restrict__ bs2,
    float* __restrict__ ws_u, float* __restrict__ out)
{
    const float L2E = 1.4426950408889634f;
    float w1[10], w2[10], c1[5], c2_0, c2_1;
#pragma unroll
    for (int i = 0; i < 10; i++) { w1[i] = Ws1[i] * (2.0f * L2E); w2[i] = Ws2[i] * (-L2E); }
#pragma unroll
    for (int i = 0; i < 5; i++) c1[i] = bs1[i] * (2.0f * L2E);
    c2_0 = bs2[0] * (-L2E); c2_1 = bs2[1] * (-L2E);

    float sv0, sv1;
    if (t0 == 1) {
        sv0 = s0[b * 2 + 0]; sv1 = s0[b * 2 + 1];
        ((float2*)(out + O_ST_OBS))[b] = make_float2(sv0, sv1);
        if (b == 0) out[O_NLL] = 0.0f;   // stream-ordered before k_dec2's atomics
    } else {
        sv0 = ws_u[b * 2 + 0]; sv1 = ws_u[b * 2 + 1];
    }

    const float2* Up   = (const float2*)ws_u;
    const float2* Nobs = (const float2*)nobs;
    const float2* Nprd = (const float2*)npred;

    auto LD = [&](int t, float2& u, float2& nz) {
        t = (t > 287) ? 287 : t;              // clamp: valid reads, values unused
        u  = Up[t * 256 + b];
        nz = (t < 256) ? Nobs[(t - 1) * 256 + b] : Nprd[(t - 256) * 256 + b];
    };
    auto STEP = [&](float2 u, float2 nz, int t) {
        const float v0 = sv0 + u.x, v1 = sv1 + u.y;
        const float h0 = fmaf(-2.f, frcp(fexp2(fmaf(v1, w1[1], fmaf(v0, w1[0], c1[0]))) + 1.f), 1.f);
        const float h1 = fmaf(-2.f, frcp(fexp2(fmaf(v1, w1[3], fmaf(v0, w1[2], c1[1]))) + 1.f), 1.f);
        const float h2 = fmaf(-2.f, frcp(fexp2(fmaf(v1, w1[5], fmaf(v0, w1[4], c1[2]))) + 1.f), 1.f);
        const float h3 = fmaf(-2.f, frcp(fexp2(fmaf(v1, w1[7], fmaf(v0, w1[6], c1[3]))) + 1.f), 1.f);
        const float h4 = fmaf(-2.f, frcp(fexp2(fmaf(v1, w1[9], fmaf(v0, w1[8], c1[4]))) + 1.f), 1.f);
        float a0 = fmaf(h0, w2[0], fmaf(h1, w2[1], c2_0));
        const float a0b = fmaf(h2, w2[2], h3 * w2[3]);
        a0 = fmaf(h4, w2[4], a0 + a0b);
        float a1 = fmaf(h0, w2[5], fmaf(h1, w2[6], c2_1));
        const float a1b = fmaf(h2, w2[7], h3 * w2[8]);
        a1 = fmaf(h4, w2[9], a1 + a1b);
        sv0 = fmaf(u.x, frcp(1.f + fexp2(a0)), sv0) + nz.x;
        sv1 = fmaf(u.y, frcp(1.f + fexp2(a1)), sv1) + nz.y;
        if (t < 256) ((float2*)(out + O_ST_OBS))[t * 256 + b] = make_float2(sv0, sv1);
        else         ((float2*)(out + O_ST_PRED))[(t - 256) * 256 + b] = make_float2(sv0, sv1);
    };

    float2 cu[8], cn[8];
#pragma unroll
    for (int j = 0; j < 8; j++) LD(t0 + j, cu[j], cn[j]);

#pragma unroll 1
    for (int base = t0; base < t1; base += 8) {
        float2 nu[8], nn[8];
#pragma unroll
        for (int j = 0; j < 8; j++) LD(base + 8 + j, nu[j], nn[j]);   // 16 loads in flight
#pragma unroll
        for (int j = 0; j < 8; j++) {
            if (base + j < t1) STEP(cu[j], cn[j], base + j);
        }
#pragma unroll
        for (int j = 0; j < 8; j++) { cu[j] = nu[j]; cn[j] = nn[j]; }
    }

    if (t1 < 288) { ws_u[b * 2 + 0] = sv0; ws_u[b * 2 + 1] = sv1; }
}

// ==================== Kernel 0 (fallback path only): U[t][b][2] = act^T . Wa ====================
extern "C" __global__ void __launch_bounds__(288)
k_pre(const float* __restrict__ act, const float* __restrict__ Wa, float* __restrict__ ws_u)
{
    const int b = blockIdx.x;
    const int t = threadIdx.x;
    float u0 = 0.f, u1 = 0.f;
#pragma unroll
    for (int a = 0; a < 5; a++) {
        const float av = act[(b * 5 + a) * 288 + t];
        u0 = fmaf(av, Wa[a], u0);
        u1 = fmaf(av, Wa[5 + a], u1);
    }
    ws_u[(t * 256 + b) * 2 + 0] = u0;
    ws_u[(t * 256 + b) * 2 + 1] = u1;
}

// ==================== Kernel 1a (fast path): U-precompute (blocks 0-255) + conv1+maxpool ====================
extern "C" __global__ void __launch_bounds__(256)
k_patch(const float* __restrict__ x, const float* __restrict__ act,
        const int* __restrict__ pos, const float* __restrict__ Wa,
        const float* __restrict__ Wc1, const float* __restrict__ bc1,
        float* __restrict__ ws_u, float* __restrict__ ws_pool)
{
    const int tid = threadIdx.x;
    if (blockIdx.x < 256) {
        const int b = blockIdx.x;
        const float wa0 = Wa[0], wa1 = Wa[1], wa2 = Wa[2], wa3 = Wa[3], wa4 = Wa[4];
        const float wa5 = Wa[5], wa6 = Wa[6], wa7 = Wa[7], wa8 = Wa[8], wa9 = Wa[9];
#pragma unroll 1
        for (int t = tid; t < 288; t += 256) {
            const float a0 = act[(b * 5 + 0) * 288 + t];
            const float a1 = act[(b * 5 + 1) * 288 + t];
            const float a2 = act[(b * 5 + 2) * 288 + t];
            const float a3 = act[(b * 5 + 3) * 288 + t];
            const float a4 = act[(b * 5 + 4) * 288 + t];
            const float u0 = fmaf(a4, wa4, fmaf(a3, wa3, fmaf(a2, wa2, fmaf(a1, wa1, a0 * wa0))));
            const float u1 = fmaf(a4, wa9, fmaf(a3, wa8, fmaf(a2, wa7, fmaf(a1, wa6, a0 * wa5))));
            ws_u[(t * 256 + b) * 2 + 0] = u0;
            ws_u[(t * 256 + b) * 2 + 1] = u1;
        }
        return;
    }
    const int bid = blockIdx.x - 256;
    const int b = bid / 5, c = bid % 5;

    __shared__ __align__(16) float sImg[3 * 1056];
    __shared__ float sWc1[192];
    __shared__ float sB1[16];

    for (int i = tid; i < 3072; i += 256) {
        const int ic = i >> 10, r = (i >> 5) & 31, cc = i & 31;
        sImg[ic * 1056 + r * 33 + cc] = x[b * 3072 + i];
    }
    if (tid < 192) sWc1[tid] = Wc1[tid];
    if (tid < 16) sB1[tid] = bc1[tid];
    __syncthreads();

    const int t = c * 64 + (tid >> 2);
    if (t >= 288) return;
    const int posq = tid & 3;
    const int py = posq >> 1, px = posq & 1;

    const int pr = 3 * pos[(b * 2 + 0) * 288 + t];
    const int pc = 3 * pos[(b * 2 + 1) * 288 + t];

    float p16[16];
#pragma unroll
    for (int i = 0; i < 16; i++) p16[i] = 0.f;

#pragma unroll 2
    for (int d = 0; d < 4; d++) {
        const int rbase = pr + 4 * py + 2 * (d >> 1);
        const int cbase = pc + 4 * px + 2 * (d & 1);
        float in[12];
#pragma unroll
        for (int ic = 0; ic < 3; ic++)
#pragma unroll
        for (int ky = 0; ky < 2; ky++)
#pragma unroll
        for (int kx = 0; kx < 2; kx++)
            in[ic * 4 + ky * 2 + kx] = sImg[ic * 1056 + (rbase + ky) * 33 + (cbase + kx)];
#pragma unroll
        for (int oc = 0; oc < 16; oc++) {
            const float4 wq0 = *(const float4*)&sWc1[oc * 12 + 0];
            const float4 wq1 = *(const float4*)&sWc1[oc * 12 + 4];
            const float4 wq2 = *(const float4*)&sWc1[oc * 12 + 8];
            float v = sB1[oc];
            v = FMA4(in[0], in[1], in[2], in[3], wq0, v);
            v = FMA4(in[4], in[5], in[6], in[7], wq1, v);
            v = FMA4(in[8], in[9], in[10], in[11], wq2, v);
            p16[oc] = fmaxf(p16[oc], fmaxf(v, 0.f));
        }
    }

    float4* dst = (float4*)(ws_pool + (((size_t)b * 288 + t) * 4 + posq) * 16);
    dst[0] = make_float4(p16[0], p16[1], p16[2], p16[3]);
    dst[1] = make_float4(p16[4], p16[5], p16[6], p16[7]);
    dst[2] = make_float4(p16[8], p16[9], p16[10], p16[11]);
    dst[3] = make_float4(p16[12], p16[13], p16[14], p16[15]);
}

// ==================== Kernel 1b (fast path): rec seg A (block 0) + BN1 + conv2 + BN2 + heads ====================
extern "C" __global__ void __launch_bounds__(256)
k_enc(const float* __restrict__ s0,   const float* __restrict__ nobs,
      const float* __restrict__ npred,
      const float* __restrict__ Ws1,  const float* __restrict__ bs1,
      const float* __restrict__ Ws2,  const float* __restrict__ bs2,
      const float* __restrict__ g1,   const float* __restrict__ be1,
      const float* __restrict__ Wc2,  const float* __restrict__ bc2,
      const float* __restrict__ g2,   const float* __restrict__ be2,
      const float* __restrict__ Wzm,  const float* __restrict__ bzm,
      const float* __restrict__ Wzs,  const float* __restrict__ bzs,
      float* __restrict__ ws_u, const float* __restrict__ ws_pool,
      float* __restrict__ out)
{
    const int tid = threadIdx.x;
    if (blockIdx.x == 0) {
        run_rec_seg(tid, 1, 97, s0, nobs, npred, Ws1, bs1, Ws2, bs2, ws_u, out);
        return;
    }
    const int t = blockIdx.x - 1, b = tid;
    const int wid = tid >> 6, lane = tid & 63;

    __shared__ __align__(16) float pooledL[256 * 68];
    __shared__ __align__(16) float sWc2r[2048];
    __shared__ __align__(16) float sM1[16], sS1[16], sE1[16];
    __shared__ float sB2[32], sE2[32];
    __shared__ float sM2[32], sS2[32];
    __shared__ float sRed[4][64];

    for (int i = tid; i < 2048; i += 256) {
        const int oc = i >> 6, rem = i & 63, ic = rem >> 2, q = rem & 3;
        sWc2r[oc * 64 + q * 16 + ic] = Wc2[i];
    }
    if (tid < 16) { sE1[tid] = be1[tid]; }
    if (tid < 32) { sB2[tid] = bc2[tid]; sE2[tid] = be2[tid]; }

    float* myrow = &pooledL[b * 68];
    {
        const float4* src = (const float4*)(ws_pool + ((size_t)b * 288 + t) * 64);
#pragma unroll
        for (int q = 0; q < 16; q++) *(float4*)&myrow[4 * q] = src[q];
    }
    __syncthreads();

    {
        const int col = tid & 63, q = tid >> 6;
        float s = 0.f, ss = 0.f;
        const float* cp = &pooledL[(q * 64) * 68 + col];
#pragma unroll 4
        for (int i = 0; i < 64; i++) { const float v = cp[i * 68]; s += v; ss = fmaf(v, v, ss); }
        sRed[q][col] = s;
        __syncthreads();
        float ssum = 0.f;
        if (tid < 16) {
#pragma unroll
            for (int p = 0; p < 4; p++)
#pragma unroll
            for (int qq = 0; qq < 4; qq++) ssum += sRed[qq][p * 16 + tid];
        }
        __syncthreads();
        sRed[q][col] = ss;
        __syncthreads();
        if (tid < 16) {
            float sssum = 0.f;
#pragma unroll
            for (int p = 0; p < 4; p++)
#pragma unroll
            for (int qq = 0; qq < 4; qq++) sssum += sRed[qq][p * 16 + tid];
            const float m = ssum * (1.f / 1024.f);
            const float var = fmaf(-m, m, sssum * (1.f / 1024.f));
            sM1[tid] = m; sS1[tid] = g1[tid] * rsqrtf(var + 1e-5f);
        }
    }
    __syncthreads();

#pragma unroll 4
    for (int tq = 0; tq < 16; tq++) {
        const int ic0 = (tq & 3) * 4;
        float4 v = *(float4*)&myrow[4 * tq];
        const float4 mq = *(const float4*)&sM1[ic0];
        const float4 sq = *(const float4*)&sS1[ic0];
        const float4 eq = *(const float4*)&sE1[ic0];
        v.x = fmaf(v.x - mq.x, sq.x, eq.x);
        v.y = fmaf(v.y - mq.y, sq.y, eq.y);
        v.z = fmaf(v.z - mq.z, sq.z, eq.z);
        v.w = fmaf(v.w - mq.w, sq.w, eq.w);
        *(float4*)&myrow[4 * tq] = v;
    }

    float h2v[32];
#pragma unroll
    for (int og = 0; og < 4; og++) {
        float acc[8];
#pragma unroll
        for (int jj = 0; jj < 8; jj++) acc[jj] = sB2[og * 8 + jj];
#pragma unroll 2
        for (int tq = 0; tq < 16; tq++) {
            const float4 hq = *(const float4*)&myrow[4 * tq];
#pragma unroll
            for (int jj = 0; jj < 8; jj++) {
                const float4 wv = *(const float4*)&sWc2r[(og * 8 + jj) * 64 + 4 * tq];
                acc[jj] = FMA4(hq.x, hq.y, hq.z, hq.w, wv, acc[jj]);
            }
        }
#pragma unroll
        for (int jj = 0; jj < 8; jj++) h2v[og * 8 + jj] = fmaxf(acc[jj], 0.f);
    }

#pragma unroll
    for (int oc = 0; oc < 32; oc++) {
        float s = wred(h2v[oc]), ss = wred(h2v[oc] * h2v[oc]);
        if (lane == 0) { sRed[wid][2 * oc] = s; sRed[wid][2 * oc + 1] = ss; }
    }
    __syncthreads();
    if (tid < 32) {
        const float s  = sRed[0][2 * tid] + sRed[1][2 * tid] + sRed[2][2 * tid] + sRed[3][2 * tid];
        const float ss = sRed[0][2 * tid + 1] + sRed[1][2 * tid + 1] + sRed[2][2 * tid + 1] + sRed[3][2 * tid + 1];
        const float m = s * (1.f / 256.f);
        const float var = fmaf(-m, m, ss * (1.f / 256.f));
        sM2[tid] = m; sS2[tid] = g2[tid] * rsqrtf(var + 1e-5f);
    }
    __syncthreads();
#pragma unroll
    for (int oc = 0; oc < 32; oc++) h2v[oc] = fmaf(h2v[oc] - sM2[oc], sS2[oc], sE2[oc]);

    const int obase_m = (t < 256) ? (O_ZM_OBS + (t * 256 + b) * 16) : (O_ZM_PRED + ((t - 256) * 256 + b) * 16);
    const int obase_s = (t < 256) ? (O_ZS_OBS + (t * 256 + b) * 16) : (O_ZS_PRED + ((t - 256) * 256 + b) * 16);
#pragma unroll 2
    for (int k = 0; k < 16; k++) {
        float vm = bzm[k], vs = bzs[k];
#pragma unroll
        for (int c = 0; c < 32; c += 4) {
            const float4 wm = *(const float4*)&Wzm[k * 32 + c];
            const float4 wsq = *(const float4*)&Wzs[k * 32 + c];
            vm = FMA4(h2v[c], h2v[c + 1], h2v[c + 2], h2v[c + 3], wm, vm);
            vs = FMA4(h2v[c], h2v[c + 1], h2v[c + 2], h2v[c + 3], wsq, vs);
        }
        out[obase_m + k] = vm;
        out[obase_s + k] = __expf(vs);
    }
}

// ==================== Kernel 1 (fallback): fused encoder with global gathers ====================
extern "C" __global__ void __launch_bounds__(256)
k_enc_full(const float* __restrict__ x,
           const int*   __restrict__ pos,  const float* __restrict__ s0,
           const float* __restrict__ nobs, const float* __restrict__ npred,
           const float* __restrict__ Ws1,  const float* __restrict__ bs1,
           const float* __restrict__ Ws2,  const float* __restrict__ bs2,
           const float* __restrict__ Wc1,  const float* __restrict__ bc1,
           const float* __restrict__ g1,   const float* __restrict__ be1,
           const float* __restrict__ Wc2,  const float* __restrict__ bc2,
           const float* __restrict__ g2,   const float* __restrict__ be2,
           const float* __restrict__ Wzm,  const float* __restrict__ bzm,
           const float* __restrict__ Wzs,  const float* __restrict__ bzs,
           float* __restrict__ ws_u, float* __restrict__ out)
{
    const int tid = threadIdx.x;
    if (blockIdx.x == 0) {
        run_rec_seg(tid, 1, 97, s0, nobs, npred, Ws1, bs1, Ws2, bs2, ws_u, out);
        return;
    }
    const int t = blockIdx.x - 1;
    __shared__ __align__(16) float sWc1[192];
    __shared__ __align__(16) float sWc2r[2048];
    __shared__ __align__(16) float sM1[16], sS1[16], sE1[16];
    __shared__ float sB1[16], sB2[32], sE2[32];
    __shared__ float sM2[32], sS2[32];
    __shared__ float sRed[4][64];
    __shared__ __align__(16) float pooledL[256 * 68];

    for (int i = tid; i < 192; i += 256) sWc1[i] = Wc1[i];
    for (int i = tid; i < 2048; i += 256) {
        const int oc = i >> 6, rem = i & 63, ic = rem >> 2, q = rem & 3;
        sWc2r[oc * 64 + q * 16 + ic] = Wc2[i];
    }
    if (tid < 16) { sB1[tid] = bc1[tid]; sE1[tid] = be1[tid]; }
    if (tid < 32) { sB2[tid] = bc2[tid]; sE2[tid] = be2[tid]; }
    __syncthreads();

    const int b = tid;
    const int wid = tid >> 6, lane = tid & 63;
    const float* xb = x + b * 3072;
    const int pr = 3 * pos[(b * 2 + 0) * 288 + t];
    const int pc = 3 * pos[(b * 2 + 1) * 288 + t];
    float* myrow = &pooledL[b * 68];

#pragma unroll
    for (int py = 0; py < 2; py++)
#pragma unroll
    for (int px = 0; px < 2; px++) {
        float p16[16];
#pragma unroll
        for (int i = 0; i < 16; i++) p16[i] = 0.f;
#pragma unroll 2
        for (int d = 0; d < 4; d++) {
            const int rbase = pr + 4 * py + 2 * (d >> 1);
            const int cbase = pc + 4 * px + 2 * (d & 1);
            float in[12];
#pragma unroll
            for (int ic = 0; ic < 3; ic++)
#pragma unroll
            for (int ky = 0; ky < 2; ky++)
#pragma unroll
            for (int kx = 0; kx < 2; kx++)
                in[ic * 4 + ky * 2 + kx] = xb[ic * 1024 + (rbase + ky) * 32 + (cbase + kx)];
#pragma unroll
            for (int oc = 0; oc < 16; oc++) {
                const float4 wq0 = *(const float4*)&sWc1[oc * 12 + 0];
                const float4 wq1 = *(const float4*)&sWc1[oc * 12 + 4];
                const float4 wq2 = *(const float4*)&sWc1[oc * 12 + 8];
                float v = sB1[oc];
                v = FMA4(in[0], in[1], in[2], in[3], wq0, v);
                v = FMA4(in[4], in[5], in[6], in[7], wq1, v);
                v = FMA4(in[8], in[9], in[10], in[11], wq2, v);
                p16[oc] = fmaxf(p16[oc], fmaxf(v, 0.f));
            }
        }
        const int pbase = (py * 2 + px) * 16;
        *(float4*)&myrow[pbase + 0]  = make_float4(p16[0], p16[1], p16[2], p16[3]);
        *(float4*)&myrow[pbase + 4]  = make_float4(p16[4], p16[5], p16[6], p16[7]);
        *(float4*)&myrow[pbase + 8]  = make_float4(p16[8], p16[9], p16[10], p16[11]);
        *(float4*)&myrow[pbase + 12] = make_float4(p16[12], p16[13], p16[14], p16[15]);
    }
    __syncthreads();

    {
        const int col = tid & 63, q = tid >> 6;
        float s = 0.f, ss = 0.f;
        const float* cp = &pooledL[(q * 64) * 68 + col];
#pragma unroll 4
        for (int i = 0; i < 64; i++) { const float v = cp[i * 68]; s += v; ss = fmaf(v, v, ss); }
        sRed[q][col] = s;
        __syncthreads();
        float ssum = 0.f;
        if (tid < 16) {
#pragma unroll
            for (int p = 0; p < 4; p++)
#pragma unroll
            for (int qq = 0; qq < 4; qq++) ssum += sRed[qq][p * 16 + tid];
        }
        __syncthreads();
        sRed[q][col] = ss;
        __syncthreads();
        if (tid < 16) {
            float sssum = 0.f;
#pragma unroll
            for (int p = 0; p < 4; p++)
#pragma unroll
            for (int qq = 0; qq < 4; qq++) sssum += sRed[qq][p * 16 + tid];
            const float m = ssum * (1.f / 1024.f);
            const float var = fmaf(-m, m, sssum * (1.f / 1024.f));
            sM1[tid] = m; sS1[tid] = g1[tid] * rsqrtf(var + 1e-5f);
        }
    }
    __syncthreads();

#pragma unroll 4
    for (int tq = 0; tq < 16; tq++) {
        const int ic0 = (tq & 3) * 4;
        float4 v = *(float4*)&myrow[4 * tq];
        const float4 mq = *(const float4*)&sM1[ic0];
        const float4 sq = *(const float4*)&sS1[ic0];
        const float4 eq = *(const float4*)&sE1[ic0];
        v.x = fmaf(v.x - mq.x, sq.x, eq.x);
        v.y = fmaf(v.y - mq.y, sq.y, eq.y);
        v.z = fmaf(v.z - mq.z, sq.z, eq.z);
        v.w = fmaf(v.w - mq.w, sq.w, eq.w);
        *(float4*)&myrow[4 * tq] = v;
    }

    float h2v[32];
#pragma unroll
    for (int og = 0; og < 4; og++) {
        float acc[8];
#pragma unroll
        for (int jj = 0; jj < 8; jj++) acc[jj] = sB2[og * 8 + jj];
#pragma unroll 2
        for (int tq = 0; tq < 16; tq++) {
            const float4 hq = *(const float4*)&myrow[4 * tq];
#pragma unroll
            for (int jj = 0; jj < 8; jj++) {
                const float4 wv = *(const float4*)&sWc2r[(og * 8 + jj) * 64 + 4 * tq];
                acc[jj] = FMA4(hq.x, hq.y, hq.z, hq.w, wv, acc[jj]);
            }
        }
#pragma unroll
        for (int jj = 0; jj < 8; jj++) h2v[og * 8 + jj] = fmaxf(acc[jj], 0.f);
    }

#pragma unroll
    for (int oc = 0; oc < 32; oc++) {
        float s = wred(h2v[oc]), ss = wred(h2v[oc] * h2v[oc]);
        if (lane == 0) { sRed[wid][2 * oc] = s; sRed[wid][2 * oc + 1] = ss; }
    }
    __syncthreads();
    if (tid < 32) {
        const float s  = sRed[0][2 * tid] + sRed[1][2 * tid] + sRed[2][2 * tid] + sRed[3][2 * tid];
        const float ss = sRed[0][2 * tid + 1] + sRed[1][2 * tid + 1] + sRed[2][2 * tid + 1] + sRed[3][2 * tid + 1];
        const float m = s * (1.f / 256.f);
        const float var = fmaf(-m, m, ss * (1.f / 256.f));
        sM2[tid] = m; sS2[tid] = g2[tid] * rsqrtf(var + 1e-5f);
    }
    __syncthreads();
#pragma unroll
    for (int oc = 0; oc < 32; oc++) h2v[oc] = fmaf(h2v[oc] - sM2[oc], sS2[oc], sE2[oc]);

    const int obase_m = (t < 256) ? (O_ZM_OBS + (t * 256 + b) * 16) : (O_ZM_PRED + ((t - 256) * 256 + b) * 16);
    const int obase_s = (t < 256) ? (O_ZS_OBS + (t * 256 + b) * 16) : (O_ZS_PRED + ((t - 256) * 256 + b) * 16);
#pragma unroll 2
    for (int k = 0; k < 16; k++) {
        float vm = bzm[k], vs = bzs[k];
#pragma unroll
        for (int c = 0; c < 32; c += 4) {
            const float4 wm = *(const float4*)&Wzm[k * 32 + c];
            const float4 wsq = *(const float4*)&Wzs[k * 32 + c];
            vm = FMA4(h2v[c], h2v[c + 1], h2v[c + 2], h2v[c + 3], wm, vm);
            vs = FMA4(h2v[c], h2v[c + 1], h2v[c + 2], h2v[c + 3], wsq, vs);
        }
        out[obase_m + k] = vm;
        out[obase_s + k] = __expf(vs);
    }
}

// ==================== Kernel 2: rec seg B (block 0) + 512-thread decoder front half ====================
// grid 129: block 0 = recurrence seg [97,193); blocks 1..128: tp = (bid-1)>>2, g = (bid-1)&3
extern "C" __global__ void __launch_bounds__(512)
k_dec1(const float* __restrict__ eps,
       const float* __restrict__ s0,   const float* __restrict__ nobs,
       const float* __restrict__ npred,
       const float* __restrict__ Ws1,  const float* __restrict__ bs1,
       const float* __restrict__ Ws2,  const float* __restrict__ bs2,
       const float* __restrict__ Wd1,  const float* __restrict__ bd1,
       const float* __restrict__ gd1,  const float* __restrict__ bed1,
       const float* __restrict__ Wd2,  const float* __restrict__ bd2,
       const float* __restrict__ gd2,  const float* __restrict__ bed2,
       const float* __restrict__ Wt1,  const float* __restrict__ bt1,
       const float* __restrict__ out_c,
       float* __restrict__ ws_u,
       float* __restrict__ ws_h2n, float* __restrict__ ws_p3,
       float* __restrict__ out)
{
    const int tid = threadIdx.x;
    if (blockIdx.x == 0) {
        if (tid < 256)
            run_rec_seg(tid, 97, 193, s0, nobs, npred, Ws1, bs1, Ws2, bs2, ws_u, out);
        return;
    }
    const int bid = blockIdx.x - 1;
    const int tp = bid >> 2, g = bid & 3;
    const int b = tid & 255, half = tid >> 8;
    const int wid = tid >> 6, lane = tid & 63;

    __shared__ __align__(16) float sWd1[1024];
    __shared__ __align__(16) float sWd2g[2048];
    __shared__ __align__(16) float sWt1g[2048];
    __shared__ float h1L[256 * 65];
    __shared__ float h2L[256 * 33];
    __shared__ float sRed[8][128];
    __shared__ float sAcc[8][32];
    __shared__ float sM1[64], sS1[64], sE1[64];
    __shared__ float sM2[32], sS2[32], sE2[32];
    __shared__ float sBd1[64], sBd2g[32], sBt1[16];
    float* sRedF = &sRed[0][0];

    for (int i = tid; i < 1024; i += 512) sWd1[i] = Wd1[i];
    for (int i = tid; i < 2048; i += 512) {
        const int ic = i >> 6, k = i & 63;
        sWd2g[i] = Wd2[(4 * ic + g) * 64 + k];
    }
    for (int i = tid; i < 2048; i += 512) {
        const int dp = i >> 9, rem = i & 511, oc = rem >> 5, ic = i & 31;
        const int py = (g >> 1) * 2 + (dp >> 1), px = (g & 1) * 2 + (dp & 1);
        const int k9 = ((py + 1) % 3) * 3 + ((px + 1) % 3);
        sWt1g[(dp * 16 + oc) * 32 + ic] = Wt1[ic * 144 + oc * 9 + k9];
    }
    if (tid < 64) sBd1[tid] = bd1[tid];
    if (tid < 32) sBd2g[tid] = bd2[4 * tid + g];
    if (tid < 16) sBt1[tid] = bt1[tid];
    if (tid < 256) ((float*)sAcc)[tid] = 0.f;
    __syncthreads();

    float4 zA, zB, zC, zD;
    {
        const int base = (tp * 256 + b) * 16;
        const float4 e0 = *(const float4*)&eps[base + 0],  e1 = *(const float4*)&eps[base + 4];
        const float4 e2 = *(const float4*)&eps[base + 8],  e3 = *(const float4*)&eps[base + 12];
        const float4 s0v = *(const float4*)&out_c[O_ZS_PRED + base + 0],  s1v = *(const float4*)&out_c[O_ZS_PRED + base + 4];
        const float4 s2v = *(const float4*)&out_c[O_ZS_PRED + base + 8],  s3v = *(const float4*)&out_c[O_ZS_PRED + base + 12];
        const float4 m0 = *(const float4*)&out_c[O_ZM_PRED + base + 0],  m1 = *(const float4*)&out_c[O_ZM_PRED + base + 4];
        const float4 m2 = *(const float4*)&out_c[O_ZM_PRED + base + 8],  m3 = *(const float4*)&out_c[O_ZM_PRED + base + 12];
        zA = make_float4(fmaf(e0.x,s0v.x,m0.x), fmaf(e0.y,s0v.y,m0.y), fmaf(e0.z,s0v.z,m0.z), fmaf(e0.w,s0v.w,m0.w));
        zB = make_float4(fmaf(e1.x,s1v.x,m1.x), fmaf(e1.y,s1v.y,m1.y), fmaf(e1.z,s1v.z,m1.z), fmaf(e1.w,s1v.w,m1.w));
        zC = make_float4(fmaf(e2.x,s2v.x,m2.x), fmaf(e2.y,s2v.y,m2.y), fmaf(e2.z,s2v.z,m2.z), fmaf(e2.w,s2v.w,m2.w));
        zD = make_float4(fmaf(e3.x,s3v.x,m3.x), fmaf(e3.y,s3v.y,m3.y), fmaf(e3.z,s3v.z,m3.z), fmaf(e3.w,s3v.w,m3.w));
    }

#pragma unroll 4
    for (int jj = 0; jj < 32; ++jj) {
        const int j = half * 32 + jj;
        const float4 wq0 = *(const float4*)&sWd1[j * 16 + 0];
        const float4 wq1 = *(const float4*)&sWd1[j * 16 + 4];
        const float4 wq2 = *(const float4*)&sWd1[j * 16 + 8];
        const float4 wq3 = *(const float4*)&sWd1[j * 16 + 12];
        float v = sBd1[j];
        v = FMA4(zA.x, zA.y, zA.z, zA.w, wq0, v);
        v = FMA4(zB.x, zB.y, zB.z, zB.w, wq1, v);
        v = FMA4(zC.x, zC.y, zC.z, zC.w, wq2, v);
        v = FMA4(zD.x, zD.y, zD.z, zD.w, wq3, v);
        h1L[b * 65 + j] = fmaxf(v, 0.f);
    }
    __syncthreads();

    {
        const int col = tid & 63, q = tid >> 6;
        float s = 0.f, ss = 0.f;
        const float* cp = &h1L[(q * 32) * 65 + col];
#pragma unroll 4
        for (int i = 0; i < 32; i++) { const float v = cp[i * 65]; s += v; ss = fmaf(v, v, ss); }
        sRed[q][2 * col] = s; sRed[q][2 * col + 1] = ss;
    }
    __syncthreads();
    if (tid < 64) {
        float s = 0.f, ss = 0.f;
#pragma unroll
        for (int q = 0; q < 8; q++) { s += sRed[q][2 * tid]; ss += sRed[q][2 * tid + 1]; }
        const float m = s * (1.f / 256.f);
        const float var = fmaf(-m, m, ss * (1.f / 256.f));
        sM1[tid] = m; sS1[tid] = gd1[tid] * rsqrtf(var + 1e-5f); sE1[tid] = bed1[tid];
    }
    __syncthreads();

#pragma unroll 4
    for (int jj = 0; jj < 32; ++jj) {
        const int j = half * 32 + jj;
        h1L[b * 65 + j] = fmaf(h1L[b * 65 + j] - sM1[j], sS1[j], sE1[j]);
    }
    __syncthreads();

    float hr[64];
#pragma unroll
    for (int k = 0; k < 64; ++k) hr[k] = h1L[b * 65 + k];

#pragma unroll 1
    for (int ic = 0; ic < 16; ++ic) {
        const int icg = half * 16 + ic;
        float v = sBd2g[icg];
#pragma unroll
        for (int k4 = 0; k4 < 16; ++k4) {
            const float4 wv = *(const float4*)&sWd2g[icg * 64 + 4 * k4];
            v = FMA4(hr[4*k4], hr[4*k4+1], hr[4*k4+2], hr[4*k4+3], wv, v);
        }
        h2L[b * 33 + icg] = fmaxf(v, 0.f);
    }
    __syncthreads();

    {
        const int col = tid & 31, q = tid >> 5;
        float s = 0.f, ss = 0.f;
        const float* cp = &h2L[(q * 16) * 33 + col];
#pragma unroll 4
        for (int i = 0; i < 16; i++) { const float v = cp[i * 33]; s += v; ss = fmaf(v, v, ss); }
        sRedF[q * 32 + col] = s;
        __syncthreads();
        float ssum = 0.f;
        if (tid < 32) {
#pragma unroll
            for (int qq = 0; qq < 16; qq++) ssum += sRedF[qq * 32 + tid];
        }
        __syncthreads();
        sRedF[q * 32 + col] = ss;
        __syncthreads();
        if (tid < 32) {
            float sssum = 0.f;
#pragma unroll
            for (int qq = 0; qq < 16; qq++) sssum += sRedF[qq * 32 + tid];
            const float m = ssum * (1.f / 256.f);
            const float var = fmaf(-m, m, sssum * (1.f / 256.f));
            sM2[tid] = m;
            sS2[tid] = gd2[4 * tid + g] * rsqrtf(var + 1e-5f);
            sE2[tid] = bed2[4 * tid + g];
        }
    }
    __syncthreads();

#pragma unroll 4
    for (int ic = 0; ic < 16; ++ic) {
        const int icg = half * 16 + ic;
        h2L[b * 33 + icg] = fmaf(h2L[b * 33 + icg] - sM2[icg], sS2[icg], sE2[icg]);
    }
    __syncthreads();

    float h2r[32];
#pragma unroll
    for (int k = 0; k < 32; ++k) h2r[k] = h2L[b * 33 + k];
    {
        float* dst = ws_h2n + (((size_t)(tp * 4 + g) * 256 + b) * 32 + half * 16);
        const int o = half * 16;
        *(float4*)&dst[0]  = make_float4(h2r[o+0],  h2r[o+1],  h2r[o+2],  h2r[o+3]);
        *(float4*)&dst[4]  = make_float4(h2r[o+4],  h2r[o+5],  h2r[o+6],  h2r[o+7]);
        *(float4*)&dst[8]  = make_float4(h2r[o+8],  h2r[o+9],  h2r[o+10], h2r[o+11]);
        *(float4*)&dst[12] = make_float4(h2r[o+12], h2r[o+13], h2r[o+14], h2r[o+15]);
    }

#pragma unroll 1
    for (int d2 = 0; d2 < 2; ++d2) {
        const int dp = half * 2 + d2;
#pragma unroll 1
        for (int oc = 0; oc < 16; ++oc) {
            float v = sBt1[oc];
            const float* wrow = &sWt1g[(dp * 16 + oc) * 32];
#pragma unroll
            for (int i4 = 0; i4 < 8; ++i4) {
                const float4 wv = *(const float4*)&wrow[4 * i4];
                v = FMA4(h2r[4*i4], h2r[4*i4+1], h2r[4*i4+2], h2r[4*i4+3], wv, v);
            }
            v = fmaxf(v, 0.f);
            const float s = wred(v), ss = wred(v * v);
            if (lane == 0) { sAcc[wid][2 * oc] += s; sAcc[wid][2 * oc + 1] += ss; }
        }
    }
    __syncthreads();
    if (tid < 16) {
        float s = 0.f, ss = 0.f;
#pragma unroll
        for (int w = 0; w < 8; w++) { s += sAcc[w][2 * tid]; ss += sAcc[w][2 * tid + 1]; }
        ws_p3[(tp * 4 + g) * 32 + 2 * tid + 0] = s;
        ws_p3[(tp * 4 + g) * 32 + 2 * tid + 1] = ss;
    }
}

// ==================== Kernel 3: rec seg C (block 0) + BN3 finalize + convT1 + convT2 + nll ====================
// grid 257: block 0 = recurrence seg [193,288); blocks 1..256: bid-1 -> tp,g,hf
extern "C" __global__ void __launch_bounds__(256)
k_dec2(const float* __restrict__ x,    const int* __restrict__ pos,
       const float* __restrict__ s0,   const float* __restrict__ nobs,
       const float* __restrict__ npred,
       const float* __restrict__ Ws1,  const float* __restrict__ bs1,
       const float* __restrict__ Ws2,  const float* __restrict__ bs2,
       const float* __restrict__ Wt1,  const float* __restrict__ bt1,
       const float* __restrict__ gt1,  const float* __restrict__ bet1,
       const float* __restrict__ Wt2,  const float* __restrict__ bt2,
       float* __restrict__ out,
       float* __restrict__ ws_u,
       const float* __restrict__ ws_h2n, const float* __restrict__ ws_p3)
{
    const int tid = threadIdx.x;
    if (blockIdx.x == 0) {
        run_rec_seg(tid, 193, 288, s0, nobs, npred, Ws1, bs1, Ws2, bs2, ws_u, out);
        return;
    }
    const int bid = blockIdx.x - 1;
    const int tp = bid >> 3, g = (bid >> 1) & 3, hf = bid & 1;
    const int b = tid;
    const int wid = tid >> 6, lane = tid & 63;

    __shared__ __align__(16) float sWt1g[1024];
    __shared__ __align__(16) float sWt2[192];
    __shared__ float sBt1[16], sBt2[3];
    __shared__ float sRed[4][64];
    __shared__ float sM3[16], sS3[16], sE3[16];

    for (int i = tid; i < 1024; i += 256) {
        const int d2 = i >> 9, rem = i & 511, oc = rem >> 5, ic = i & 31;
        const int dp = hf * 2 + d2;
        const int py = (g >> 1) * 2 + (dp >> 1), px = (g & 1) * 2 + (dp & 1);
        const int k9 = ((py + 1) % 3) * 3 + ((px + 1) % 3);
        sWt1g[(d2 * 16 + oc) * 32 + ic] = Wt1[ic * 144 + oc * 9 + k9];
    }
    if (tid < 192) { const int ic = tid / 12, r = tid % 12; sWt2[r * 16 + ic] = Wt2[tid]; }
    if (tid < 16) sBt1[tid] = bt1[tid];
    if (tid < 3) sBt2[tid] = bt2[tid];
    if (tid < 16) {
        float s = 0.f, ss = 0.f;
#pragma unroll
        for (int gg = 0; gg < 4; gg++) {
            s  += ws_p3[(tp * 4 + gg) * 32 + 2 * tid + 0];
            ss += ws_p3[(tp * 4 + gg) * 32 + 2 * tid + 1];
        }
        const float m = s * (1.f / 4096.f);
        const float var = fmaf(-m, m, ss * (1.f / 4096.f));
        sM3[tid] = m; sS3[tid] = gt1[tid] * rsqrtf(var + 1e-5f); sE3[tid] = bet1[tid];
    }
    __syncthreads();

    float h2g[32];
    {
        const float* src = ws_h2n + (((size_t)(tp * 4 + g) * 256 + b) * 32);
#pragma unroll
        for (int i4 = 0; i4 < 8; i4++) {
            const float4 v4 = *(const float4*)&src[4 * i4];
            h2g[4 * i4] = v4.x; h2g[4 * i4 + 1] = v4.y; h2g[4 * i4 + 2] = v4.z; h2g[4 * i4 + 3] = v4.w;
        }
    }

    const int t = 256 + tp;
    const int pr = 3 * pos[(b * 2 + 0) * 288 + t];
    const int pc = 3 * pos[(b * 2 + 1) * 288 + t];
    const float* xb = x + b * 3072;
    const int rbase = O_XREC + (tp * 256 + b) * 192;
    const int py0 = (g >> 1) * 2, px0 = (g & 1) * 2;
    float err = 0.f;

#pragma unroll 1
    for (int d2 = 0; d2 < 2; d2++) {
        const int dp = hf * 2 + d2;
        const int py = py0 + (dp >> 1), px = px0 + (dp & 1);
        float hn[16];
#pragma unroll
        for (int og = 0; og < 4; og++) {
            float acc[4];
#pragma unroll
            for (int jj = 0; jj < 4; jj++) acc[jj] = sBt1[og * 4 + jj];
#pragma unroll
            for (int i4 = 0; i4 < 8; i4++) {
#pragma unroll
                for (int jj = 0; jj < 4; jj++) {
                    const float4 wv = *(const float4*)&sWt1g[(d2 * 16 + og * 4 + jj) * 32 + 4 * i4];
                    acc[jj] = FMA4(h2g[4*i4], h2g[4*i4+1], h2g[4*i4+2], h2g[4*i4+3], wv, acc[jj]);
                }
            }
#pragma unroll
            for (int jj = 0; jj < 4; jj++) {
                const int oc = og * 4 + jj;
                hn[oc] = fmaf(fmaxf(acc[jj], 0.f) - sM3[oc], sS3[oc], sE3[oc]);
            }
        }
#pragma unroll
        for (int c = 0; c < 3; c++)
#pragma unroll
        for (int dy = 0; dy < 2; dy++)
#pragma unroll
        for (int dx = 0; dx < 2; dx++) {
            const float* wp = &sWt2[(c * 4 + dy * 2 + dx) * 16];
            float v = sBt2[c];
#pragma unroll
            for (int ic = 0; ic < 16; ic += 4) {
                const float4 wq = *(const float4*)&wp[ic];
                v = FMA4(hn[ic], hn[ic + 1], hn[ic + 2], hn[ic + 3], wq, v);
            }
            v = sigm(v);
            const int oy = 2 * py + dy, ox = 2 * px + dx;
            out[rbase + c * 64 + oy * 8 + ox] = v;
            const float d = v - xb[c * 1024 + (pr + oy) * 32 + (pc + ox)];
            err = fmaf(d, d, err);
        }
    }

    const float es = wred(err);
    if (lane == 0) sRed[wid][0] = es;
    __syncthreads();
    if (tid == 0)
        atomicAdd(&out[O_NLL], sRed[0][0] + sRed[1][0] + sRed[2][0] + sRed[3][0]);
}

// ==================== host ====================
extern "C" void kernel_launch(void* const* d_in, const int* in_sizes, int n_in,
                              void* d_out, int out_size, void* d_ws, size_t ws_size,
                              hipStream_t stream)
{
    const float* x    = (const float*)d_in[0];
    const float* act  = (const float*)d_in[1];
    const int*   pos  = (const int*)d_in[2];
    const float* s0   = (const float*)d_in[3];
    const float* nobs = (const float*)d_in[4];
    const float* nprd = (const float*)d_in[5];
    const float* eps  = (const float*)d_in[6];
    const float* Wa   = (const float*)d_in[7];
    const float* Ws1  = (const float*)d_in[8];
    const float* bs1  = (const float*)d_in[9];
    const float* Ws2  = (const float*)d_in[10];
    const float* bs2  = (const float*)d_in[11];
    const float* Wc1  = (const float*)d_in[12];
    const float* bc1  = (const float*)d_in[13];
    const float* g1   = (const float*)d_in[14];
    const float* be1  = (const float*)d_in[15];
    const float* Wc2  = (const float*)d_in[16];
    const float* bc2  = (const float*)d_in[17];
    const float* g2   = (const float*)d_in[18];
    const float* be2  = (const float*)d_in[19];
    const float* Wzm  = (const float*)d_in[20];
    const float* bzm  = (const float*)d_in[21];
    const float* Wzs  = (const float*)d_in[22];
    const float* bzs  = (const float*)d_in[23];
    const float* Wd1  = (const float*)d_in[24];
    const float* bd1  = (const float*)d_in[25];
    const float* gd1  = (const float*)d_in[26];
    const float* bed1 = (const float*)d_in[27];
    const float* Wd2  = (const float*)d_in[28];
    const float* bd2  = (const float*)d_in[29];
    const float* gd2  = (const float*)d_in[30];
    const float* bed2 = (const float*)d_in[31];
    const float* Wt1  = (const float*)d_in[32];
    const float* bt1  = (const float*)d_in[33];
    const float* gt1  = (const float*)d_in[34];
    const float* bet1 = (const float*)d_in[35];
    const float* Wt2  = (const float*)d_in[36];
    const float* bt2  = (const float*)d_in[37];
    float* out = (float*)d_out;
    float* ws  = (float*)d_ws;

    const size_t need_fast = (POOL_FLOATS + 147456) * sizeof(float);  // 19.46 MB

    if (ws_size >= need_fast) {
        float* ws_pool = ws;
        float* ws_u    = ws + POOL_FLOATS;   // row 0 doubles as sv carry (t=0 never read)
        float* ws_h2n  = ws;                 // reuses pool region after k_enc consumed it
        float* ws_p3   = ws + 1048576;

        k_patch<<<dim3(1536), dim3(256), 0, stream>>>(
            x, act, pos, Wa, Wc1, bc1, ws_u, ws_pool);
        k_enc<<<dim3(289), dim3(256), 0, stream>>>(
            s0, nobs, nprd, Ws1, bs1, Ws2, bs2,
            g1, be1, Wc2, bc2, g2, be2, Wzm, bzm, Wzs, bzs, ws_u, ws_pool, out);
        k_dec1<<<dim3(129), dim3(512), 0, stream>>>(
            eps, s0, nobs, nprd, Ws1, bs1, Ws2, bs2,
            Wd1, bd1, gd1, bed1, Wd2, bd2, gd2, bed2, Wt1, bt1,
            out, ws_u, ws_h2n, ws_p3, out);
        k_dec2<<<dim3(257), dim3(256), 0, stream>>>(
            x, pos, s0, nobs, nprd, Ws1, bs1, Ws2, bs2,
            Wt1, bt1, gt1, bet1, Wt2, bt2, out, ws_u, ws_h2n, ws_p3);
    } else {
        float* ws_u   = ws;                  // row 0 doubles as sv carry
        float* ws_h2n = ws + 147456;
        float* ws_p3  = ws + 1196032;

        k_pre<<<dim3(256), dim3(288), 0, stream>>>(act, Wa, ws_u);
        k_enc_full<<<dim3(289), dim3(256), 0, stream>>>(
            x, pos, s0, nobs, nprd, Ws1, bs1, Ws2, bs2,
            Wc1, bc1, g1, be1, Wc2, bc2, g2, be2, Wzm, bzm, Wzs, bzs, ws_u, out);
        k_dec1<<<dim3(129), dim3(512), 0, stream>>>(
            eps, s0, nobs, nprd, Ws1, bs1, Ws2, bs2,
            Wd1, bd1, gd1, bed1, Wd2, bd2, gd2, bed2, Wt1, bt1,
            out, ws_u, ws_h2n, ws_p3, out);
        k_dec2<<<dim3(257), dim3(256), 0, stream>>>(
            x, pos, s0, nobs, nprd, Ws1, bs1, Ws2, bs2,
            Wt1, bt1, gt1, bet1, Wt2, bt2, out, ws_u, ws_h2n, ws_p3);
    }
}